// Round 1
// baseline (844.971 us; speedup 1.0000x reference)
//
#include <hip/hip_runtime.h>
#include <stdint.h>

typedef unsigned short u16;
typedef float f32x4 __attribute__((ext_vector_type(4)));
typedef __bf16 bf16x8 __attribute__((ext_vector_type(8)));

#define N1P 6272   // padded concat width: q(1024)|k(1024)|v(2048)|b(16)|a(16)|g(2048)|pad(96)

__device__ __forceinline__ u16 f2bf(float f) {
    union { float f; uint32_t u; } v; v.f = f;
    uint32_t u = v.u;
    return (u16)((u + 0x7FFFu + ((u >> 16) & 1u)) >> 16);
}
__device__ __forceinline__ float bf2f(u16 h) {
    union { uint32_t u; float f; } v; v.u = ((uint32_t)h) << 16; return v.f;
}
__device__ __forceinline__ float sigm(float x) { return 1.f / (1.f + __expf(-x)); }

__device__ __forceinline__ void async16(const u16* g, u16* l) {
    __builtin_amdgcn_global_load_lds((const __attribute__((address_space(1))) void*)g,
                                     (__attribute__((address_space(3))) void*)l, 16, 0, 0);
}

// ---------------- transpose + fp32->bf16 convert: dst[(rowOff+n)*srcRows + k] = src[k*srcCols + n]
__global__ __launch_bounds__(256) void k_transpose(const float* __restrict__ src, int srcRows, int srcCols,
                                                   u16* __restrict__ dst, int dstRowOff, int nOut) {
    __shared__ float tile[32][33];
    const int n0 = blockIdx.x * 32, k0 = blockIdx.y * 32;
    const int tx = threadIdx.x, ty = threadIdx.y;  // 32x8
#pragma unroll
    for (int j = 0; j < 32; j += 8) {
        int r = k0 + ty + j, c = n0 + tx;
        tile[ty + j][tx] = (r < srcRows && c < srcCols) ? src[(size_t)r * srcCols + c] : 0.f;
    }
    __syncthreads();
#pragma unroll
    for (int j = 0; j < 32; j += 8) {
        int n = n0 + ty + j, k = k0 + tx;
        if (n < nOut) dst[(size_t)(dstRowOff + n) * srcRows + k] = f2bf(tile[tx][ty + j]);
    }
}

// ---------------- rmsnorm over D=1024, fp32 in -> bf16 out
__global__ __launch_bounds__(256) void k_rmsnorm(const float* __restrict__ x, const float* __restrict__ w,
                                                 u16* __restrict__ out) {
    const int row = blockIdx.x, tid = threadIdx.x, lane = tid & 63, wave = tid >> 6;
    const float4 v = ((const float4*)(x + (size_t)row * 1024))[tid];
    float ss = v.x * v.x + v.y * v.y + v.z * v.z + v.w * v.w;
#pragma unroll
    for (int o = 1; o < 64; o <<= 1) ss += __shfl_xor(ss, o);
    __shared__ float sred[4];
    if (lane == 0) sred[wave] = ss;
    __syncthreads();
    const float tot = sred[0] + sred[1] + sred[2] + sred[3];
    const float rn = rsqrtf(tot * (1.f / 1024.f) + 1e-6f);
    const float4 wv = ((const float4*)w)[tid];
    uint2 pk;
    pk.x = (uint32_t)f2bf(v.x * rn * wv.x) | ((uint32_t)f2bf(v.y * rn * wv.y) << 16);
    pk.y = (uint32_t)f2bf(v.z * rn * wv.z) | ((uint32_t)f2bf(v.w * rn * wv.w) << 16);
    *(uint2*)&out[(size_t)row * 1024 + tid * 4] = pk;
}

// ---------------- bf16 GEMM, A[M][K] row-major, Bt[N][K] row-major (B transposed)
// EPI: 0 = fp32 store, 1 = fp32 store + fp32 residual add, 2 = bf16 store
template <int EPI>
__global__ __launch_bounds__(256) void k_gemm(const u16* __restrict__ A, const u16* __restrict__ Bt,
                                              void* __restrict__ Cout, const float* __restrict__ Res,
                                              int N, int Kd) {
    __shared__ __align__(16) u16 As[128 * 32];
    __shared__ __align__(16) u16 Bs[128 * 32];
    const int bm = blockIdx.x, bn = blockIdx.y;
    const int tid = threadIdx.x, lane = tid & 63, wave = tid >> 6;
    const int wm = wave >> 1, wn = wave & 1;

    const int lrow = wave * 16 + (lane >> 2);
    const int lcol = (lane & 3) * 8;
    const u16* gA = A + (size_t)(bm * 128 + lrow) * Kd + lcol;
    const u16* gB = Bt + (size_t)(bn * 128 + lrow) * Kd + lcol;
    u16* lA = As + wave * 512;
    u16* lB = Bs + wave * 512;

    f32x4 acc[4][4] = {};
    const int frow = lane & 15;
    const int fk = (lane >> 4) * 8;

    for (int k0 = 0; k0 < Kd; k0 += 32) {
        async16(gA + k0, lA);
        async16(gA + k0 + 64 * Kd, lA + 2048);
        async16(gB + k0, lB);
        async16(gB + k0 + 64 * Kd, lB + 2048);
        asm volatile("s_waitcnt vmcnt(0)" ::: "memory");
        __syncthreads();

        bf16x8 af[4], bfr[4];
#pragma unroll
        for (int mi = 0; mi < 4; ++mi)
            af[mi] = *(const bf16x8*)&As[(wm * 64 + mi * 16 + frow) * 32 + fk];
#pragma unroll
        for (int ni = 0; ni < 4; ++ni)
            bfr[ni] = *(const bf16x8*)&Bs[(wn * 64 + ni * 16 + frow) * 32 + fk];
#pragma unroll
        for (int mi = 0; mi < 4; ++mi)
#pragma unroll
            for (int ni = 0; ni < 4; ++ni)
                acc[mi][ni] = __builtin_amdgcn_mfma_f32_16x16x32_bf16(af[mi], bfr[ni], acc[mi][ni], 0, 0, 0);
        __syncthreads();
    }

    const int crow0 = bm * 128 + wm * 64;
    const int ccol0 = bn * 128 + wn * 64;
    const int rsub = (lane >> 4) * 4;
    const int csub = lane & 15;
#pragma unroll
    for (int mi = 0; mi < 4; ++mi)
#pragma unroll
        for (int ni = 0; ni < 4; ++ni) {
            const int c = ccol0 + ni * 16 + csub;
#pragma unroll
            for (int r = 0; r < 4; ++r) {
                const int rr = crow0 + mi * 16 + rsub + r;
                float v = acc[mi][ni][r];
                if (EPI == 2) {
                    ((u16*)Cout)[(size_t)rr * N + c] = f2bf(v);
                } else {
                    if (EPI == 1) v += Res[(size_t)rr * N + c];
                    ((float*)Cout)[(size_t)rr * N + c] = v;
                }
            }
        }
}

// ---------------- depthwise causal conv(4) + silu + l2norm(q,k) + beta/decay
__global__ __launch_bounds__(256) void k_conv(const u16* __restrict__ P, const float* __restrict__ cwq,
                                              const float* __restrict__ cwk, const float* __restrict__ cwv,
                                              const float* __restrict__ A_log, const float* __restrict__ dtb,
                                              float* __restrict__ Qs, float* __restrict__ Ks,
                                              float* __restrict__ Vs, float* __restrict__ Gd,
                                              float* __restrict__ Bbuf) {
    const int row = blockIdx.x;  // b*1024 + t
    const int t = row & 1023;
    const int tid = threadIdx.x;
    const long prow = (long)row * N1P;
#pragma unroll
    for (int p = 0; p < 16; ++p) {
        const int c = p * 256 + tid;
        float xv[4];
#pragma unroll
        for (int j = 0; j < 4; ++j) {
            const int tt = t - 3 + j;
            xv[j] = (tt >= 0) ? bf2f(P[prow + (long)(j - 3) * N1P + c]) : 0.f;
        }
        const float4 w = (c < 1024) ? ((const float4*)cwq)[c]
                         : (c < 2048) ? ((const float4*)cwk)[c - 1024]
                                      : ((const float4*)cwv)[c - 2048];
        float y = xv[0] * w.x + xv[1] * w.y + xv[2] * w.z + xv[3] * w.w;
        y = y * sigm(y);
        if (c < 2048) {
            float ss = y * y;
#pragma unroll
            for (int o = 1; o < 64; o <<= 1) ss += __shfl_xor(ss, o);
            const float rn = rsqrtf(ss + 1e-6f);
            if (c < 1024) Qs[(size_t)row * 1024 + c] = y * rn * 0.125f;
            else          Ks[(size_t)row * 1024 + (c - 1024)] = y * rn;
        } else {
            Vs[(size_t)row * 2048 + (c - 2048)] = y;
        }
    }
    if (tid < 32) {
        const int h = tid & 15;
        const float val = bf2f(P[prow + 4096 + tid]);
        if (tid < 16) {
            Bbuf[(size_t)row * 16 + h] = sigm(val);
        } else {
            const float a = val + dtb[h];
            const float sp = (a > 15.f) ? a : log1pf(__expf(a));
            Gd[(size_t)row * 16 + h] = __expf(-__expf(A_log[h]) * sp);
        }
    }
}

// ---------------- gated delta rule scan. block = (b,h,dv-group of 16); wave = 4 dv, lane: 16 dk-lanes x 4 dv
__global__ __launch_bounds__(256) void k_scan(const float* __restrict__ Qs, const float* __restrict__ Ks,
                                              const float* __restrict__ Vs, const float* __restrict__ Gd,
                                              const float* __restrict__ Bbuf, float* __restrict__ O) {
    const int blk = blockIdx.x;  // 256 = B(2) * H(16) * DVG(8)
    const int bb = blk >> 7;
    const int h = (blk >> 3) & 15;
    const int dvg = blk & 7;
    const int tid = threadIdx.x, lane = tid & 63, wave = tid >> 6;
    const int dv = dvg * 16 + wave * 4 + (lane >> 4);
    const int dk0 = (lane & 15) * 4;

    const float* qp = Qs + (size_t)bb * 1024 * 1024 + h * 64 + dk0;
    const float* kp = Ks + (size_t)bb * 1024 * 1024 + h * 64 + dk0;
    const float* vp = Vs + (size_t)bb * 1024 * 2048 + h * 128 + dv;
    const float* gp = Gd + (size_t)bb * 1024 * 16 + h;
    const float* bp = Bbuf + (size_t)bb * 1024 * 16 + h;
    float* op = O + (size_t)bb * 1024 * 2048 + h * 128 + dv;

    float S0 = 0.f, S1 = 0.f, S2 = 0.f, S3 = 0.f;
    float4 kc = *(const float4*)kp;
    float4 qc = *(const float4*)qp;
    float vc = *vp, dc = *gp, bc = *bp;

    for (int t = 0; t < 1024; ++t) {
        float4 kn = kc, qn = qc;
        float vn = vc, dn = dc, bn = bc;
        if (t < 1023) {
            kn = *(const float4*)(kp + (size_t)(t + 1) * 1024);
            qn = *(const float4*)(qp + (size_t)(t + 1) * 1024);
            vn = vp[(size_t)(t + 1) * 2048];
            dn = gp[(size_t)(t + 1) * 16];
            bn = bp[(size_t)(t + 1) * 16];
        }
        S0 *= dc; S1 *= dc; S2 *= dc; S3 *= dc;
        float p0 = kc.x * S0 + kc.y * S1;
        float p1 = kc.z * S2 + kc.w * S3;
        float p = p0 + p1;
        p += __shfl_xor(p, 1); p += __shfl_xor(p, 2);
        p += __shfl_xor(p, 4); p += __shfl_xor(p, 8);
        const float u = (vc - p) * bc;
        S0 = fmaf(kc.x, u, S0); S1 = fmaf(kc.y, u, S1);
        S2 = fmaf(kc.z, u, S2); S3 = fmaf(kc.w, u, S3);
        float q0 = qc.x * S0 + qc.y * S1;
        float q1 = qc.z * S2 + qc.w * S3;
        float oo = q0 + q1;
        oo += __shfl_xor(oo, 1); oo += __shfl_xor(oo, 2);
        oo += __shfl_xor(oo, 4); oo += __shfl_xor(oo, 8);
        if ((lane & 15) == 0) op[(size_t)t * 2048] = oo;
        kc = kn; qc = qn; vc = vn; dc = dn; bc = bn;
    }
}

// ---------------- per-head RMSNorm(o) * gate * sigmoid(gate) -> bf16
__global__ __launch_bounds__(256) void k_gate(const float* __restrict__ O, const u16* __restrict__ P,
                                              const float* __restrict__ onw, u16* __restrict__ OG) {
    const int row = blockIdx.x;
    const int tid = threadIdx.x, lane = tid & 63, wave = tid >> 6;
#pragma unroll
    for (int p = 0; p < 4; ++p) {
        const int h = p * 4 + wave;
        const int dv = lane * 2;
        const float2 o2 = *(const float2*)&O[(size_t)row * 2048 + h * 128 + dv];
        float ss = o2.x * o2.x + o2.y * o2.y;
#pragma unroll
        for (int o = 1; o < 64; o <<= 1) ss += __shfl_xor(ss, o);
        const float rn = rsqrtf(ss * (1.f / 128.f) + 1e-6f);
        const float g0 = bf2f(P[(size_t)row * N1P + 4128 + h * 128 + dv]);
        const float g1 = bf2f(P[(size_t)row * N1P + 4128 + h * 128 + dv + 1]);
        const float r0 = o2.x * rn * onw[dv] * g0 * sigm(g0);
        const float r1 = o2.y * rn * onw[dv + 1] * g1 * sigm(g1);
        const uint32_t pk = (uint32_t)f2bf(r0) | ((uint32_t)f2bf(r1) << 16);
        *(uint32_t*)&OG[(size_t)row * 2048 + h * 128 + dv] = pk;
    }
}

// ---------------- silu(u1) * u3 -> bf16
__global__ __launch_bounds__(256) void k_silumul(const u16* __restrict__ U13, u16* __restrict__ Mm) {
    const int idx = blockIdx.x * 256 + threadIdx.x;  // one per 4 elems; total 2048*704
    const int row = idx / 704, c4 = idx % 704;
    const size_t b1 = (size_t)row * 5632 + c4 * 4;
    const uint2 ua = *(const uint2*)&U13[b1];
    const uint2 ub = *(const uint2*)&U13[b1 + 2816];
    float a0 = bf2f(ua.x & 0xffff), a1 = bf2f(ua.x >> 16), a2 = bf2f(ua.y & 0xffff), a3 = bf2f(ua.y >> 16);
    float b0 = bf2f(ub.x & 0xffff), b1f = bf2f(ub.x >> 16), b2 = bf2f(ub.y & 0xffff), b3 = bf2f(ub.y >> 16);
    const float r0 = a0 * sigm(a0) * b0, r1 = a1 * sigm(a1) * b1f;
    const float r2 = a2 * sigm(a2) * b2, r3 = a3 * sigm(a3) * b3;
    uint2 pk;
    pk.x = (uint32_t)f2bf(r0) | ((uint32_t)f2bf(r1) << 16);
    pk.y = (uint32_t)f2bf(r2) | ((uint32_t)f2bf(r3) << 16);
    *(uint2*)&Mm[(size_t)row * 2816 + c4 * 4] = pk;
}

extern "C" void kernel_launch(void* const* d_in, const int* in_sizes, int n_in,
                              void* d_out, int out_size, void* d_ws, size_t ws_size,
                              hipStream_t stream) {
    const float* x   = (const float*)d_in[0];
    const float* n1w = (const float*)d_in[1];
    const float* wq  = (const float*)d_in[2];
    const float* wk  = (const float*)d_in[3];
    const float* wv  = (const float*)d_in[4];
    const float* cq  = (const float*)d_in[5];
    const float* ck  = (const float*)d_in[6];
    const float* cv  = (const float*)d_in[7];
    const float* wb  = (const float*)d_in[8];
    const float* wa  = (const float*)d_in[9];
    const float* Alg = (const float*)d_in[10];
    const float* dtb = (const float*)d_in[11];
    const float* wg  = (const float*)d_in[12];
    const float* onw = (const float*)d_in[13];
    const float* wo  = (const float*)d_in[14];
    const float* n2w = (const float*)d_in[15];
    const float* w1  = (const float*)d_in[16];
    const float* w2  = (const float*)d_in[17];
    const float* w3  = (const float*)d_in[18];

    if (ws_size < 114819072ULL) return;  // need ~114.8 MB scratch

    char* ws = (char*)d_ws;
    u16*   WcatT = (u16*)(ws + 0);           // [6272][1024] bf16
    u16*   WoT   = (u16*)(ws + 12845056);    // [1024][2048]
    u16*   W13T  = (u16*)(ws + 17039360);    // [5632][1024]
    u16*   W2T   = (u16*)(ws + 28573696);    // [1024][2816]
    u16*   hA    = (u16*)(ws + 34340864);    // [2048][1024] (reused as h2A)
    u16*   P     = (u16*)(ws + 38535168);    // [2048][6272] (reused as U13 [2048][5632])
    float* Qs    = (float*)(ws + 64225280);  // [2048][1024] (reused as Mm bf16 [2048][2816])
    float* Ks    = (float*)(ws + 72613888);  // [2048][1024]
    float* Vs    = (float*)(ws + 81002496);  // [2048][2048] (reused as OG bf16)
    float* Gd    = (float*)(ws + 97779712);  // [2048][16]
    float* Bbf   = (float*)(ws + 97910784);  // [2048][16]
    float* O     = (float*)(ws + 98041856);  // [2048][2048] (reused as X2 fp32 [2048][1024])
    u16*   U13 = P;
    u16*   Mm  = (u16*)Qs;
    u16*   OG  = (u16*)Vs;
    float* X2  = O;
    u16*   h2A = hA;

    const dim3 tb(32, 8);
    // weight transposes (fp32 [K][N] -> bf16 [N][K])
    k_transpose<<<dim3(32, 32), tb, 0, stream>>>(wq, 1024, 1024, WcatT, 0, 1024);
    k_transpose<<<dim3(32, 32), tb, 0, stream>>>(wk, 1024, 1024, WcatT, 1024, 1024);
    k_transpose<<<dim3(64, 32), tb, 0, stream>>>(wv, 1024, 2048, WcatT, 2048, 2048);
    k_transpose<<<dim3(1, 32),  tb, 0, stream>>>(wb, 1024, 16,   WcatT, 4096, 16);
    k_transpose<<<dim3(1, 32),  tb, 0, stream>>>(wa, 1024, 16,   WcatT, 4112, 16);
    k_transpose<<<dim3(67, 32), tb, 0, stream>>>(wg, 1024, 2048, WcatT, 4128, 2144);  // +96 zero pad rows
    k_transpose<<<dim3(32, 64), tb, 0, stream>>>(wo, 2048, 1024, WoT, 0, 1024);
    k_transpose<<<dim3(88, 32), tb, 0, stream>>>(w1, 1024, 2816, W13T, 0, 2816);
    k_transpose<<<dim3(88, 32), tb, 0, stream>>>(w3, 1024, 2816, W13T, 2816, 2816);
    k_transpose<<<dim3(32, 88), tb, 0, stream>>>(w2, 2816, 1024, W2T, 0, 1024);

    // h = rmsnorm(x) ; P = h @ [wq|wk|wv|wb|wa|wg]
    k_rmsnorm<<<2048, 256, 0, stream>>>(x, n1w, hA);
    k_gemm<2><<<dim3(16, 49), 256, 0, stream>>>(hA, WcatT, P, nullptr, N1P, 1024);

    // conv+silu+l2norm, beta, decay
    k_conv<<<2048, 256, 0, stream>>>(P, cq, ck, cv, Alg, dtb, Qs, Ks, Vs, Gd, Bbf);

    // gated delta rule scan
    k_scan<<<256, 256, 0, stream>>>(Qs, Ks, Vs, Gd, Bbf, O);

    // output gating, out-projection + residual
    k_gate<<<2048, 256, 0, stream>>>(O, P, onw, OG);
    k_gemm<1><<<dim3(16, 8), 256, 0, stream>>>(OG, WoT, X2, x, 1024, 2048);

    // SwiGLU MLP + residual
    k_rmsnorm<<<2048, 256, 0, stream>>>(X2, n2w, h2A);
    k_gemm<2><<<dim3(16, 44), 256, 0, stream>>>(h2A, W13T, U13, nullptr, 5632, 1024);
    k_silumul<<<5632, 256, 0, stream>>>(U13, Mm);
    k_gemm<1><<<dim3(16, 8), 256, 0, stream>>>(Mm, W2T, (float*)d_out, X2, 1024, 2816);
}

// Round 2
// 383.782 us; speedup vs baseline: 2.2017x; 2.2017x over previous
//
#include <hip/hip_runtime.h>
#include <stdint.h>

typedef unsigned short u16;
typedef float f32x4 __attribute__((ext_vector_type(4)));
typedef __bf16 bf16x8 __attribute__((ext_vector_type(8)));
typedef unsigned short u16x8 __attribute__((ext_vector_type(8)));

#define N1P 6272   // padded concat width: q(1024)|k(1024)|v(2048)|b(16)|a(16)|g(2048)|pad(96)

__device__ __forceinline__ u16 f2bf(float f) {
    union { float f; uint32_t u; } v; v.f = f;
    uint32_t u = v.u;
    return (u16)((u + 0x7FFFu + ((u >> 16) & 1u)) >> 16);
}
__device__ __forceinline__ float bf2f(u16 h) {
    union { uint32_t u; float f; } v; v.u = ((uint32_t)h) << 16; return v.f;
}
__device__ __forceinline__ float sigm(float x) { return 1.f / (1.f + __expf(-x)); }

__device__ __forceinline__ void async16(const u16* g, u16* l) {
    __builtin_amdgcn_global_load_lds((const __attribute__((address_space(1))) void*)g,
                                     (__attribute__((address_space(3))) void*)l, 16, 0, 0);
}

// byte offset inside a [R][64] bf16 "swizzled image": 16B units XOR'd with row&7
__device__ __forceinline__ int swz64(int row, int col) {
    return row * 128 + ((((col >> 3) ^ (row & 7)) << 3) + (col & 7)) * 2;
}
// MFMA fragment read from a swizzled [R][64] bf16 image (rows rowbase..rowbase+15, K-offset kk*32)
__device__ __forceinline__ bf16x8 frag64(const u16* m, int rowbase, int lane, int kk) {
    const int row = rowbase + (lane & 15);
    const int unit = (lane >> 4) + (kk << 2);
    return *(const bf16x8*)((const char*)m + row * 128 + ((unit ^ (row & 7)) << 4));
}

// ---------------- transpose + fp32->bf16 convert
__global__ __launch_bounds__(256) void k_transpose(const float* __restrict__ src, int srcRows, int srcCols,
                                                   u16* __restrict__ dst, int dstRowOff, int nOut) {
    __shared__ float tile[32][33];
    const int n0 = blockIdx.x * 32, k0 = blockIdx.y * 32;
    const int tx = threadIdx.x, ty = threadIdx.y;  // 32x8
#pragma unroll
    for (int j = 0; j < 32; j += 8) {
        int r = k0 + ty + j, c = n0 + tx;
        tile[ty + j][tx] = (r < srcRows && c < srcCols) ? src[(size_t)r * srcCols + c] : 0.f;
    }
    __syncthreads();
#pragma unroll
    for (int j = 0; j < 32; j += 8) {
        int n = n0 + ty + j, k = k0 + tx;
        if (n < nOut) dst[(size_t)(dstRowOff + n) * srcRows + k] = f2bf(tile[tx][ty + j]);
    }
}

// ---------------- rmsnorm over D=1024, fp32 in -> bf16 out
__global__ __launch_bounds__(256) void k_rmsnorm(const float* __restrict__ x, const float* __restrict__ w,
                                                 u16* __restrict__ out) {
    const int row = blockIdx.x, tid = threadIdx.x, lane = tid & 63, wave = tid >> 6;
    const float4 v = ((const float4*)(x + (size_t)row * 1024))[tid];
    float ss = v.x * v.x + v.y * v.y + v.z * v.z + v.w * v.w;
#pragma unroll
    for (int o = 1; o < 64; o <<= 1) ss += __shfl_xor(ss, o);
    __shared__ float sred[4];
    if (lane == 0) sred[wave] = ss;
    __syncthreads();
    const float tot = sred[0] + sred[1] + sred[2] + sred[3];
    const float rn = rsqrtf(tot * (1.f / 1024.f) + 1e-6f);
    const float4 wv = ((const float4*)w)[tid];
    uint2 pk;
    pk.x = (uint32_t)f2bf(v.x * rn * wv.x) | ((uint32_t)f2bf(v.y * rn * wv.y) << 16);
    pk.y = (uint32_t)f2bf(v.z * rn * wv.z) | ((uint32_t)f2bf(v.w * rn * wv.w) << 16);
    *(uint2*)&out[(size_t)row * 1024 + tid * 4] = pk;
}

// ---------------- bf16 GEMM, A[M][K] row-major, Bt[N][K] row-major
// EPI: 0 = fp32 store, 1 = fp32 store + fp32 residual add, 2 = bf16 store
template <int EPI>
__global__ __launch_bounds__(256) void k_gemm(const u16* __restrict__ A, const u16* __restrict__ Bt,
                                              void* __restrict__ Cout, const float* __restrict__ Res,
                                              int N, int Kd) {
    __shared__ __align__(16) u16 As[128 * 32];
    __shared__ __align__(16) u16 Bs[128 * 32];
    const int bm = blockIdx.x, bn = blockIdx.y;
    const int tid = threadIdx.x, lane = tid & 63, wave = tid >> 6;
    const int wm = wave >> 1, wn = wave & 1;

    const int lrow = wave * 16 + (lane >> 2);
    const int lcol = (lane & 3) * 8;
    const u16* gA = A + (size_t)(bm * 128 + lrow) * Kd + lcol;
    const u16* gB = Bt + (size_t)(bn * 128 + lrow) * Kd + lcol;
    u16* lA = As + wave * 512;
    u16* lB = Bs + wave * 512;

    f32x4 acc[4][4] = {};
    const int frow = lane & 15;
    const int fk = (lane >> 4) * 8;

    for (int k0 = 0; k0 < Kd; k0 += 32) {
        async16(gA + k0, lA);
        async16(gA + k0 + 64 * Kd, lA + 2048);
        async16(gB + k0, lB);
        async16(gB + k0 + 64 * Kd, lB + 2048);
        asm volatile("s_waitcnt vmcnt(0)" ::: "memory");
        __syncthreads();

        bf16x8 af[4], bfr[4];
#pragma unroll
        for (int mi = 0; mi < 4; ++mi)
            af[mi] = *(const bf16x8*)&As[(wm * 64 + mi * 16 + frow) * 32 + fk];
#pragma unroll
        for (int ni = 0; ni < 4; ++ni)
            bfr[ni] = *(const bf16x8*)&Bs[(wn * 64 + ni * 16 + frow) * 32 + fk];
#pragma unroll
        for (int mi = 0; mi < 4; ++mi)
#pragma unroll
            for (int ni = 0; ni < 4; ++ni)
                acc[mi][ni] = __builtin_amdgcn_mfma_f32_16x16x32_bf16(af[mi], bfr[ni], acc[mi][ni], 0, 0, 0);
        __syncthreads();
    }

    const int crow0 = bm * 128 + wm * 64;
    const int ccol0 = bn * 128 + wn * 64;
    const int rsub = (lane >> 4) * 4;
    const int csub = lane & 15;
#pragma unroll
    for (int mi = 0; mi < 4; ++mi)
#pragma unroll
        for (int ni = 0; ni < 4; ++ni) {
            const int c = ccol0 + ni * 16 + csub;
#pragma unroll
            for (int r = 0; r < 4; ++r) {
                const int rr = crow0 + mi * 16 + rsub + r;
                float v = acc[mi][ni][r];
                if (EPI == 2) {
                    ((u16*)Cout)[(size_t)rr * N + c] = f2bf(v);
                } else {
                    if (EPI == 1) v += Res[(size_t)rr * N + c];
                    ((float*)Cout)[(size_t)rr * N + c] = v;
                }
            }
        }
}

// ---------------- depthwise causal conv(4) + silu + l2norm(q,k) + beta / log-decay
__global__ __launch_bounds__(256) void k_conv(const u16* __restrict__ P, const float* __restrict__ cwq,
                                              const float* __restrict__ cwk, const float* __restrict__ cwv,
                                              const float* __restrict__ A_log, const float* __restrict__ dtb,
                                              u16* __restrict__ Qb, u16* __restrict__ Kb,
                                              u16* __restrict__ Vb, float* __restrict__ Gl,
                                              float* __restrict__ Bbuf) {
    const int row = blockIdx.x;  // b*1024 + t
    const int t = row & 1023;
    const int tid = threadIdx.x;
    const long prow = (long)row * N1P;
#pragma unroll
    for (int p = 0; p < 16; ++p) {
        const int c = p * 256 + tid;
        float xv[4];
#pragma unroll
        for (int j = 0; j < 4; ++j) {
            const int tt = t - 3 + j;
            xv[j] = (tt >= 0) ? bf2f(P[prow + (long)(j - 3) * N1P + c]) : 0.f;
        }
        const float4 w = (c < 1024) ? ((const float4*)cwq)[c]
                         : (c < 2048) ? ((const float4*)cwk)[c - 1024]
                                      : ((const float4*)cwv)[c - 2048];
        float y = xv[0] * w.x + xv[1] * w.y + xv[2] * w.z + xv[3] * w.w;
        y = y * sigm(y);
        if (c < 2048) {
            float ss = y * y;
#pragma unroll
            for (int o = 1; o < 64; o <<= 1) ss += __shfl_xor(ss, o);
            const float rn = rsqrtf(ss + 1e-6f);
            if (c < 1024) Qb[(size_t)row * 1024 + c] = f2bf(y * rn * 0.125f);
            else          Kb[(size_t)row * 1024 + (c - 1024)] = f2bf(y * rn);
        } else {
            Vb[(size_t)row * 2048 + (c - 2048)] = f2bf(y);
        }
    }
    if (tid < 32) {
        const int h = tid & 15;
        const float val = bf2f(P[prow + 4096 + tid]);
        if (tid < 16) {
            Bbuf[(size_t)row * 16 + h] = sigm(val);
        } else {
            const float a = val + dtb[h];
            const float sp = (a > 15.f) ? a : log1pf(__expf(a));
            Gl[(size_t)row * 16 + h] = -__expf(A_log[h]) * sp;   // log decay
        }
    }
}

// ---------------- chunked gated delta rule: stage 1 (per b,h,chunk — fully parallel)
__global__ __launch_bounds__(256) void k_scan1(
    const u16* __restrict__ Qb, const u16* __restrict__ Kb, const u16* __restrict__ Vb,
    const float* __restrict__ Gl, const float* __restrict__ Bb,
    u16* __restrict__ CHW, u16* __restrict__ CHM, u16* __restrict__ CHQc,
    u16* __restrict__ CHKcT, u16* __restrict__ CHU0T, float* __restrict__ CHcC) {
    __shared__ __align__(16) u16 Ql[64 * 64], Kl[64 * 64], VTb[128 * 64];
    __shared__ __align__(16) u16 Tb[64 * 64], KT1b[64 * 64], Ab[64 * 64];
    __shared__ float Tl[64 * 65];
    __shared__ float gcs[64], betal[64];
    const int blk = blockIdx.x;                      // bb*256 + h*16 + ch
    const int bb = blk >> 8, h = (blk >> 4) & 15, ch = blk & 15;
    const int bhc = blk;
    const int tid = threadIdx.x, lane = tid & 63, wave = tid >> 6;
    const long rowbase = (long)bb * 1024 + ch * 64;

    if (tid < 64) {
        gcs[tid] = Gl[(rowbase + tid) * 16 + h];
        betal[tid] = Bb[(rowbase + tid) * 16 + h];
    }
    for (int u = tid; u < 512; u += 256) {           // stage K,Q swizzled
        int r = u >> 3, c8 = u & 7;
        uint4 kv = *(const uint4*)&Kb[(rowbase + r) * 1024 + h * 64 + c8 * 8];
        uint4 qv = *(const uint4*)&Qb[(rowbase + r) * 1024 + h * 64 + c8 * 8];
        int b = r * 128 + ((c8 ^ (r & 7)) << 4);
        *(uint4*)((char*)Kl + b) = kv;
        *(uint4*)((char*)Ql + b) = qv;
    }
    __syncthreads();
    if (wave == 0) {                                 // inclusive cumsum of log decay
        float g = gcs[lane];
#pragma unroll
        for (int off = 1; off < 64; off <<= 1) {
            float n = __shfl_up(g, off, 64);
            if (lane >= off) g += n;
        }
        gcs[lane] = g;
    }
    // VTb[dv][c] = beta_c * V[c][dv]  (swizzled, bf16)
    for (int u = tid; u < 1024; u += 256) {
        int r = u >> 4, c8 = u & 15;
        u16x8 vv = *(const u16x8*)&Vb[(rowbase + r) * 2048 + h * 128 + c8 * 8];
        float bsc = betal[r];
#pragma unroll
        for (int j = 0; j < 8; ++j) {
            int dv = c8 * 8 + j;
            *(u16*)((char*)VTb + swz64(dv, r)) = f2bf(bf2f(vv[j]) * bsc);
        }
    }
    // QK^T and KK^T (wave = row-tile)
    f32x4 aQK[4] = {}, aKK[4] = {};
#pragma unroll
    for (int nt = 0; nt < 4; ++nt)
#pragma unroll
        for (int kk = 0; kk < 2; ++kk) {
            bf16x8 bq = frag64(Kl, nt * 16, lane, kk);
            aQK[nt] = __builtin_amdgcn_mfma_f32_16x16x32_bf16(frag64(Ql, wave * 16, lane, kk), bq, aQK[nt], 0, 0, 0);
            aKK[nt] = __builtin_amdgcn_mfma_f32_16x16x32_bf16(frag64(Kl, wave * 16, lane, kk), bq, aKK[nt], 0, 0, 0);
        }
    __syncthreads();   // gcs + VTb published

    const float gcsC = gcs[63];
#pragma unroll
    for (int nt = 0; nt < 4; ++nt)
#pragma unroll
        for (int reg = 0; reg < 4; ++reg) {
            int t = wave * 16 + ((lane >> 4) << 2) + reg;
            int i = nt * 16 + (lane & 15);
            float dec = __expf(gcs[t] - gcs[i]);
            float mv = (i <= t) ? dec * aQK[nt][reg] : 0.f;
            *(u16*)((char*)CHM + (size_t)bhc * 8192 + swz64(t, i)) = f2bf(mv);
            Ab[t * 64 + i] = (i < t) ? f2bf(betal[t] * dec * aKK[nt][reg]) : (u16)0;
        }
    for (int e = tid; e < 4096; e += 256) {
        int r = e >> 6, c = e & 63;
        Tl[r * 65 + c] = (r == c) ? 1.f : 0.f;
        int ib = swz64(r, c);
        float qv = bf2f(*(const u16*)((const char*)Ql + ib)) * __expf(gcs[r]);
        *(u16*)((char*)CHQc + (size_t)bhc * 8192 + ib) = f2bf(qv);
        float kv = bf2f(*(const u16*)((const char*)Kl + ib));
        int ob = swz64(c, r);
        *(u16*)((char*)KT1b + ob) = f2bf(kv * betal[r] * __expf(gcs[r]));
        *(u16*)((char*)CHKcT + (size_t)bhc * 8192 + ob) = f2bf(kv * __expf(gcsC - gcs[r]));
    }
    if (tid == 0) CHcC[bhc] = __expf(gcsC);
    __syncthreads();
    // T = (I+A)^{-1} by forward elimination (row i final at step i)
    for (int i = 0; i < 63; ++i) {
        if (lane <= i) {
            float tij = Tl[i * 65 + lane];
            for (int t = i + 1 + wave; t < 64; t += 4) {
                float a = bf2f(Ab[t * 64 + i]);
                Tl[t * 65 + lane] -= a * tij;
            }
        }
        __syncthreads();
    }
    for (int e = tid; e < 4096; e += 256) {
        int r = e >> 6, c = e & 63;
        *(u16*)((char*)Tb + swz64(r, c)) = f2bf(Tl[r * 65 + c]);
    }
    __syncthreads();
    // W = T @ (beta*c*K)   [rows c]
    {
        f32x4 aW[4] = {};
#pragma unroll
        for (int nt = 0; nt < 4; ++nt)
#pragma unroll
            for (int kk = 0; kk < 2; ++kk)
                aW[nt] = __builtin_amdgcn_mfma_f32_16x16x32_bf16(
                    frag64(Tb, wave * 16, lane, kk), frag64(KT1b, nt * 16, lane, kk), aW[nt], 0, 0, 0);
#pragma unroll
        for (int nt = 0; nt < 4; ++nt)
#pragma unroll
            for (int reg = 0; reg < 4; ++reg) {
                int r = wave * 16 + ((lane >> 4) << 2) + reg;
                int c = nt * 16 + (lane & 15);
                *(u16*)((char*)CHW + (size_t)bhc * 8192 + swz64(r, c)) = f2bf(aW[nt][reg]);
            }
    }
    // U0T = (beta*V)^T @ T^T   [rows dv = 128]
#pragma unroll
    for (int rt = 0; rt < 2; ++rt) {
        f32x4 aU[4] = {};
        int rb = (wave * 2 + rt) * 16;
#pragma unroll
        for (int nt = 0; nt < 4; ++nt)
#pragma unroll
            for (int kk = 0; kk < 2; ++kk)
                aU[nt] = __builtin_amdgcn_mfma_f32_16x16x32_bf16(
                    frag64(VTb, rb, lane, kk), frag64(Tb, nt * 16, lane, kk), aU[nt], 0, 0, 0);
#pragma unroll
        for (int nt = 0; nt < 4; ++nt)
#pragma unroll
            for (int reg = 0; reg < 4; ++reg) {
                int dv = rb + ((lane >> 4) << 2) + reg;
                int c = nt * 16 + (lane & 15);
                *(u16*)((char*)CHU0T + (size_t)bhc * 16384 + swz64(dv, c)) = f2bf(aU[nt][reg]);
            }
    }
}

// ---------------- chunked gated delta rule: stage 2 (sequential over 16 chunks; block = b,h,dv-half)
__global__ __launch_bounds__(256) void k_scan2(
    const u16* __restrict__ CHW, const u16* __restrict__ CHM, const u16* __restrict__ CHQc,
    const u16* __restrict__ CHKcT, const u16* __restrict__ CHU0T, const float* __restrict__ CHcC,
    float* __restrict__ O) {
    __shared__ __align__(16) u16 stg[2][5 * 4096];
    __shared__ __align__(16) u16 STb[4096], uTl[4096];
    __shared__ float ST[64 * 66];
    const int blk = blockIdx.x;
    const int bb = blk >> 5, h = (blk >> 1) & 15, dvh = blk & 1;
    const int bh = bb * 16 + h;
    const int tid = threadIdx.x, lane = tid & 63, wave = tid >> 6;

    for (int e = tid; e < 64 * 66; e += 256) ST[e] = 0.f;
    for (int e = tid; e < 4096; e += 256) STb[e] = 0;

    auto stage = [&](int buf, int ch) {
        const size_t base = (size_t)(bh * 16 + ch);
        const u16* srcs[5] = { CHW + base * 4096, CHM + base * 4096, CHQc + base * 4096,
                               CHKcT + base * 4096, CHU0T + base * 8192 + dvh * 4096 };
#pragma unroll
        for (int s = 0; s < 5; ++s)
#pragma unroll
            for (int r = 0; r < 2; ++r) {
                int ub = r * 256 + wave * 64;
                async16(srcs[s] + (size_t)(ub + lane) * 8, &stg[buf][s * 4096 + ub * 8]);
            }
    };
    stage(0, 0);
    for (int ch = 0; ch < 16; ++ch) {
        const int cur = ch & 1;
        asm volatile("s_waitcnt vmcnt(0)" ::: "memory");
        __syncthreads();
        if (ch < 15) stage(cur ^ 1, ch + 1);
        const u16* sW = &stg[cur][0];
        const u16* sM = &stg[cur][4096];
        const u16* sQc = &stg[cur][8192];
        const u16* sKcT = &stg[cur][12288];
        const u16* sU0 = &stg[cur][16384];
        // phase A: uT = U0T - (S0 W^T)    [rows dv]
        {
            f32x4 acc[4] = {};
#pragma unroll
            for (int nt = 0; nt < 4; ++nt)
#pragma unroll
                for (int kk = 0; kk < 2; ++kk)
                    acc[nt] = __builtin_amdgcn_mfma_f32_16x16x32_bf16(
                        frag64(STb, wave * 16, lane, kk), frag64(sW, nt * 16, lane, kk), acc[nt], 0, 0, 0);
#pragma unroll
            for (int nt = 0; nt < 4; ++nt)
#pragma unroll
                for (int reg = 0; reg < 4; ++reg) {
                    int dv = wave * 16 + ((lane >> 4) << 2) + reg;
                    int c = nt * 16 + (lane & 15);
                    int b = swz64(dv, c);
                    float u0 = bf2f(*(const u16*)((const char*)sU0 + b));
                    *(u16*)((char*)uTl + b) = f2bf(u0 - acc[nt][reg]);
                }
        }
        __syncthreads();
        // phase B: O = M@u + Qc@S0 (rows c); Sacc = u^T-rows-dv @ KcT (rows dv)
        f32x4 accO[4] = {}, accS[4] = {};
#pragma unroll
        for (int nt = 0; nt < 4; ++nt)
#pragma unroll
            for (int kk = 0; kk < 2; ++kk) {
                accO[nt] = __builtin_amdgcn_mfma_f32_16x16x32_bf16(
                    frag64(sM, wave * 16, lane, kk), frag64(uTl, nt * 16, lane, kk), accO[nt], 0, 0, 0);
                accO[nt] = __builtin_amdgcn_mfma_f32_16x16x32_bf16(
                    frag64(sQc, wave * 16, lane, kk), frag64(STb, nt * 16, lane, kk), accO[nt], 0, 0, 0);
                accS[nt] = __builtin_amdgcn_mfma_f32_16x16x32_bf16(
                    frag64(uTl, wave * 16, lane, kk), frag64(sKcT, nt * 16, lane, kk), accS[nt], 0, 0, 0);
            }
        __syncthreads();
        // phase C: write O; update state
        const float cC = CHcC[bh * 16 + ch];
#pragma unroll
        for (int nt = 0; nt < 4; ++nt)
#pragma unroll
            for (int reg = 0; reg < 4; ++reg) {
                int rr = wave * 16 + ((lane >> 4) << 2) + reg;
                int cc = nt * 16 + (lane & 15);
                O[((size_t)(bb * 1024 + ch * 64 + rr)) * 2048 + h * 128 + dvh * 64 + cc] = accO[nt][reg];
                float ns = cC * ST[rr * 66 + cc] + accS[nt][reg];
                ST[rr * 66 + cc] = ns;
                *(u16*)((char*)STb + swz64(rr, cc)) = f2bf(ns);
            }
    }
}

// ---------------- per-head RMSNorm(o) * gate * sigmoid(gate) -> bf16
__global__ __launch_bounds__(256) void k_gate(const float* __restrict__ O, const u16* __restrict__ P,
                                              const float* __restrict__ onw, u16* __restrict__ OG) {
    const int row = blockIdx.x;
    const int tid = threadIdx.x, lane = tid & 63, wave = tid >> 6;
#pragma unroll
    for (int p = 0; p < 4; ++p) {
        const int h = p * 4 + wave;
        const int dv = lane * 2;
        const float2 o2 = *(const float2*)&O[(size_t)row * 2048 + h * 128 + dv];
        float ss = o2.x * o2.x + o2.y * o2.y;
#pragma unroll
        for (int o = 1; o < 64; o <<= 1) ss += __shfl_xor(ss, o);
        const float rn = rsqrtf(ss * (1.f / 128.f) + 1e-6f);
        const float g0 = bf2f(P[(size_t)row * N1P + 4128 + h * 128 + dv]);
        const float g1 = bf2f(P[(size_t)row * N1P + 4128 + h * 128 + dv + 1]);
        const float r0 = o2.x * rn * onw[dv] * g0 * sigm(g0);
        const float r1 = o2.y * rn * onw[dv + 1] * g1 * sigm(g1);
        const uint32_t pk = (uint32_t)f2bf(r0) | ((uint32_t)f2bf(r1) << 16);
        *(uint32_t*)&OG[(size_t)row * 2048 + h * 128 + dv] = pk;
    }
}

// ---------------- silu(u1) * u3 -> bf16
__global__ __launch_bounds__(256) void k_silumul(const u16* __restrict__ U13, u16* __restrict__ Mm) {
    const int idx = blockIdx.x * 256 + threadIdx.x;
    const int row = idx / 704, c4 = idx % 704;
    const size_t b1 = (size_t)row * 5632 + c4 * 4;
    const uint2 ua = *(const uint2*)&U13[b1];
    const uint2 ub = *(const uint2*)&U13[b1 + 2816];
    float a0 = bf2f(ua.x & 0xffff), a1 = bf2f(ua.x >> 16), a2 = bf2f(ua.y & 0xffff), a3 = bf2f(ua.y >> 16);
    float b0 = bf2f(ub.x & 0xffff), b1f = bf2f(ub.x >> 16), b2 = bf2f(ub.y & 0xffff), b3 = bf2f(ub.y >> 16);
    const float r0 = a0 * sigm(a0) * b0, r1 = a1 * sigm(a1) * b1f;
    const float r2 = a2 * sigm(a2) * b2, r3 = a3 * sigm(a3) * b3;
    uint2 pk;
    pk.x = (uint32_t)f2bf(r0) | ((uint32_t)f2bf(r1) << 16);
    pk.y = (uint32_t)f2bf(r2) | ((uint32_t)f2bf(r3) << 16);
    *(uint2*)&Mm[(size_t)row * 2816 + c4 * 4] = pk;
}

extern "C" void kernel_launch(void* const* d_in, const int* in_sizes, int n_in,
                              void* d_out, int out_size, void* d_ws, size_t ws_size,
                              hipStream_t stream) {
    const float* x   = (const float*)d_in[0];
    const float* n1w = (const float*)d_in[1];
    const float* wq  = (const float*)d_in[2];
    const float* wk  = (const float*)d_in[3];
    const float* wv  = (const float*)d_in[4];
    const float* cq  = (const float*)d_in[5];
    const float* ck  = (const float*)d_in[6];
    const float* cv  = (const float*)d_in[7];
    const float* wb  = (const float*)d_in[8];
    const float* wa  = (const float*)d_in[9];
    const float* Alg = (const float*)d_in[10];
    const float* dtb = (const float*)d_in[11];
    const float* wg  = (const float*)d_in[12];
    const float* onw = (const float*)d_in[13];
    const float* wo  = (const float*)d_in[14];
    const float* n2w = (const float*)d_in[15];
    const float* w1  = (const float*)d_in[16];
    const float* w2  = (const float*)d_in[17];
    const float* w3  = (const float*)d_in[18];

    if (ws_size < 114819072ULL) return;

    char* ws = (char*)d_ws;
    u16*   WcatT = (u16*)(ws + 0);            // [6272][1024] bf16 (CHW/CHM/CHQc reuse)
    u16*   WoT   = (u16*)(ws + 12845056);     // [1024][2048]
    u16*   W13T  = (u16*)(ws + 17039360);     // [5632][1024]
    u16*   W2T   = (u16*)(ws + 28573696);     // [1024][2816]
    u16*   hA    = (u16*)(ws + 34340864);     // [2048][1024] (h2A reuse)
    u16*   P     = (u16*)(ws + 38535168);     // [2048][6272] (U13 reuse)
    u16*   Qb    = (u16*)(ws + 64225280);     // [2048][1024] bf16 (Mm reuse)
    u16*   Kb    = (u16*)(ws + 68419584);     // [2048][1024] bf16
    u16*   Vb    = (u16*)(ws + 72613888);     // [2048][2048] bf16 (OG reuse)
    float* Gl    = (float*)(ws + 81002496);   // [2048][16] log decay
    float* Bbf   = (float*)(ws + 81133568);   // [2048][16]
    float* O     = (float*)(ws + 81264640);   // [2048][2048] fp32 (X2 reuse)
    u16*   CHKcT = (u16*)(ws + 98041856);     // [512][64][64] bf16 image
    u16*   CHU0T = (u16*)(ws + 102236160);    // [512][128][64] bf16 image
    float* CHcC  = (float*)(ws + 110624768);  // [512]
    u16*   CHW   = WcatT;                     // [512][64][64] image
    u16*   CHM   = (u16*)(ws + 4194304);
    u16*   CHQc  = (u16*)(ws + 8388608);
    u16*   U13 = P;
    u16*   Mm  = Qb;
    u16*   OG  = Vb;
    float* X2  = O;
    u16*   h2A = hA;

    const dim3 tb(32, 8);
    k_transpose<<<dim3(32, 32), tb, 0, stream>>>(wq, 1024, 1024, WcatT, 0, 1024);
    k_transpose<<<dim3(32, 32), tb, 0, stream>>>(wk, 1024, 1024, WcatT, 1024, 1024);
    k_transpose<<<dim3(64, 32), tb, 0, stream>>>(wv, 1024, 2048, WcatT, 2048, 2048);
    k_transpose<<<dim3(1, 32),  tb, 0, stream>>>(wb, 1024, 16,   WcatT, 4096, 16);
    k_transpose<<<dim3(1, 32),  tb, 0, stream>>>(wa, 1024, 16,   WcatT, 4112, 16);
    k_transpose<<<dim3(67, 32), tb, 0, stream>>>(wg, 1024, 2048, WcatT, 4128, 2144);
    k_transpose<<<dim3(32, 64), tb, 0, stream>>>(wo, 2048, 1024, WoT, 0, 1024);
    k_transpose<<<dim3(88, 32), tb, 0, stream>>>(w1, 1024, 2816, W13T, 0, 2816);
    k_transpose<<<dim3(88, 32), tb, 0, stream>>>(w3, 1024, 2816, W13T, 2816, 2816);
    k_transpose<<<dim3(32, 88), tb, 0, stream>>>(w2, 2816, 1024, W2T, 0, 1024);

    k_rmsnorm<<<2048, 256, 0, stream>>>(x, n1w, hA);
    k_gemm<2><<<dim3(16, 49), 256, 0, stream>>>(hA, WcatT, P, nullptr, N1P, 1024);

    k_conv<<<2048, 256, 0, stream>>>(P, cq, ck, cv, Alg, dtb, Qb, Kb, Vb, Gl, Bbf);

    k_scan1<<<512, 256, 0, stream>>>(Qb, Kb, Vb, Gl, Bbf, CHW, CHM, CHQc, CHKcT, CHU0T, CHcC);
    k_scan2<<<64, 256, 0, stream>>>(CHW, CHM, CHQc, CHKcT, CHU0T, CHcC, O);

    k_gate<<<2048, 256, 0, stream>>>(O, P, onw, OG);
    k_gemm<1><<<dim3(16, 8), 256, 0, stream>>>(OG, WoT, X2, x, 1024, 2048);

    k_rmsnorm<<<2048, 256, 0, stream>>>(X2, n2w, h2A);
    k_gemm<2><<<dim3(16, 44), 256, 0, stream>>>(h2A, W13T, U13, nullptr, 5632, 1024);
    k_silumul<<<5632, 256, 0, stream>>>(U13, Mm);
    k_gemm<1><<<dim3(16, 8), 256, 0, stream>>>(Mm, W2T, (float*)d_out, X2, 1024, 2816);
}

// Round 3
// 322.113 us; speedup vs baseline: 2.6232x; 1.1915x over previous
//
#include <hip/hip_runtime.h>
#include <stdint.h>

typedef unsigned short u16;
typedef float f32x4 __attribute__((ext_vector_type(4)));
typedef __bf16 bf16x8 __attribute__((ext_vector_type(8)));
typedef unsigned short u16x8 __attribute__((ext_vector_type(8)));

#define N1P 6272   // padded concat width: q(1024)|k(1024)|v(2048)|b(16)|a(16)|g(2048)|pad(96)

__device__ __forceinline__ u16 f2bf(float f) {
    union { float f; uint32_t u; } v; v.f = f;
    uint32_t u = v.u;
    return (u16)((u + 0x7FFFu + ((u >> 16) & 1u)) >> 16);
}
__device__ __forceinline__ float bf2f(u16 h) {
    union { uint32_t u; float f; } v; v.u = ((uint32_t)h) << 16; return v.f;
}
__device__ __forceinline__ float sigm(float x) { return 1.f / (1.f + __expf(-x)); }

__device__ __forceinline__ void async16(const u16* g, u16* l) {
    __builtin_amdgcn_global_load_lds((const __attribute__((address_space(1))) void*)g,
                                     (__attribute__((address_space(3))) void*)l, 16, 0, 0);
}

// byte offset inside a [R][64] bf16 "swizzled image": 16B units XOR'd with row&7
__device__ __forceinline__ int swz64(int row, int col) {
    return row * 128 + ((((col >> 3) ^ (row & 7)) << 3) + (col & 7)) * 2;
}
// MFMA fragment read from a swizzled [R][64] bf16 image (rows rowbase..rowbase+15, K-offset kk*32)
__device__ __forceinline__ bf16x8 frag64(const u16* m, int rowbase, int lane, int kk) {
    const int row = rowbase + (lane & 15);
    const int unit = (lane >> 4) + (kk << 2);
    return *(const bf16x8*)((const char*)m + row * 128 + ((unit ^ (row & 7)) << 4));
}

// ---------------- transpose + fp32->bf16 convert
__global__ __launch_bounds__(256) void k_transpose(const float* __restrict__ src, int srcRows, int srcCols,
                                                   u16* __restrict__ dst, int dstRowOff, int nOut) {
    __shared__ float tile[32][33];
    const int n0 = blockIdx.x * 32, k0 = blockIdx.y * 32;
    const int tx = threadIdx.x, ty = threadIdx.y;  // 32x8
#pragma unroll
    for (int j = 0; j < 32; j += 8) {
        int r = k0 + ty + j, c = n0 + tx;
        tile[ty + j][tx] = (r < srcRows && c < srcCols) ? src[(size_t)r * srcCols + c] : 0.f;
    }
    __syncthreads();
#pragma unroll
    for (int j = 0; j < 32; j += 8) {
        int n = n0 + ty + j, k = k0 + tx;
        if (n < nOut) dst[(size_t)(dstRowOff + n) * srcRows + k] = f2bf(tile[tx][ty + j]);
    }
}

// ---------------- rmsnorm over D=1024, fp32 in -> bf16 out
__global__ __launch_bounds__(256) void k_rmsnorm(const float* __restrict__ x, const float* __restrict__ w,
                                                 u16* __restrict__ out) {
    const int row = blockIdx.x, tid = threadIdx.x, lane = tid & 63, wave = tid >> 6;
    const float4 v = ((const float4*)(x + (size_t)row * 1024))[tid];
    float ss = v.x * v.x + v.y * v.y + v.z * v.z + v.w * v.w;
#pragma unroll
    for (int o = 1; o < 64; o <<= 1) ss += __shfl_xor(ss, o);
    __shared__ float sred[4];
    if (lane == 0) sred[wave] = ss;
    __syncthreads();
    const float tot = sred[0] + sred[1] + sred[2] + sred[3];
    const float rn = rsqrtf(tot * (1.f / 1024.f) + 1e-6f);
    const float4 wv = ((const float4*)w)[tid];
    uint2 pk;
    pk.x = (uint32_t)f2bf(v.x * rn * wv.x) | ((uint32_t)f2bf(v.y * rn * wv.y) << 16);
    pk.y = (uint32_t)f2bf(v.z * rn * wv.z) | ((uint32_t)f2bf(v.w * rn * wv.w) << 16);
    *(uint2*)&out[(size_t)row * 1024 + tid * 4] = pk;
}

// ---------------- bf16 GEMM, A[M][K] row-major, Bt[N][K] row-major, BK=64, swizzled LDS
// TILE in {64,128}; EPI: 0 = fp32 store, 1 = fp32 + residual, 2 = bf16 store
template <int TILE, int EPI>
__global__ __launch_bounds__(256) void k_gemm(const u16* __restrict__ A, const u16* __restrict__ Bt,
                                              void* __restrict__ Cout, const float* __restrict__ Res,
                                              int N, int Kd) {
    __shared__ __align__(16) u16 As[TILE * 64];
    __shared__ __align__(16) u16 Bs[TILE * 64];
    const int bm = blockIdx.x, bn = blockIdx.y;
    const int tid = threadIdx.x, lane = tid & 63, wave = tid >> 6;
    const int wm = wave >> 1, wn = wave & 1;
    constexpr int WS = TILE / 2;   // per-wave output span
    constexpr int FR = WS / 16;    // 16x16 frags per dim
    constexpr int IS = TILE / 32;  // async16 issues per matrix per K-step

    const int srow = wave * 8 + (lane >> 3);           // staging row (mod 32-group)
    const int scol = ((lane & 7) ^ (lane >> 3)) * 8;   // pre-swizzled source granule
    const u16* gA = A + (size_t)(bm * TILE + srow) * Kd + scol;
    const u16* gB = Bt + (size_t)(bn * TILE + srow) * Kd + scol;

    f32x4 acc[FR][FR] = {};

    for (int k0 = 0; k0 < Kd; k0 += 64) {
#pragma unroll
        for (int j = 0; j < IS; ++j) {
            async16(gA + (size_t)j * 32 * Kd + k0, As + j * 2048 + wave * 512);
            async16(gB + (size_t)j * 32 * Kd + k0, Bs + j * 2048 + wave * 512);
        }
        asm volatile("s_waitcnt vmcnt(0)" ::: "memory");
        __syncthreads();

#pragma unroll
        for (int kk = 0; kk < 2; ++kk) {
            bf16x8 af[FR], bfr[FR];
#pragma unroll
            for (int mi = 0; mi < FR; ++mi) af[mi] = frag64(As, wm * WS + mi * 16, lane, kk);
#pragma unroll
            for (int ni = 0; ni < FR; ++ni) bfr[ni] = frag64(Bs, wn * WS + ni * 16, lane, kk);
#pragma unroll
            for (int mi = 0; mi < FR; ++mi)
#pragma unroll
                for (int ni = 0; ni < FR; ++ni)
                    acc[mi][ni] = __builtin_amdgcn_mfma_f32_16x16x32_bf16(af[mi], bfr[ni], acc[mi][ni], 0, 0, 0);
        }
        __syncthreads();
    }

    const int crow0 = bm * TILE + wm * WS;
    const int ccol0 = bn * TILE + wn * WS;
    const int rsub = (lane >> 4) * 4;
    const int csub = lane & 15;
#pragma unroll
    for (int mi = 0; mi < FR; ++mi)
#pragma unroll
        for (int ni = 0; ni < FR; ++ni) {
            const int c = ccol0 + ni * 16 + csub;
#pragma unroll
            for (int r = 0; r < 4; ++r) {
                const int rr = crow0 + mi * 16 + rsub + r;
                float v = acc[mi][ni][r];
                if (EPI == 2) {
                    ((u16*)Cout)[(size_t)rr * N + c] = f2bf(v);
                } else {
                    if (EPI == 1) v += Res[(size_t)rr * N + c];
                    ((float*)Cout)[(size_t)rr * N + c] = v;
                }
            }
        }
}

// ---------------- depthwise causal conv(4) + silu + l2norm(q,k) + beta / log-decay
__global__ __launch_bounds__(256) void k_conv(const u16* __restrict__ P, const float* __restrict__ cwq,
                                              const float* __restrict__ cwk, const float* __restrict__ cwv,
                                              const float* __restrict__ A_log, const float* __restrict__ dtb,
                                              u16* __restrict__ Qb, u16* __restrict__ Kb,
                                              u16* __restrict__ Vb, float* __restrict__ Gl,
                                              float* __restrict__ Bbuf) {
    const int row = blockIdx.x;  // b*1024 + t
    const int t = row & 1023;
    const int tid = threadIdx.x;
    const long prow = (long)row * N1P;
#pragma unroll
    for (int p = 0; p < 16; ++p) {
        const int c = p * 256 + tid;
        float xv[4];
#pragma unroll
        for (int j = 0; j < 4; ++j) {
            const int tt = t - 3 + j;
            xv[j] = (tt >= 0) ? bf2f(P[prow + (long)(j - 3) * N1P + c]) : 0.f;
        }
        const float4 w = (c < 1024) ? ((const float4*)cwq)[c]
                         : (c < 2048) ? ((const float4*)cwk)[c - 1024]
                                      : ((const float4*)cwv)[c - 2048];
        float y = xv[0] * w.x + xv[1] * w.y + xv[2] * w.z + xv[3] * w.w;
        y = y * sigm(y);
        if (c < 2048) {
            float ss = y * y;
#pragma unroll
            for (int o = 1; o < 64; o <<= 1) ss += __shfl_xor(ss, o);
            const float rn = rsqrtf(ss + 1e-6f);
            if (c < 1024) Qb[(size_t)row * 1024 + c] = f2bf(y * rn * 0.125f);
            else          Kb[(size_t)row * 1024 + (c - 1024)] = f2bf(y * rn);
        } else {
            Vb[(size_t)row * 2048 + (c - 2048)] = f2bf(y);
        }
    }
    if (tid < 32) {
        const int h = tid & 15;
        const float val = bf2f(P[prow + 4096 + tid]);
        if (tid < 16) {
            Bbuf[(size_t)row * 16 + h] = sigm(val);
        } else {
            const float a = val + dtb[h];
            const float sp = (a > 15.f) ? a : log1pf(__expf(a));
            Gl[(size_t)row * 16 + h] = -__expf(A_log[h]) * sp;   // log decay
        }
    }
}

// ---------------- chunked gated delta rule: stage 1 (per b,h,chunk — fully parallel)
__global__ __launch_bounds__(256) void k_scan1(
    const u16* __restrict__ Qb, const u16* __restrict__ Kb, const u16* __restrict__ Vb,
    const float* __restrict__ Gl, const float* __restrict__ Bb,
    u16* __restrict__ CHW, u16* __restrict__ CHM, u16* __restrict__ CHQc,
    u16* __restrict__ CHKcT, u16* __restrict__ CHU0T, float* __restrict__ CHcC) {
    __shared__ __align__(16) u16 Ql[64 * 64], Kl[64 * 64], VTb[128 * 64];
    __shared__ __align__(16) u16 Tb[64 * 64], KT1b[64 * 64], Ab[64 * 64];
    __shared__ float Tl[64 * 65];
    __shared__ float gcs[64], betal[64];
    const int blk = blockIdx.x;                      // bb*256 + h*16 + ch
    const int bb = blk >> 8, h = (blk >> 4) & 15, ch = blk & 15;
    const int bhc = blk;
    const int tid = threadIdx.x, lane = tid & 63, wave = tid >> 6;
    const long rowbase = (long)bb * 1024 + ch * 64;

    if (tid < 64) {
        gcs[tid] = Gl[(rowbase + tid) * 16 + h];
        betal[tid] = Bb[(rowbase + tid) * 16 + h];
    }
    for (int u = tid; u < 512; u += 256) {           // stage K,Q swizzled
        int r = u >> 3, c8 = u & 7;
        uint4 kv = *(const uint4*)&Kb[(rowbase + r) * 1024 + h * 64 + c8 * 8];
        uint4 qv = *(const uint4*)&Qb[(rowbase + r) * 1024 + h * 64 + c8 * 8];
        int b = r * 128 + ((c8 ^ (r & 7)) << 4);
        *(uint4*)((char*)Kl + b) = kv;
        *(uint4*)((char*)Ql + b) = qv;
    }
    __syncthreads();
    if (wave == 0) {                                 // inclusive cumsum of log decay
        float g = gcs[lane];
#pragma unroll
        for (int off = 1; off < 64; off <<= 1) {
            float n = __shfl_up(g, off, 64);
            if (lane >= off) g += n;
        }
        gcs[lane] = g;
    }
    // VTb[dv][c] = beta_c * V[c][dv]  (swizzled, bf16)
    for (int u = tid; u < 1024; u += 256) {
        int r = u >> 4, c8 = u & 15;
        u16x8 vv = *(const u16x8*)&Vb[(rowbase + r) * 2048 + h * 128 + c8 * 8];
        float bsc = betal[r];
#pragma unroll
        for (int j = 0; j < 8; ++j) {
            int dv = c8 * 8 + j;
            *(u16*)((char*)VTb + swz64(dv, r)) = f2bf(bf2f(vv[j]) * bsc);
        }
    }
    // QK^T and KK^T (wave = row-tile)
    f32x4 aQK[4] = {}, aKK[4] = {};
#pragma unroll
    for (int nt = 0; nt < 4; ++nt)
#pragma unroll
        for (int kk = 0; kk < 2; ++kk) {
            bf16x8 bq = frag64(Kl, nt * 16, lane, kk);
            aQK[nt] = __builtin_amdgcn_mfma_f32_16x16x32_bf16(frag64(Ql, wave * 16, lane, kk), bq, aQK[nt], 0, 0, 0);
            aKK[nt] = __builtin_amdgcn_mfma_f32_16x16x32_bf16(frag64(Kl, wave * 16, lane, kk), bq, aKK[nt], 0, 0, 0);
        }
    __syncthreads();   // gcs + VTb published

    const float gcsC = gcs[63];
#pragma unroll
    for (int nt = 0; nt < 4; ++nt)
#pragma unroll
        for (int reg = 0; reg < 4; ++reg) {
            int t = wave * 16 + ((lane >> 4) << 2) + reg;
            int i = nt * 16 + (lane & 15);
            float dec = __expf(gcs[t] - gcs[i]);
            float mv = (i <= t) ? dec * aQK[nt][reg] : 0.f;
            *(u16*)((char*)CHM + (size_t)bhc * 8192 + swz64(t, i)) = f2bf(mv);
            Ab[t * 64 + i] = (i < t) ? f2bf(betal[t] * dec * aKK[nt][reg]) : (u16)0;
        }
    for (int e = tid; e < 4096; e += 256) {
        int r = e >> 6, c = e & 63;
        Tl[r * 65 + c] = (r == c) ? 1.f : 0.f;
        int ib = swz64(r, c);
        float qv = bf2f(*(const u16*)((const char*)Ql + ib)) * __expf(gcs[r]);
        *(u16*)((char*)CHQc + (size_t)bhc * 8192 + ib) = f2bf(qv);
        float kv = bf2f(*(const u16*)((const char*)Kl + ib));
        int ob = swz64(c, r);
        *(u16*)((char*)KT1b + ob) = f2bf(kv * betal[r] * __expf(gcs[r]));
        *(u16*)((char*)CHKcT + (size_t)bhc * 8192 + ob) = f2bf(kv * __expf(gcsC - gcs[r]));
    }
    if (tid == 0) CHcC[bhc] = __expf(gcsC);
    __syncthreads();
    // T = (I+A)^{-1} by forward elimination (row i final at step i)
    for (int i = 0; i < 63; ++i) {
        if (lane <= i) {
            float tij = Tl[i * 65 + lane];
            for (int t = i + 1 + wave; t < 64; t += 4) {
                float a = bf2f(Ab[t * 64 + i]);
                Tl[t * 65 + lane] -= a * tij;
            }
        }
        __syncthreads();
    }
    for (int e = tid; e < 4096; e += 256) {
        int r = e >> 6, c = e & 63;
        *(u16*)((char*)Tb + swz64(r, c)) = f2bf(Tl[r * 65 + c]);
    }
    __syncthreads();
    // W = T @ (beta*c*K)   [rows c]
    {
        f32x4 aW[4] = {};
#pragma unroll
        for (int nt = 0; nt < 4; ++nt)
#pragma unroll
            for (int kk = 0; kk < 2; ++kk)
                aW[nt] = __builtin_amdgcn_mfma_f32_16x16x32_bf16(
                    frag64(Tb, wave * 16, lane, kk), frag64(KT1b, nt * 16, lane, kk), aW[nt], 0, 0, 0);
#pragma unroll
        for (int nt = 0; nt < 4; ++nt)
#pragma unroll
            for (int reg = 0; reg < 4; ++reg) {
                int r = wave * 16 + ((lane >> 4) << 2) + reg;
                int c = nt * 16 + (lane & 15);
                *(u16*)((char*)CHW + (size_t)bhc * 8192 + swz64(r, c)) = f2bf(aW[nt][reg]);
            }
    }
    // U0T = (beta*V)^T @ T^T   [rows dv = 128]
#pragma unroll
    for (int rt = 0; rt < 2; ++rt) {
        f32x4 aU[4] = {};
        int rb = (wave * 2 + rt) * 16;
#pragma unroll
        for (int nt = 0; nt < 4; ++nt)
#pragma unroll
            for (int kk = 0; kk < 2; ++kk)
                aU[nt] = __builtin_amdgcn_mfma_f32_16x16x32_bf16(
                    frag64(VTb, rb, lane, kk), frag64(Tb, nt * 16, lane, kk), aU[nt], 0, 0, 0);
#pragma unroll
        for (int nt = 0; nt < 4; ++nt)
#pragma unroll
            for (int reg = 0; reg < 4; ++reg) {
                int dv = rb + ((lane >> 4) << 2) + reg;
                int c = nt * 16 + (lane & 15);
                *(u16*)((char*)CHU0T + (size_t)bhc * 16384 + swz64(dv, c)) = f2bf(aU[nt][reg]);
            }
    }
}

// ---------------- chunked gated delta rule: stage 2 (sequential over 16 chunks; block = b,h,dv-half)
__global__ __launch_bounds__(256) void k_scan2(
    const u16* __restrict__ CHW, const u16* __restrict__ CHM, const u16* __restrict__ CHQc,
    const u16* __restrict__ CHKcT, const u16* __restrict__ CHU0T, const float* __restrict__ CHcC,
    float* __restrict__ O) {
    __shared__ __align__(16) u16 stg[2][5 * 4096];
    __shared__ __align__(16) u16 STb[4096], uTl[4096];
    __shared__ float ST[64 * 66];
    const int blk = blockIdx.x;
    const int bb = blk >> 5, h = (blk >> 1) & 15, dvh = blk & 1;
    const int bh = bb * 16 + h;
    const int tid = threadIdx.x, lane = tid & 63, wave = tid >> 6;

    for (int e = tid; e < 64 * 66; e += 256) ST[e] = 0.f;
    for (int e = tid; e < 4096; e += 256) STb[e] = 0;

    auto stage = [&](int buf, int ch) {
        const size_t base = (size_t)(bh * 16 + ch);
        const u16* srcs[5] = { CHW + base * 4096, CHM + base * 4096, CHQc + base * 4096,
                               CHKcT + base * 4096, CHU0T + base * 8192 + dvh * 4096 };
#pragma unroll
        for (int s = 0; s < 5; ++s)
#pragma unroll
            for (int r = 0; r < 2; ++r) {
                int ub = r * 256 + wave * 64;
                async16(srcs[s] + (size_t)(ub + lane) * 8, &stg[buf][s * 4096 + ub * 8]);
            }
    };
    stage(0, 0);
    for (int ch = 0; ch < 16; ++ch) {
        const int cur = ch & 1;
        asm volatile("s_waitcnt vmcnt(0)" ::: "memory");
        __syncthreads();
        if (ch < 15) stage(cur ^ 1, ch + 1);
        const u16* sW = &stg[cur][0];
        const u16* sM = &stg[cur][4096];
        const u16* sQc = &stg[cur][8192];
        const u16* sKcT = &stg[cur][12288];
        const u16* sU0 = &stg[cur][16384];
        // phase A: uT = U0T - (S0 W^T)    [rows dv]
        {
            f32x4 acc[4] = {};
#pragma unroll
            for (int nt = 0; nt < 4; ++nt)
#pragma unroll
                for (int kk = 0; kk < 2; ++kk)
                    acc[nt] = __builtin_amdgcn_mfma_f32_16x16x32_bf16(
                        frag64(STb, wave * 16, lane, kk), frag64(sW, nt * 16, lane, kk), acc[nt], 0, 0, 0);
#pragma unroll
            for (int nt = 0; nt < 4; ++nt)
#pragma unroll
                for (int reg = 0; reg < 4; ++reg) {
                    int dv = wave * 16 + ((lane >> 4) << 2) + reg;
                    int c = nt * 16 + (lane & 15);
                    int b = swz64(dv, c);
                    float u0 = bf2f(*(const u16*)((const char*)sU0 + b));
                    *(u16*)((char*)uTl + b) = f2bf(u0 - acc[nt][reg]);
                }
        }
        __syncthreads();
        // phase B: O = M@u + Qc@S0 (rows c); Sacc = u^T-rows-dv @ KcT (rows dv)
        f32x4 accO[4] = {}, accS[4] = {};
#pragma unroll
        for (int nt = 0; nt < 4; ++nt)
#pragma unroll
            for (int kk = 0; kk < 2; ++kk) {
                accO[nt] = __builtin_amdgcn_mfma_f32_16x16x32_bf16(
                    frag64(sM, wave * 16, lane, kk), frag64(uTl, nt * 16, lane, kk), accO[nt], 0, 0, 0);
                accO[nt] = __builtin_amdgcn_mfma_f32_16x16x32_bf16(
                    frag64(sQc, wave * 16, lane, kk), frag64(STb, nt * 16, lane, kk), accO[nt], 0, 0, 0);
                accS[nt] = __builtin_amdgcn_mfma_f32_16x16x32_bf16(
                    frag64(uTl, wave * 16, lane, kk), frag64(sKcT, nt * 16, lane, kk), accS[nt], 0, 0, 0);
            }
        __syncthreads();
        // phase C: write O; update state
        const float cC = CHcC[bh * 16 + ch];
#pragma unroll
        for (int nt = 0; nt < 4; ++nt)
#pragma unroll
            for (int reg = 0; reg < 4; ++reg) {
                int rr = wave * 16 + ((lane >> 4) << 2) + reg;
                int cc = nt * 16 + (lane & 15);
                O[((size_t)(bb * 1024 + ch * 64 + rr)) * 2048 + h * 128 + dvh * 64 + cc] = accO[nt][reg];
                float ns = cC * ST[rr * 66 + cc] + accS[nt][reg];
                ST[rr * 66 + cc] = ns;
                *(u16*)((char*)STb + swz64(rr, cc)) = f2bf(ns);
            }
    }
}

// ---------------- per-head RMSNorm(o) * gate * sigmoid(gate) -> bf16
__global__ __launch_bounds__(256) void k_gate(const float* __restrict__ O, const u16* __restrict__ P,
                                              const float* __restrict__ onw, u16* __restrict__ OG) {
    const int row = blockIdx.x;
    const int tid = threadIdx.x, lane = tid & 63, wave = tid >> 6;
#pragma unroll
    for (int p = 0; p < 4; ++p) {
        const int h = p * 4 + wave;
        const int dv = lane * 2;
        const float2 o2 = *(const float2*)&O[(size_t)row * 2048 + h * 128 + dv];
        float ss = o2.x * o2.x + o2.y * o2.y;
#pragma unroll
        for (int o = 1; o < 64; o <<= 1) ss += __shfl_xor(ss, o);
        const float rn = rsqrtf(ss * (1.f / 128.f) + 1e-6f);
        const float g0 = bf2f(P[(size_t)row * N1P + 4128 + h * 128 + dv]);
        const float g1 = bf2f(P[(size_t)row * N1P + 4128 + h * 128 + dv + 1]);
        const float r0 = o2.x * rn * onw[dv] * g0 * sigm(g0);
        const float r1 = o2.y * rn * onw[dv + 1] * g1 * sigm(g1);
        const uint32_t pk = (uint32_t)f2bf(r0) | ((uint32_t)f2bf(r1) << 16);
        *(uint32_t*)&OG[(size_t)row * 2048 + h * 128 + dv] = pk;
    }
}

// ---------------- silu(u1) * u3 -> bf16
__global__ __launch_bounds__(256) void k_silumul(const u16* __restrict__ U13, u16* __restrict__ Mm) {
    const int idx = blockIdx.x * 256 + threadIdx.x;
    const int row = idx / 704, c4 = idx % 704;
    const size_t b1 = (size_t)row * 5632 + c4 * 4;
    const uint2 ua = *(const uint2*)&U13[b1];
    const uint2 ub = *(const uint2*)&U13[b1 + 2816];
    float a0 = bf2f(ua.x & 0xffff), a1 = bf2f(ua.x >> 16), a2 = bf2f(ua.y & 0xffff), a3 = bf2f(ua.y >> 16);
    float b0 = bf2f(ub.x & 0xffff), b1f = bf2f(ub.x >> 16), b2 = bf2f(ub.y & 0xffff), b3 = bf2f(ub.y >> 16);
    const float r0 = a0 * sigm(a0) * b0, r1 = a1 * sigm(a1) * b1f;
    const float r2 = a2 * sigm(a2) * b2, r3 = a3 * sigm(a3) * b3;
    uint2 pk;
    pk.x = (uint32_t)f2bf(r0) | ((uint32_t)f2bf(r1) << 16);
    pk.y = (uint32_t)f2bf(r2) | ((uint32_t)f2bf(r3) << 16);
    *(uint2*)&Mm[(size_t)row * 2816 + c4 * 4] = pk;
}

extern "C" void kernel_launch(void* const* d_in, const int* in_sizes, int n_in,
                              void* d_out, int out_size, void* d_ws, size_t ws_size,
                              hipStream_t stream) {
    const float* x   = (const float*)d_in[0];
    const float* n1w = (const float*)d_in[1];
    const float* wq  = (const float*)d_in[2];
    const float* wk  = (const float*)d_in[3];
    const float* wv  = (const float*)d_in[4];
    const float* cq  = (const float*)d_in[5];
    const float* ck  = (const float*)d_in[6];
    const float* cv  = (const float*)d_in[7];
    const float* wb  = (const float*)d_in[8];
    const float* wa  = (const float*)d_in[9];
    const float* Alg = (const float*)d_in[10];
    const float* dtb = (const float*)d_in[11];
    const float* wg  = (const float*)d_in[12];
    const float* onw = (const float*)d_in[13];
    const float* wo  = (const float*)d_in[14];
    const float* n2w = (const float*)d_in[15];
    const float* w1  = (const float*)d_in[16];
    const float* w2  = (const float*)d_in[17];
    const float* w3  = (const float*)d_in[18];

    if (ws_size < 114819072ULL) return;

    char* ws = (char*)d_ws;
    u16*   WcatT = (u16*)(ws + 0);            // [6272][1024] bf16 (CHW/CHM/CHQc reuse)
    u16*   WoT   = (u16*)(ws + 12845056);     // [1024][2048]
    u16*   W13T  = (u16*)(ws + 17039360);     // [5632][1024]
    u16*   W2T   = (u16*)(ws + 28573696);     // [1024][2816]
    u16*   hA    = (u16*)(ws + 34340864);     // [2048][1024] (h2A reuse)
    u16*   P     = (u16*)(ws + 38535168);     // [2048][6272] (U13 reuse)
    u16*   Qb    = (u16*)(ws + 64225280);     // [2048][1024] bf16 (Mm reuse)
    u16*   Kb    = (u16*)(ws + 68419584);     // [2048][1024] bf16
    u16*   Vb    = (u16*)(ws + 72613888);     // [2048][2048] bf16 (OG reuse)
    float* Gl    = (float*)(ws + 81002496);   // [2048][16] log decay
    float* Bbf   = (float*)(ws + 81133568);   // [2048][16]
    float* O     = (float*)(ws + 81264640);   // [2048][2048] fp32 (X2 reuse)
    u16*   CHKcT = (u16*)(ws + 98041856);     // [512][64][64] bf16 image
    u16*   CHU0T = (u16*)(ws + 102236160);    // [512][128][64] bf16 image
    float* CHcC  = (float*)(ws + 110624768);  // [512]
    u16*   CHW   = WcatT;                     // [512][64][64] image
    u16*   CHM   = (u16*)(ws + 4194304);
    u16*   CHQc  = (u16*)(ws + 8388608);
    u16*   U13 = P;
    u16*   Mm  = Qb;
    u16*   OG  = Vb;
    float* X2  = O;
    u16*   h2A = hA;

    const dim3 tb(32, 8);
    k_transpose<<<dim3(32, 32), tb, 0, stream>>>(wq, 1024, 1024, WcatT, 0, 1024);
    k_transpose<<<dim3(32, 32), tb, 0, stream>>>(wk, 1024, 1024, WcatT, 1024, 1024);
    k_transpose<<<dim3(64, 32), tb, 0, stream>>>(wv, 1024, 2048, WcatT, 2048, 2048);
    k_transpose<<<dim3(1, 32),  tb, 0, stream>>>(wb, 1024, 16,   WcatT, 4096, 16);
    k_transpose<<<dim3(1, 32),  tb, 0, stream>>>(wa, 1024, 16,   WcatT, 4112, 16);
    k_transpose<<<dim3(67, 32), tb, 0, stream>>>(wg, 1024, 2048, WcatT, 4128, 2144);
    k_transpose<<<dim3(32, 64), tb, 0, stream>>>(wo, 2048, 1024, WoT, 0, 1024);
    k_transpose<<<dim3(88, 32), tb, 0, stream>>>(w1, 1024, 2816, W13T, 0, 2816);
    k_transpose<<<dim3(88, 32), tb, 0, stream>>>(w3, 1024, 2816, W13T, 2816, 2816);
    k_transpose<<<dim3(32, 88), tb, 0, stream>>>(w2, 2816, 1024, W2T, 0, 1024);

    k_rmsnorm<<<2048, 256, 0, stream>>>(x, n1w, hA);
    k_gemm<128, 2><<<dim3(16, 49), 256, 0, stream>>>(hA, WcatT, P, nullptr, N1P, 1024);

    k_conv<<<2048, 256, 0, stream>>>(P, cq, ck, cv, Alg, dtb, Qb, Kb, Vb, Gl, Bbf);

    k_scan1<<<512, 256, 0, stream>>>(Qb, Kb, Vb, Gl, Bbf, CHW, CHM, CHQc, CHKcT, CHU0T, CHcC);
    k_scan2<<<64, 256, 0, stream>>>(CHW, CHM, CHQc, CHKcT, CHU0T, CHcC, O);

    k_gate<<<2048, 256, 0, stream>>>(O, P, onw, OG);
    k_gemm<64, 1><<<dim3(32, 16), 256, 0, stream>>>(OG, WoT, X2, x, 1024, 2048);

    k_rmsnorm<<<2048, 256, 0, stream>>>(X2, n2w, h2A);
    k_gemm<128, 2><<<dim3(16, 44), 256, 0, stream>>>(h2A, W13T, U13, nullptr, 5632, 1024);
    k_silumul<<<5632, 256, 0, stream>>>(U13, Mm);
    k_gemm<64, 1><<<dim3(32, 16), 256, 0, stream>>>(Mm, W2T, (float*)d_out, X2, 1024, 2816);
}

// Round 5
// 297.151 us; speedup vs baseline: 2.8436x; 1.0840x over previous
//
#include <hip/hip_runtime.h>
#include <stdint.h>

typedef unsigned short u16;
typedef float f32x4 __attribute__((ext_vector_type(4)));
typedef __bf16 bf16x8 __attribute__((ext_vector_type(8)));
typedef unsigned short u16x8 __attribute__((ext_vector_type(8)));

#define N1P 6272   // padded concat width: q(1024)|k(1024)|v(2048)|b(16)|a(16)|g(2048)|pad(96)

__device__ __forceinline__ u16 f2bf(float f) {
    union { float f; uint32_t u; } v; v.f = f;
    uint32_t u = v.u;
    return (u16)((u + 0x7FFFu + ((u >> 16) & 1u)) >> 16);
}
__device__ __forceinline__ float bf2f(u16 h) {
    union { uint32_t u; float f; } v; v.u = ((uint32_t)h) << 16; return v.f;
}
__device__ __forceinline__ float sigm(float x) { return 1.f / (1.f + __expf(-x)); }

__device__ __forceinline__ void async16(const u16* g, u16* l) {
    __builtin_amdgcn_global_load_lds((const __attribute__((address_space(1))) void*)g,
                                     (__attribute__((address_space(3))) void*)l, 16, 0, 0);
}

// byte offset inside a [R][64] bf16 "swizzled image": 16B units XOR'd with row&7
__device__ __forceinline__ int swz64(int row, int col) {
    return row * 128 + ((((col >> 3) ^ (row & 7)) << 3) + (col & 7)) * 2;
}
// MFMA fragment read from a swizzled [R][64] bf16 image (rows rowbase..rowbase+15, K-offset kk*32)
__device__ __forceinline__ bf16x8 frag64(const u16* m, int rowbase, int lane, int kk) {
    const int row = rowbase + (lane & 15);
    const int unit = (lane >> 4) + (kk << 2);
    return *(const bf16x8*)((const char*)m + row * 128 + ((unit ^ (row & 7)) << 4));
}

// ---------------- transpose + fp32->bf16 convert
__global__ __launch_bounds__(256) void k_transpose(const float* __restrict__ src, int srcRows, int srcCols,
                                                   u16* __restrict__ dst, int dstRowOff, int nOut) {
    __shared__ float tile[32][33];
    const int n0 = blockIdx.x * 32, k0 = blockIdx.y * 32;
    const int tx = threadIdx.x, ty = threadIdx.y;  // 32x8
#pragma unroll
    for (int j = 0; j < 32; j += 8) {
        int r = k0 + ty + j, c = n0 + tx;
        tile[ty + j][tx] = (r < srcRows && c < srcCols) ? src[(size_t)r * srcCols + c] : 0.f;
    }
    __syncthreads();
#pragma unroll
    for (int j = 0; j < 32; j += 8) {
        int n = n0 + ty + j, k = k0 + tx;
        if (n < nOut) dst[(size_t)(dstRowOff + n) * srcRows + k] = f2bf(tile[tx][ty + j]);
    }
}

// ---------------- rmsnorm over D=1024, fp32 in -> bf16 out
__global__ __launch_bounds__(256) void k_rmsnorm(const float* __restrict__ x, const float* __restrict__ w,
                                                 u16* __restrict__ out) {
    const int row = blockIdx.x, tid = threadIdx.x, lane = tid & 63, wave = tid >> 6;
    const float4 v = ((const float4*)(x + (size_t)row * 1024))[tid];
    float ss = v.x * v.x + v.y * v.y + v.z * v.z + v.w * v.w;
#pragma unroll
    for (int o = 1; o < 64; o <<= 1) ss += __shfl_xor(ss, o);
    __shared__ float sred[4];
    if (lane == 0) sred[wave] = ss;
    __syncthreads();
    const float tot = sred[0] + sred[1] + sred[2] + sred[3];
    const float rn = rsqrtf(tot * (1.f / 1024.f) + 1e-6f);
    const float4 wv = ((const float4*)w)[tid];
    uint2 pk;
    pk.x = (uint32_t)f2bf(v.x * rn * wv.x) | ((uint32_t)f2bf(v.y * rn * wv.y) << 16);
    pk.y = (uint32_t)f2bf(v.z * rn * wv.z) | ((uint32_t)f2bf(v.w * rn * wv.w) << 16);
    *(uint2*)&out[(size_t)row * 1024 + tid * 4] = pk;
}

// ---------------- bf16 GEMM, A[M][K] row-major, Bt[N][K] row-major, BK=64, swizzled LDS
// TILE in {64,128}; EPI: 0 = fp32 store, 1 = fp32 + residual, 2 = bf16 store
template <int TILE, int EPI>
__global__ __launch_bounds__(256) void k_gemm(const u16* __restrict__ A, const u16* __restrict__ Bt,
                                              void* __restrict__ Cout, const float* __restrict__ Res,
                                              int N, int Kd) {
    __shared__ __align__(16) u16 As[TILE * 64];
    __shared__ __align__(16) u16 Bs[TILE * 64];
    const int bm = blockIdx.x, bn = blockIdx.y;
    const int tid = threadIdx.x, lane = tid & 63, wave = tid >> 6;
    const int wm = wave >> 1, wn = wave & 1;
    constexpr int WS = TILE / 2;   // per-wave output span
    constexpr int FR = WS / 16;    // 16x16 frags per dim
    constexpr int IS = TILE / 32;  // async16 issues per matrix per K-step

    const int srow = wave * 8 + (lane >> 3);           // staging row (mod 32-group)
    const int scol = ((lane & 7) ^ (lane >> 3)) * 8;   // pre-swizzled source granule
    const u16* gA = A + (size_t)(bm * TILE + srow) * Kd + scol;
    const u16* gB = Bt + (size_t)(bn * TILE + srow) * Kd + scol;

    f32x4 acc[FR][FR] = {};

    for (int k0 = 0; k0 < Kd; k0 += 64) {
#pragma unroll
        for (int j = 0; j < IS; ++j) {
            async16(gA + (size_t)j * 32 * Kd + k0, As + j * 2048 + wave * 512);
            async16(gB + (size_t)j * 32 * Kd + k0, Bs + j * 2048 + wave * 512);
        }
        asm volatile("s_waitcnt vmcnt(0)" ::: "memory");
        __syncthreads();

#pragma unroll
        for (int kk = 0; kk < 2; ++kk) {
            bf16x8 af[FR], bfr[FR];
#pragma unroll
            for (int mi = 0; mi < FR; ++mi) af[mi] = frag64(As, wm * WS + mi * 16, lane, kk);
#pragma unroll
            for (int ni = 0; ni < FR; ++ni) bfr[ni] = frag64(Bs, wn * WS + ni * 16, lane, kk);
#pragma unroll
            for (int mi = 0; mi < FR; ++mi)
#pragma unroll
                for (int ni = 0; ni < FR; ++ni)
                    acc[mi][ni] = __builtin_amdgcn_mfma_f32_16x16x32_bf16(af[mi], bfr[ni], acc[mi][ni], 0, 0, 0);
        }
        __syncthreads();
    }

    const int crow0 = bm * TILE + wm * WS;
    const int ccol0 = bn * TILE + wn * WS;
    const int rsub = (lane >> 4) * 4;
    const int csub = lane & 15;
#pragma unroll
    for (int mi = 0; mi < FR; ++mi)
#pragma unroll
        for (int ni = 0; ni < FR; ++ni) {
            const int c = ccol0 + ni * 16 + csub;
#pragma unroll
            for (int r = 0; r < 4; ++r) {
                const int rr = crow0 + mi * 16 + rsub + r;
                float v = acc[mi][ni][r];
                if (EPI == 2) {
                    ((u16*)Cout)[(size_t)rr * N + c] = f2bf(v);
                } else {
                    if (EPI == 1) v += Res[(size_t)rr * N + c];
                    ((float*)Cout)[(size_t)rr * N + c] = v;
                }
            }
        }
}

// ---------------- depthwise causal conv(4) + silu + l2norm(q,k) + beta / log-decay
__global__ __launch_bounds__(256) void k_conv(const u16* __restrict__ P, const float* __restrict__ cwq,
                                              const float* __restrict__ cwk, const float* __restrict__ cwv,
                                              const float* __restrict__ A_log, const float* __restrict__ dtb,
                                              u16* __restrict__ Qb, u16* __restrict__ Kb,
                                              u16* __restrict__ Vb, float* __restrict__ Gl,
                                              float* __restrict__ Bbuf) {
    const int row = blockIdx.x;  // b*1024 + t
    const int t = row & 1023;
    const int tid = threadIdx.x;
    const long prow = (long)row * N1P;
#pragma unroll
    for (int p = 0; p < 16; ++p) {
        const int c = p * 256 + tid;
        float xv[4];
#pragma unroll
        for (int j = 0; j < 4; ++j) {
            const int tt = t - 3 + j;
            xv[j] = (tt >= 0) ? bf2f(P[prow + (long)(j - 3) * N1P + c]) : 0.f;
        }
        const float4 w = (c < 1024) ? ((const float4*)cwq)[c]
                         : (c < 2048) ? ((const float4*)cwk)[c - 1024]
                                      : ((const float4*)cwv)[c - 2048];
        float y = xv[0] * w.x + xv[1] * w.y + xv[2] * w.z + xv[3] * w.w;
        y = y * sigm(y);
        if (c < 2048) {
            float ss = y * y;
#pragma unroll
            for (int o = 1; o < 64; o <<= 1) ss += __shfl_xor(ss, o);
            const float rn = rsqrtf(ss + 1e-6f);
            if (c < 1024) Qb[(size_t)row * 1024 + c] = f2bf(y * rn * 0.125f);
            else          Kb[(size_t)row * 1024 + (c - 1024)] = f2bf(y * rn);
        } else {
            Vb[(size_t)row * 2048 + (c - 2048)] = f2bf(y);
        }
    }
    if (tid < 32) {
        const int h = tid & 15;
        const float val = bf2f(P[prow + 4096 + tid]);
        if (tid < 16) {
            Bbuf[(size_t)row * 16 + h] = sigm(val);
        } else {
            const float a = val + dtb[h];
            const float sp = (a > 15.f) ? a : log1pf(__expf(a));
            Gl[(size_t)row * 16 + h] = -__expf(A_log[h]) * sp;   // log decay
        }
    }
}

// ---------------- chunked gated delta rule: stage 1 (per b,h,chunk — fully parallel)
// T = (I+A)^{-1} = (I+M0)(I+M1)...(I+M5), M0 = -A, M_j = M_{j-1}^2 (exact, A nilpotent)
__global__ __launch_bounds__(256) void k_scan1(
    const u16* __restrict__ Qb, const u16* __restrict__ Kb, const u16* __restrict__ Vb,
    const float* __restrict__ Gl, const float* __restrict__ Bb,
    u16* __restrict__ CHW, u16* __restrict__ CHM, u16* __restrict__ CHQc,
    u16* __restrict__ CHKcT, u16* __restrict__ CHU0T, float* __restrict__ CHcC) {
    __shared__ __align__(16) char sm[66048];
    u16* Ql   = (u16*)(sm);            // 8KB   (phase<=2a; then low half of fp32 T master)
    u16* Kl   = (u16*)(sm + 8192);     // 8KB   (phase<=2a; then high half of T master)
    u16* VTb  = (u16*)(sm + 16384);    // 16KB
    u16* KT1b = (u16*)(sm + 32768);    // 8KB
    u16* Mim  = (u16*)(sm + 40960);    // 8KB   M_j image (in-place squared)
    u16* MTim = (u16*)(sm + 49152);    // 8KB   M_j^T image
    u16* Tb   = (u16*)(sm + 57344);    // 8KB   bf16 T image (per-wave-owned rows)
    float* Tl    = (float*)sm;         // 16KB fp32 T master, overlays Ql+Kl after 2a
    float* gcs   = (float*)(sm + 65536);
    float* betal = (float*)(sm + 65792);

    const int blk = blockIdx.x;                      // bb*256 + h*16 + ch
    const int bb = blk >> 8, h = (blk >> 4) & 15, ch = blk & 15;
    const int bhc = blk;
    const int tid = threadIdx.x, lane = tid & 63, wave = tid >> 6;
    const long rowbase = (long)bb * 1024 + ch * 64;

    // phase 0: stage K,Q swizzled; load per-row gate scalars
    if (tid < 64) {
        gcs[tid] = Gl[(rowbase + tid) * 16 + h];
        betal[tid] = Bb[(rowbase + tid) * 16 + h];
    }
    for (int u = tid; u < 512; u += 256) {
        int r = u >> 3, c8 = u & 7;
        uint4 kv = *(const uint4*)&Kb[(rowbase + r) * 1024 + h * 64 + c8 * 8];
        uint4 qv = *(const uint4*)&Qb[(rowbase + r) * 1024 + h * 64 + c8 * 8];
        int b = r * 128 + ((c8 ^ (r & 7)) << 4);
        *(uint4*)((char*)Kl + b) = kv;
        *(uint4*)((char*)Ql + b) = qv;
    }
    __syncthreads();
    // phase 1: cumsum (wave 0); VTb build; QK^T / KK^T
    if (wave == 0) {
        float g = gcs[lane];
#pragma unroll
        for (int off = 1; off < 64; off <<= 1) {
            float n = __shfl_up(g, off, 64);
            if (lane >= off) g += n;
        }
        gcs[lane] = g;
    }
    for (int u = tid; u < 1024; u += 256) {          // VTb[dv][c] = beta_c * V[c][dv]
        int r = u >> 4, c8 = u & 15;
        u16x8 vv = *(const u16x8*)&Vb[(rowbase + r) * 2048 + h * 128 + c8 * 8];
        float bsc = betal[r];
#pragma unroll
        for (int j = 0; j < 8; ++j) {
            int dv = c8 * 8 + j;
            *(u16*)((char*)VTb + swz64(dv, r)) = f2bf(bf2f(vv[j]) * bsc);
        }
    }
    f32x4 aQK[4] = {}, aKK[4] = {};
#pragma unroll
    for (int nt = 0; nt < 4; ++nt)
#pragma unroll
        for (int kk = 0; kk < 2; ++kk) {
            bf16x8 bq = frag64(Kl, nt * 16, lane, kk);
            aQK[nt] = __builtin_amdgcn_mfma_f32_16x16x32_bf16(frag64(Ql, wave * 16, lane, kk), bq, aQK[nt], 0, 0, 0);
            aKK[nt] = __builtin_amdgcn_mfma_f32_16x16x32_bf16(frag64(Kl, wave * 16, lane, kk), bq, aKK[nt], 0, 0, 0);
        }
    __syncthreads();   // gcs + VTb published

    // phase 2a: CHM, M0 = -A images, CHQc, KT1b, CHKcT (reads Ql/Kl)
    const float gcsC = gcs[63];
    float am[4][4];    // keep -A values for phase 2b
#pragma unroll
    for (int nt = 0; nt < 4; ++nt)
#pragma unroll
        for (int reg = 0; reg < 4; ++reg) {
            int t = wave * 16 + ((lane >> 4) << 2) + reg;
            int i = nt * 16 + (lane & 15);
            float dec = __expf(gcs[t] - gcs[i]);
            float mv = (i <= t) ? dec * aQK[nt][reg] : 0.f;
            *(u16*)((char*)CHM + (size_t)bhc * 8192 + swz64(t, i)) = f2bf(mv);
            float a = (i < t) ? betal[t] * dec * aKK[nt][reg] : 0.f;
            am[nt][reg] = -a;
            u16 amb = f2bf(-a);
            *(u16*)((char*)Mim + swz64(t, i)) = amb;
            *(u16*)((char*)MTim + swz64(i, t)) = amb;
        }
    for (int e = tid; e < 4096; e += 256) {
        int r = e >> 6, c = e & 63;
        int ib = swz64(r, c);
        float qv = bf2f(*(const u16*)((const char*)Ql + ib)) * __expf(gcs[r]);
        *(u16*)((char*)CHQc + (size_t)bhc * 8192 + ib) = f2bf(qv);
        float kv = bf2f(*(const u16*)((const char*)Kl + ib));
        int ob = swz64(c, r);
        *(u16*)((char*)KT1b + ob) = f2bf(kv * betal[r] * __expf(gcs[r]));
        *(u16*)((char*)CHKcT + (size_t)bhc * 8192 + ob) = f2bf(kv * __expf(gcsC - gcs[r]));
    }
    if (tid == 0) CHcC[bhc] = __expf(gcsC);
    __syncthreads();   // Ql/Kl dead; Tl overlay becomes safe

    // phase 2b: T0 = I + M0 = I - A  (fp32 master + bf16 image, own rows)
#pragma unroll
    for (int nt = 0; nt < 4; ++nt)
#pragma unroll
        for (int reg = 0; reg < 4; ++reg) {
            int t = wave * 16 + ((lane >> 4) << 2) + reg;
            int i = nt * 16 + (lane & 15);
            float tv = (t == i) ? 1.f : am[nt][reg];
            Tl[t * 64 + i] = tv;
            *(u16*)((char*)Tb + swz64(t, i)) = f2bf(tv);
        }
    __syncthreads();

    // phase 3: doubling. stage j: M <- M^2 (in place), then T <- T + T*M.
    const int hi = wave * 16 + 15;
#pragma unroll
    for (int j = 1; j <= 5; ++j) {
        // square M (read Mim own rows as A-op, MTim all rows as B-op)
        f32x4 aM[4] = {};
#pragma unroll
        for (int nt = 0; nt < 4; ++nt) {
            if (nt * 16 > hi - (1 << j)) continue;
#pragma unroll
            for (int kk = 0; kk < 2; ++kk) {
                if (kk * 32 > hi) break;
                aM[nt] = __builtin_amdgcn_mfma_f32_16x16x32_bf16(
                    frag64(Mim, wave * 16, lane, kk), frag64(MTim, nt * 16, lane, kk), aM[nt], 0, 0, 0);
            }
        }
        __syncthreads();   // all reads of M_{j-1} done
        // write M_j in place (ALL entries — masked zeros, no stale data)
#pragma unroll
        for (int nt = 0; nt < 4; ++nt)
#pragma unroll
            for (int reg = 0; reg < 4; ++reg) {
                int t = wave * 16 + ((lane >> 4) << 2) + reg;
                int i = nt * 16 + (lane & 15);
                float mv = (t - i >= (1 << j)) ? aM[nt][reg] : 0.f;
                u16 mb = f2bf(mv);
                *(u16*)((char*)Mim + swz64(t, i)) = mb;
                *(u16*)((char*)MTim + swz64(i, t)) = mb;
            }
        __syncthreads();   // M_j published
        // T update: aT = T (fp32 master) + T*M_j ; own rows only -> no barrier needed after
        f32x4 aT[4];
#pragma unroll
        for (int nt = 0; nt < 4; ++nt)
#pragma unroll
            for (int reg = 0; reg < 4; ++reg) {
                int t = wave * 16 + ((lane >> 4) << 2) + reg;
                int i = nt * 16 + (lane & 15);
                aT[nt][reg] = Tl[t * 64 + i];
            }
#pragma unroll
        for (int nt = 0; nt < 4; ++nt) {
            if (nt * 16 > hi - (1 << j)) continue;
#pragma unroll
            for (int kk = 0; kk < 2; ++kk) {
                if (kk * 32 > hi) break;
                aT[nt] = __builtin_amdgcn_mfma_f32_16x16x32_bf16(
                    frag64(Tb, wave * 16, lane, kk), frag64(MTim, nt * 16, lane, kk), aT[nt], 0, 0, 0);
            }
        }
#pragma unroll
        for (int nt = 0; nt < 4; ++nt)
#pragma unroll
            for (int reg = 0; reg < 4; ++reg) {
                int t = wave * 16 + ((lane >> 4) << 2) + reg;
                int i = nt * 16 + (lane & 15);
                Tl[t * 64 + i] = aT[nt][reg];
                *(u16*)((char*)Tb + swz64(t, i)) = f2bf(aT[nt][reg]);
            }
    }
    __syncthreads();   // U0T below reads other waves' Tb rows

    // final: W = T @ (beta*c*K);  U0T = (beta*V)^T @ T^T
    {
        f32x4 aW[4] = {};
#pragma unroll
        for (int nt = 0; nt < 4; ++nt)
#pragma unroll
            for (int kk = 0; kk < 2; ++kk) {
                if (kk * 32 > hi) break;   // T[t][k] zero for k > t
                aW[nt] = __builtin_amdgcn_mfma_f32_16x16x32_bf16(
                    frag64(Tb, wave * 16, lane, kk), frag64(KT1b, nt * 16, lane, kk), aW[nt], 0, 0, 0);
            }
#pragma unroll
        for (int nt = 0; nt < 4; ++nt)
#pragma unroll
            for (int reg = 0; reg < 4; ++reg) {
                int r = wave * 16 + ((lane >> 4) << 2) + reg;
                int c = nt * 16 + (lane & 15);
                *(u16*)((char*)CHW + (size_t)bhc * 8192 + swz64(r, c)) = f2bf(aW[nt][reg]);
            }
    }
#pragma unroll
    for (int rt = 0; rt < 2; ++rt) {
        f32x4 aU[4] = {};
        int rb = (wave * 2 + rt) * 16;
#pragma unroll
        for (int nt = 0; nt < 4; ++nt)
#pragma unroll
            for (int kk = 0; kk < 2; ++kk) {
                if (kk * 32 > nt * 16 + 15) continue;  // T[c][k] zero for k > c
                aU[nt] = __builtin_amdgcn_mfma_f32_16x16x32_bf16(
                    frag64(VTb, rb, lane, kk), frag64(Tb, nt * 16, lane, kk), aU[nt], 0, 0, 0);
            }
#pragma unroll
        for (int nt = 0; nt < 4; ++nt)
#pragma unroll
            for (int reg = 0; reg < 4; ++reg) {
                int dv = rb + ((lane >> 4) << 2) + reg;
                int c = nt * 16 + (lane & 15);
                *(u16*)((char*)CHU0T + (size_t)bhc * 16384 + swz64(dv, c)) = f2bf(aU[nt][reg]);
            }
    }
}

// ---------------- chunked gated delta rule: stage 2 (sequential over 16 chunks; block = b,h,dv-half)
__global__ __launch_bounds__(256) void k_scan2(
    const u16* __restrict__ CHW, const u16* __restrict__ CHM, const u16* __restrict__ CHQc,
    const u16* __restrict__ CHKcT, const u16* __restrict__ CHU0T, const float* __restrict__ CHcC,
    float* __restrict__ O) {
    __shared__ __align__(16) u16 stg[2][5 * 4096];
    __shared__ __align__(16) u16 STb[4096], uTl[4096];
    __shared__ float ST[64 * 66];
    const int blk = blockIdx.x;
    const int bb = blk >> 5, h = (blk >> 1) & 15, dvh = blk & 1;
    const int bh = bb * 16 + h;
    const int tid = threadIdx.x, lane = tid & 63, wave = tid >> 6;

    for (int e = tid; e < 64 * 66; e += 256) ST[e] = 0.f;
    for (int e = tid; e < 4096; e += 256) STb[e] = 0;

    auto stage = [&](int buf, int ch) {
        const size_t base = (size_t)(bh * 16 + ch);
        const u16* srcs[5] = { CHW + base * 4096, CHM + base * 4096, CHQc + base * 4096,
                               CHKcT + base * 4096, CHU0T + base * 8192 + dvh * 4096 };
#pragma unroll
        for (int s = 0; s < 5; ++s)
#pragma unroll
            for (int r = 0; r < 2; ++r) {
                int ub = r * 256 + wave * 64;
                async16(srcs[s] + (size_t)(ub + lane) * 8, &stg[buf][s * 4096 + ub * 8]);
            }
    };
    stage(0, 0);
    for (int ch = 0; ch < 16; ++ch) {
        const int cur = ch & 1;
        asm volatile("s_waitcnt vmcnt(0)" ::: "memory");
        __syncthreads();
        if (ch < 15) stage(cur ^ 1, ch + 1);
        const u16* sW = &stg[cur][0];
        const u16* sM = &stg[cur][4096];
        const u16* sQc = &stg[cur][8192];
        const u16* sKcT = &stg[cur][12288];
        const u16* sU0 = &stg[cur][16384];
        // phase A: uT = U0T - (S0 W^T)    [rows dv]
        {
            f32x4 acc[4] = {};
#pragma unroll
            for (int nt = 0; nt < 4; ++nt)
#pragma unroll
                for (int kk = 0; kk < 2; ++kk)
                    acc[nt] = __builtin_amdgcn_mfma_f32_16x16x32_bf16(
                        frag64(STb, wave * 16, lane, kk), frag64(sW, nt * 16, lane, kk), acc[nt], 0, 0, 0);
#pragma unroll
            for (int nt = 0; nt < 4; ++nt)
#pragma unroll
                for (int reg = 0; reg < 4; ++reg) {
                    int dv = wave * 16 + ((lane >> 4) << 2) + reg;
                    int c = nt * 16 + (lane & 15);
                    int b = swz64(dv, c);
                    float u0 = bf2f(*(const u16*)((const char*)sU0 + b));
                    *(u16*)((char*)uTl + b) = f2bf(u0 - acc[nt][reg]);
                }
        }
        __syncthreads();
        // phase B: O = M@u + Qc@S0 (rows c); Sacc = u^T-rows-dv @ KcT (rows dv)
        f32x4 accO[4] = {}, accS[4] = {};
#pragma unroll
        for (int nt = 0; nt < 4; ++nt)
#pragma unroll
            for (int kk = 0; kk < 2; ++kk) {
                accO[nt] = __builtin_amdgcn_mfma_f32_16x16x32_bf16(
                    frag64(sM, wave * 16, lane, kk), frag64(uTl, nt * 16, lane, kk), accO[nt], 0, 0, 0);
                accO[nt] = __builtin_amdgcn_mfma_f32_16x16x32_bf16(
                    frag64(sQc, wave * 16, lane, kk), frag64(STb, nt * 16, lane, kk), accO[nt], 0, 0, 0);
                accS[nt] = __builtin_amdgcn_mfma_f32_16x16x32_bf16(
                    frag64(uTl, wave * 16, lane, kk), frag64(sKcT, nt * 16, lane, kk), accS[nt], 0, 0, 0);
            }
        __syncthreads();
        // phase C: write O; update state
        const float cC = CHcC[bh * 16 + ch];
#pragma unroll
        for (int nt = 0; nt < 4; ++nt)
#pragma unroll
            for (int reg = 0; reg < 4; ++reg) {
                int rr = wave * 16 + ((lane >> 4) << 2) + reg;
                int cc = nt * 16 + (lane & 15);
                O[((size_t)(bb * 1024 + ch * 64 + rr)) * 2048 + h * 128 + dvh * 64 + cc] = accO[nt][reg];
                float ns = cC * ST[rr * 66 + cc] + accS[nt][reg];
                ST[rr * 66 + cc] = ns;
                *(u16*)((char*)STb + swz64(rr, cc)) = f2bf(ns);
            }
    }
}

// ---------------- per-head RMSNorm(o) * gate * sigmoid(gate) -> bf16
__global__ __launch_bounds__(256) void k_gate(const float* __restrict__ O, const u16* __restrict__ P,
                                              const float* __restrict__ onw, u16* __restrict__ OG) {
    const int row = blockIdx.x;
    const int tid = threadIdx.x, lane = tid & 63, wave = tid >> 6;
#pragma unroll
    for (int p = 0; p < 4; ++p) {
        const int h = p * 4 + wave;
        const int dv = lane * 2;
        const float2 o2 = *(const float2*)&O[(size_t)row * 2048 + h * 128 + dv];
        float ss = o2.x * o2.x + o2.y * o2.y;
#pragma unroll
        for (int o = 1; o < 64; o <<= 1) ss += __shfl_xor(ss, o);
        const float rn = rsqrtf(ss * (1.f / 128.f) + 1e-6f);
        const float g0 = bf2f(P[(size_t)row * N1P + 4128 + h * 128 + dv]);
        const float g1 = bf2f(P[(size_t)row * N1P + 4128 + h * 128 + dv + 1]);
        const float r0 = o2.x * rn * onw[dv] * g0 * sigm(g0);
        const float r1 = o2.y * rn * onw[dv + 1] * g1 * sigm(g1);
        const uint32_t pk = (uint32_t)f2bf(r0) | ((uint32_t)f2bf(r1) << 16);
        *(uint32_t*)&OG[(size_t)row * 2048 + h * 128 + dv] = pk;
    }
}

// ---------------- silu(u1) * u3 -> bf16
__global__ __launch_bounds__(256) void k_silumul(const u16* __restrict__ U13, u16* __restrict__ Mm) {
    const int idx = blockIdx.x * 256 + threadIdx.x;
    const int row = idx / 704, c4 = idx % 704;
    const size_t b1 = (size_t)row * 5632 + c4 * 4;
    const uint2 ua = *(const uint2*)&U13[b1];
    const uint2 ub = *(const uint2*)&U13[b1 + 2816];
    float a0 = bf2f(ua.x & 0xffff), a1 = bf2f(ua.x >> 16), a2 = bf2f(ua.y & 0xffff), a3 = bf2f(ua.y >> 16);
    float b0 = bf2f(ub.x & 0xffff), b1f = bf2f(ub.x >> 16), b2 = bf2f(ub.y & 0xffff), b3 = bf2f(ub.y >> 16);
    const float r0 = a0 * sigm(a0) * b0, r1 = a1 * sigm(a1) * b1f;
    const float r2 = a2 * sigm(a2) * b2, r3 = a3 * sigm(a3) * b3;
    uint2 pk;
    pk.x = (uint32_t)f2bf(r0) | ((uint32_t)f2bf(r1) << 16);
    pk.y = (uint32_t)f2bf(r2) | ((uint32_t)f2bf(r3) << 16);
    *(uint2*)&Mm[(size_t)row * 2816 + c4 * 4] = pk;
}

extern "C" void kernel_launch(void* const* d_in, const int* in_sizes, int n_in,
                              void* d_out, int out_size, void* d_ws, size_t ws_size,
                              hipStream_t stream) {
    const float* x   = (const float*)d_in[0];
    const float* n1w = (const float*)d_in[1];
    const float* wq  = (const float*)d_in[2];
    const float* wk  = (const float*)d_in[3];
    const float* wv  = (const float*)d_in[4];
    const float* cq  = (const float*)d_in[5];
    const float* ck  = (const float*)d_in[6];
    const float* cv  = (const float*)d_in[7];
    const float* wb  = (const float*)d_in[8];
    const float* wa  = (const float*)d_in[9];
    const float* Alg = (const float*)d_in[10];
    const float* dtb = (const float*)d_in[11];
    const float* wg  = (const float*)d_in[12];
    const float* onw = (const float*)d_in[13];
    const float* wo  = (const float*)d_in[14];
    const float* n2w = (const float*)d_in[15];
    const float* w1  = (const float*)d_in[16];
    const float* w2  = (const float*)d_in[17];
    const float* w3  = (const float*)d_in[18];

    if (ws_size < 114819072ULL) return;

    char* ws = (char*)d_ws;
    u16*   WcatT = (u16*)(ws + 0);            // [6272][1024] bf16 (CHW/CHM/CHQc reuse)
    u16*   WoT   = (u16*)(ws + 12845056);     // [1024][2048]
    u16*   W13T  = (u16*)(ws + 17039360);     // [5632][1024]
    u16*   W2T   = (u16*)(ws + 28573696);     // [1024][2816]
    u16*   hA    = (u16*)(ws + 34340864);     // [2048][1024] (h2A reuse)
    u16*   P     = (u16*)(ws + 38535168);     // [2048][6272] (U13 reuse)
    u16*   Qb    = (u16*)(ws + 64225280);     // [2048][1024] bf16 (Mm reuse)
    u16*   Kb    = (u16*)(ws + 68419584);     // [2048][1024] bf16
    u16*   Vb    = (u16*)(ws + 72613888);     // [2048][2048] bf16 (OG reuse)
    float* Gl    = (float*)(ws + 81002496);   // [2048][16] log decay
    float* Bbf   = (float*)(ws + 81133568);   // [2048][16]
    float* O     = (float*)(ws + 81264640);   // [2048][2048] fp32 (X2 reuse)
    u16*   CHKcT = (u16*)(ws + 98041856);     // [512][64][64] bf16 image
    u16*   CHU0T = (u16*)(ws + 102236160);    // [512][128][64] bf16 image
    float* CHcC  = (float*)(ws + 110624768);  // [512]
    u16*   CHW   = WcatT;                     // [512][64][64] image
    u16*   CHM   = (u16*)(ws + 4194304);
    u16*   CHQc  = (u16*)(ws + 8388608);
    u16*   U13 = P;
    u16*   Mm  = Qb;
    u16*   OG  = Vb;
    float* X2  = O;
    u16*   h2A = hA;

    const dim3 tb(32, 8);
    k_transpose<<<dim3(32, 32), tb, 0, stream>>>(wq, 1024, 1024, WcatT, 0, 1024);
    k_transpose<<<dim3(32, 32), tb, 0, stream>>>(wk, 1024, 1024, WcatT, 1024, 1024);
    k_transpose<<<dim3(64, 32), tb, 0, stream>>>(wv, 1024, 2048, WcatT, 2048, 2048);
    k_transpose<<<dim3(1, 32),  tb, 0, stream>>>(wb, 1024, 16,   WcatT, 4096, 16);
    k_transpose<<<dim3(1, 32),  tb, 0, stream>>>(wa, 1024, 16,   WcatT, 4112, 16);
    k_transpose<<<dim3(67, 32), tb, 0, stream>>>(wg, 1024, 2048, WcatT, 4128, 2144);
    k_transpose<<<dim3(32, 64), tb, 0, stream>>>(wo, 2048, 1024, WoT, 0, 1024);
    k_transpose<<<dim3(88, 32), tb, 0, stream>>>(w1, 1024, 2816, W13T, 0, 2816);
    k_transpose<<<dim3(88, 32), tb, 0, stream>>>(w3, 1024, 2816, W13T, 2816, 2816);
    k_transpose<<<dim3(32, 88), tb, 0, stream>>>(w2, 2816, 1024, W2T, 0, 1024);

    k_rmsnorm<<<2048, 256, 0, stream>>>(x, n1w, hA);
    k_gemm<128, 2><<<dim3(16, 49), 256, 0, stream>>>(hA, WcatT, P, nullptr, N1P, 1024);

    k_conv<<<2048, 256, 0, stream>>>(P, cq, ck, cv, Alg, dtb, Qb, Kb, Vb, Gl, Bbf);

    k_scan1<<<512, 256, 0, stream>>>(Qb, Kb, Vb, Gl, Bbf, CHW, CHM, CHQc, CHKcT, CHU0T, CHcC);
    k_scan2<<<64, 256, 0, stream>>>(CHW, CHM, CHQc, CHKcT, CHU0T, CHcC, O);

    k_gate<<<2048, 256, 0, stream>>>(O, P, onw, OG);
    k_gemm<64, 1><<<dim3(32, 16), 256, 0, stream>>>(OG, WoT, X2, x, 1024, 2048);

    k_rmsnorm<<<2048, 256, 0, stream>>>(X2, n2w, h2A);
    k_gemm<128, 2><<<dim3(16, 44), 256, 0, stream>>>(h2A, W13T, U13, nullptr, 5632, 1024);
    k_silumul<<<5632, 256, 0, stream>>>(U13, Mm);
    k_gemm<64, 1><<<dim3(32, 16), 256, 0, stream>>>(Mm, W2T, (float*)d_out, X2, 1024, 2816);
}

// Round 6
// 275.823 us; speedup vs baseline: 3.0635x; 1.0773x over previous
//
#include <hip/hip_runtime.h>
#include <stdint.h>

typedef unsigned short u16;
typedef float f32x4 __attribute__((ext_vector_type(4)));
typedef __bf16 bf16x8 __attribute__((ext_vector_type(8)));
typedef unsigned short u16x8 __attribute__((ext_vector_type(8)));

#define N1P 6272   // padded concat width: q(1024)|k(1024)|v(2048)|b(16)|a(16)|g(2048)|pad(96)

__device__ __forceinline__ u16 f2bf(float f) {
    union { float f; uint32_t u; } v; v.f = f;
    uint32_t u = v.u;
    return (u16)((u + 0x7FFFu + ((u >> 16) & 1u)) >> 16);
}
__device__ __forceinline__ float bf2f(u16 h) {
    union { uint32_t u; float f; } v; v.u = ((uint32_t)h) << 16; return v.f;
}
__device__ __forceinline__ float sigm(float x) { return 1.f / (1.f + __expf(-x)); }

__device__ __forceinline__ void async16(const u16* g, u16* l) {
    __builtin_amdgcn_global_load_lds((const __attribute__((address_space(1))) void*)g,
                                     (__attribute__((address_space(3))) void*)l, 16, 0, 0);
}

// byte offset inside a [R][64] bf16 "swizzled image": 16B units XOR'd with row&7
__device__ __forceinline__ int swz64(int row, int col) {
    return row * 128 + ((((col >> 3) ^ (row & 7)) << 3) + (col & 7)) * 2;
}
// MFMA fragment read from a swizzled [R][64] bf16 image (rows rowbase..rowbase+15, K-offset kk*32)
__device__ __forceinline__ bf16x8 frag64(const u16* m, int rowbase, int lane, int kk) {
    const int row = rowbase + (lane & 15);
    const int unit = (lane >> 4) + (kk << 2);
    return *(const bf16x8*)((const char*)m + row * 128 + ((unit ^ (row & 7)) << 4));
}

// ---------------- fused transpose + fp32->bf16 convert (all 10 weight matrices, one launch)
struct TJob { const float* src; u16* dst; int rows, cols, rowOff, nOut, blkBase, gx; };
struct TJobs { TJob j[10]; };

__global__ __launch_bounds__(256) void k_transpose_all(TJobs jobs, int njobs) {
    __shared__ float tile[32][33];
    const int bid = blockIdx.x;
    int ji = 0;
#pragma unroll
    for (int i = 1; i < 10; ++i)
        if (i < njobs && bid >= jobs.j[i].blkBase) ji = i;
    const TJob J = jobs.j[ji];
    const int bx = bid - J.blkBase;
    const int n0 = (bx % J.gx) * 32, k0 = (bx / J.gx) * 32;
    const int tx = threadIdx.x, ty = threadIdx.y;  // 32x8
#pragma unroll
    for (int j = 0; j < 32; j += 8) {
        int r = k0 + ty + j, c = n0 + tx;
        tile[ty + j][tx] = (r < J.rows && c < J.cols) ? J.src[(size_t)r * J.cols + c] : 0.f;
    }
    __syncthreads();
#pragma unroll
    for (int j = 0; j < 32; j += 8) {
        int n = n0 + ty + j, k = k0 + tx;
        if (n < J.nOut) J.dst[(size_t)(J.rowOff + n) * J.rows + k] = f2bf(tile[tx][ty + j]);
    }
}

// ---------------- rmsnorm over D=1024, fp32 in -> bf16 out
__global__ __launch_bounds__(256) void k_rmsnorm(const float* __restrict__ x, const float* __restrict__ w,
                                                 u16* __restrict__ out) {
    const int row = blockIdx.x, tid = threadIdx.x, lane = tid & 63, wave = tid >> 6;
    const float4 v = ((const float4*)(x + (size_t)row * 1024))[tid];
    float ss = v.x * v.x + v.y * v.y + v.z * v.z + v.w * v.w;
#pragma unroll
    for (int o = 1; o < 64; o <<= 1) ss += __shfl_xor(ss, o);
    __shared__ float sred[4];
    if (lane == 0) sred[wave] = ss;
    __syncthreads();
    const float tot = sred[0] + sred[1] + sred[2] + sred[3];
    const float rn = rsqrtf(tot * (1.f / 1024.f) + 1e-6f);
    const float4 wv = ((const float4*)w)[tid];
    uint2 pk;
    pk.x = (uint32_t)f2bf(v.x * rn * wv.x) | ((uint32_t)f2bf(v.y * rn * wv.y) << 16);
    pk.y = (uint32_t)f2bf(v.z * rn * wv.z) | ((uint32_t)f2bf(v.w * rn * wv.w) << 16);
    *(uint2*)&out[(size_t)row * 1024 + tid * 4] = pk;
}

// ---------------- bf16 GEMM, A[M][K] row-major, Bt[N][K] row-major, BK=64, swizzled LDS
// double-buffered, issue-early staging (T3-minimum 2-phase)
// TILE in {64,128}; EPI: 0 = fp32 store, 1 = fp32 + residual, 2 = bf16 store
template <int TILE, int EPI>
__global__ __launch_bounds__(256) void k_gemm(const u16* __restrict__ A, const u16* __restrict__ Bt,
                                              void* __restrict__ Cout, const float* __restrict__ Res,
                                              int N, int Kd) {
    __shared__ __align__(16) u16 As[2][TILE * 64];
    __shared__ __align__(16) u16 Bs[2][TILE * 64];
    const int bm = blockIdx.x, bn = blockIdx.y;
    const int tid = threadIdx.x, lane = tid & 63, wave = tid >> 6;
    const int wm = wave >> 1, wn = wave & 1;
    constexpr int WS = TILE / 2;   // per-wave output span
    constexpr int FR = WS / 16;    // 16x16 frags per dim
    constexpr int IS = TILE / 32;  // async16 issues per matrix per K-step

    const int srow = wave * 8 + (lane >> 3);           // staging row (mod 32-group)
    const int scol = ((lane & 7) ^ (lane >> 3)) * 8;   // pre-swizzled source granule
    const u16* gA = A + (size_t)(bm * TILE + srow) * Kd + scol;
    const u16* gB = Bt + (size_t)(bn * TILE + srow) * Kd + scol;

    f32x4 acc[FR][FR] = {};
    const int NT = Kd >> 6;

    // prologue: stage tile 0 into buf 0
#pragma unroll
    for (int j = 0; j < IS; ++j) {
        async16(gA + (size_t)j * 32 * Kd, &As[0][j * 2048 + wave * 512]);
        async16(gB + (size_t)j * 32 * Kd, &Bs[0][j * 2048 + wave * 512]);
    }
    asm volatile("s_waitcnt vmcnt(0)" ::: "memory");
    __syncthreads();

    int buf = 0;
    for (int t = 0; t < NT; ++t) {
        if (t + 1 < NT) {                              // issue next-tile loads EARLY
            const int k0 = (t + 1) << 6;
#pragma unroll
            for (int j = 0; j < IS; ++j) {
                async16(gA + (size_t)j * 32 * Kd + k0, &As[buf ^ 1][j * 2048 + wave * 512]);
                async16(gB + (size_t)j * 32 * Kd + k0, &Bs[buf ^ 1][j * 2048 + wave * 512]);
            }
        }
#pragma unroll
        for (int kk = 0; kk < 2; ++kk) {               // compute current buffer
            bf16x8 af[FR], bfr[FR];
#pragma unroll
            for (int mi = 0; mi < FR; ++mi) af[mi] = frag64(As[buf], wm * WS + mi * 16, lane, kk);
#pragma unroll
            for (int ni = 0; ni < FR; ++ni) bfr[ni] = frag64(Bs[buf], wn * WS + ni * 16, lane, kk);
#pragma unroll
            for (int mi = 0; mi < FR; ++mi)
#pragma unroll
                for (int ni = 0; ni < FR; ++ni)
                    acc[mi][ni] = __builtin_amdgcn_mfma_f32_16x16x32_bf16(af[mi], bfr[ni], acc[mi][ni], 0, 0, 0);
        }
        asm volatile("s_waitcnt vmcnt(0)" ::: "memory");   // next-tile loads landed (hidden under MFMA)
        __syncthreads();                                   // + everyone done reading buf
        buf ^= 1;
    }

    const int crow0 = bm * TILE + wm * WS;
    const int ccol0 = bn * TILE + wn * WS;
    const int rsub = (lane >> 4) * 4;
    const int csub = lane & 15;
#pragma unroll
    for (int mi = 0; mi < FR; ++mi)
#pragma unroll
        for (int ni = 0; ni < FR; ++ni) {
            const int c = ccol0 + ni * 16 + csub;
#pragma unroll
            for (int r = 0; r < 4; ++r) {
                const int rr = crow0 + mi * 16 + rsub + r;
                float v = acc[mi][ni][r];
                if (EPI == 2) {
                    ((u16*)Cout)[(size_t)rr * N + c] = f2bf(v);
                } else {
                    if (EPI == 1) v += Res[(size_t)rr * N + c];
                    ((float*)Cout)[(size_t)rr * N + c] = v;
                }
            }
        }
}

// ---------------- depthwise causal conv(4) + silu + l2norm(q,k) + beta / log-decay
__global__ __launch_bounds__(256) void k_conv(const u16* __restrict__ P, const float* __restrict__ cwq,
                                              const float* __restrict__ cwk, const float* __restrict__ cwv,
                                              const float* __restrict__ A_log, const float* __restrict__ dtb,
                                              u16* __restrict__ Qb, u16* __restrict__ Kb,
                                              u16* __restrict__ Vb, float* __restrict__ Gl,
                                              float* __restrict__ Bbuf) {
    const int row = blockIdx.x;  // b*1024 + t
    const int t = row & 1023;
    const int tid = threadIdx.x;
    const long prow = (long)row * N1P;
#pragma unroll
    for (int p = 0; p < 16; ++p) {
        const int c = p * 256 + tid;
        float xv[4];
#pragma unroll
        for (int j = 0; j < 4; ++j) {
            const int tt = t - 3 + j;
            xv[j] = (tt >= 0) ? bf2f(P[prow + (long)(j - 3) * N1P + c]) : 0.f;
        }
        const float4 w = (c < 1024) ? ((const float4*)cwq)[c]
                         : (c < 2048) ? ((const float4*)cwk)[c - 1024]
                                      : ((const float4*)cwv)[c - 2048];
        float y = xv[0] * w.x + xv[1] * w.y + xv[2] * w.z + xv[3] * w.w;
        y = y * sigm(y);
        if (c < 2048) {
            float ss = y * y;
#pragma unroll
            for (int o = 1; o < 64; o <<= 1) ss += __shfl_xor(ss, o);
            const float rn = rsqrtf(ss + 1e-6f);
            if (c < 1024) Qb[(size_t)row * 1024 + c] = f2bf(y * rn * 0.125f);
            else          Kb[(size_t)row * 1024 + (c - 1024)] = f2bf(y * rn);
        } else {
            Vb[(size_t)row * 2048 + (c - 2048)] = f2bf(y);
        }
    }
    if (tid < 32) {
        const int h = tid & 15;
        const float val = bf2f(P[prow + 4096 + tid]);
        if (tid < 16) {
            Bbuf[(size_t)row * 16 + h] = sigm(val);
        } else {
            const float a = val + dtb[h];
            const float sp = (a > 15.f) ? a : log1pf(__expf(a));
            Gl[(size_t)row * 16 + h] = -__expf(A_log[h]) * sp;   // log decay
        }
    }
}

// ---------------- chunked gated delta rule: stage 1 (per b,h,chunk — fully parallel)
// T = (I+A)^{-1} = (I+M0)(I+M1)...(I+M5), M0 = -A, M_j = M_{j-1}^2 (exact, A nilpotent)
__global__ __launch_bounds__(256) void k_scan1(
    const u16* __restrict__ Qb, const u16* __restrict__ Kb, const u16* __restrict__ Vb,
    const float* __restrict__ Gl, const float* __restrict__ Bb,
    u16* __restrict__ CHW, u16* __restrict__ CHM, u16* __restrict__ CHQc,
    u16* __restrict__ CHKcT, u16* __restrict__ CHU0T, float* __restrict__ CHcC) {
    __shared__ __align__(16) char sm[66048];
    u16* Ql   = (u16*)(sm);            // 8KB   (phase<=2a; then low half of fp32 T master)
    u16* Kl   = (u16*)(sm + 8192);     // 8KB   (phase<=2a; then high half of T master)
    u16* VTb  = (u16*)(sm + 16384);    // 16KB
    u16* KT1b = (u16*)(sm + 32768);    // 8KB
    u16* Mim  = (u16*)(sm + 40960);    // 8KB   M_j image (in-place squared)
    u16* MTim = (u16*)(sm + 49152);    // 8KB   M_j^T image
    u16* Tb   = (u16*)(sm + 57344);    // 8KB   bf16 T image (per-wave-owned rows)
    float* Tl    = (float*)sm;         // 16KB fp32 T master, overlays Ql+Kl after 2a
    float* gcs   = (float*)(sm + 65536);
    float* betal = (float*)(sm + 65792);

    const int blk = blockIdx.x;                      // bb*256 + h*16 + ch
    const int bb = blk >> 8, h = (blk >> 4) & 15, ch = blk & 15;
    const int bhc = blk;
    const int tid = threadIdx.x, lane = tid & 63, wave = tid >> 6;
    const long rowbase = (long)bb * 1024 + ch * 64;

    // phase 0: stage K,Q swizzled; load per-row gate scalars
    if (tid < 64) {
        gcs[tid] = Gl[(rowbase + tid) * 16 + h];
        betal[tid] = Bb[(rowbase + tid) * 16 + h];
    }
    for (int u = tid; u < 512; u += 256) {
        int r = u >> 3, c8 = u & 7;
        uint4 kv = *(const uint4*)&Kb[(rowbase + r) * 1024 + h * 64 + c8 * 8];
        uint4 qv = *(const uint4*)&Qb[(rowbase + r) * 1024 + h * 64 + c8 * 8];
        int b = r * 128 + ((c8 ^ (r & 7)) << 4);
        *(uint4*)((char*)Kl + b) = kv;
        *(uint4*)((char*)Ql + b) = qv;
    }
    __syncthreads();
    // phase 1: cumsum (wave 0); VTb build; QK^T / KK^T
    if (wave == 0) {
        float g = gcs[lane];
#pragma unroll
        for (int off = 1; off < 64; off <<= 1) {
            float n = __shfl_up(g, off, 64);
            if (lane >= off) g += n;
        }
        gcs[lane] = g;
    }
    for (int u = tid; u < 1024; u += 256) {          // VTb[dv][c] = beta_c * V[c][dv]
        int r = u >> 4, c8 = u & 15;
        u16x8 vv = *(const u16x8*)&Vb[(rowbase + r) * 2048 + h * 128 + c8 * 8];
        float bsc = betal[r];
#pragma unroll
        for (int j = 0; j < 8; ++j) {
            int dv = c8 * 8 + j;
            *(u16*)((char*)VTb + swz64(dv, r)) = f2bf(bf2f(vv[j]) * bsc);
        }
    }
    f32x4 aQK[4] = {}, aKK[4] = {};
#pragma unroll
    for (int nt = 0; nt < 4; ++nt)
#pragma unroll
        for (int kk = 0; kk < 2; ++kk) {
            bf16x8 bq = frag64(Kl, nt * 16, lane, kk);
            aQK[nt] = __builtin_amdgcn_mfma_f32_16x16x32_bf16(frag64(Ql, wave * 16, lane, kk), bq, aQK[nt], 0, 0, 0);
            aKK[nt] = __builtin_amdgcn_mfma_f32_16x16x32_bf16(frag64(Kl, wave * 16, lane, kk), bq, aKK[nt], 0, 0, 0);
        }
    __syncthreads();   // gcs + VTb published

    // phase 2a: CHM, M0 = -A images, CHQc, KT1b, CHKcT (reads Ql/Kl)
    const float gcsC = gcs[63];
    float am[4][4];    // keep -A values for phase 2b
#pragma unroll
    for (int nt = 0; nt < 4; ++nt)
#pragma unroll
        for (int reg = 0; reg < 4; ++reg) {
            int t = wave * 16 + ((lane >> 4) << 2) + reg;
            int i = nt * 16 + (lane & 15);
            float dec = __expf(gcs[t] - gcs[i]);
            float mv = (i <= t) ? dec * aQK[nt][reg] : 0.f;
            *(u16*)((char*)CHM + (size_t)bhc * 8192 + swz64(t, i)) = f2bf(mv);
            float a = (i < t) ? betal[t] * dec * aKK[nt][reg] : 0.f;
            am[nt][reg] = -a;
            u16 amb = f2bf(-a);
            *(u16*)((char*)Mim + swz64(t, i)) = amb;
            *(u16*)((char*)MTim + swz64(i, t)) = amb;
        }
    for (int e = tid; e < 4096; e += 256) {
        int r = e >> 6, c = e & 63;
        int ib = swz64(r, c);
        float qv = bf2f(*(const u16*)((const char*)Ql + ib)) * __expf(gcs[r]);
        *(u16*)((char*)CHQc + (size_t)bhc * 8192 + ib) = f2bf(qv);
        float kv = bf2f(*(const u16*)((const char*)Kl + ib));
        int ob = swz64(c, r);
        *(u16*)((char*)KT1b + ob) = f2bf(kv * betal[r] * __expf(gcs[r]));
        *(u16*)((char*)CHKcT + (size_t)bhc * 8192 + ob) = f2bf(kv * __expf(gcsC - gcs[r]));
    }
    if (tid == 0) CHcC[bhc] = __expf(gcsC);
    __syncthreads();   // Ql/Kl dead; Tl overlay becomes safe

    // phase 2b: T0 = I + M0 = I - A  (fp32 master + bf16 image, own rows)
#pragma unroll
    for (int nt = 0; nt < 4; ++nt)
#pragma unroll
        for (int reg = 0; reg < 4; ++reg) {
            int t = wave * 16 + ((lane >> 4) << 2) + reg;
            int i = nt * 16 + (lane & 15);
            float tv = (t == i) ? 1.f : am[nt][reg];
            Tl[t * 64 + i] = tv;
            *(u16*)((char*)Tb + swz64(t, i)) = f2bf(tv);
        }
    __syncthreads();

    // phase 3: doubling. stage j: M <- M^2 (in place), then T <- T + T*M.
    const int hi = wave * 16 + 15;
#pragma unroll
    for (int j = 1; j <= 5; ++j) {
        // square M (read Mim own rows as A-op, MTim all rows as B-op)
        f32x4 aM[4] = {};
#pragma unroll
        for (int nt = 0; nt < 4; ++nt) {
            if (nt * 16 > hi - (1 << j)) continue;
#pragma unroll
            for (int kk = 0; kk < 2; ++kk) {
                if (kk * 32 > hi) break;
                aM[nt] = __builtin_amdgcn_mfma_f32_16x16x32_bf16(
                    frag64(Mim, wave * 16, lane, kk), frag64(MTim, nt * 16, lane, kk), aM[nt], 0, 0, 0);
            }
        }
        __syncthreads();   // all reads of M_{j-1} done
        // write M_j in place (ALL entries — masked zeros, no stale data)
#pragma unroll
        for (int nt = 0; nt < 4; ++nt)
#pragma unroll
            for (int reg = 0; reg < 4; ++reg) {
                int t = wave * 16 + ((lane >> 4) << 2) + reg;
                int i = nt * 16 + (lane & 15);
                float mv = (t - i >= (1 << j)) ? aM[nt][reg] : 0.f;
                u16 mb = f2bf(mv);
                *(u16*)((char*)Mim + swz64(t, i)) = mb;
                *(u16*)((char*)MTim + swz64(i, t)) = mb;
            }
        __syncthreads();   // M_j published
        // T update: aT = T (fp32 master) + T*M_j ; own rows only -> no barrier needed after
        f32x4 aT[4];
#pragma unroll
        for (int nt = 0; nt < 4; ++nt)
#pragma unroll
            for (int reg = 0; reg < 4; ++reg) {
                int t = wave * 16 + ((lane >> 4) << 2) + reg;
                int i = nt * 16 + (lane & 15);
                aT[nt][reg] = Tl[t * 64 + i];
            }
#pragma unroll
        for (int nt = 0; nt < 4; ++nt) {
            if (nt * 16 > hi - (1 << j)) continue;
#pragma unroll
            for (int kk = 0; kk < 2; ++kk) {
                if (kk * 32 > hi) break;
                aT[nt] = __builtin_amdgcn_mfma_f32_16x16x32_bf16(
                    frag64(Tb, wave * 16, lane, kk), frag64(MTim, nt * 16, lane, kk), aT[nt], 0, 0, 0);
            }
        }
#pragma unroll
        for (int nt = 0; nt < 4; ++nt)
#pragma unroll
            for (int reg = 0; reg < 4; ++reg) {
                int t = wave * 16 + ((lane >> 4) << 2) + reg;
                int i = nt * 16 + (lane & 15);
                Tl[t * 64 + i] = aT[nt][reg];
                *(u16*)((char*)Tb + swz64(t, i)) = f2bf(aT[nt][reg]);
            }
    }
    __syncthreads();   // U0T below reads other waves' Tb rows

    // final: W = T @ (beta*c*K);  U0T = (beta*V)^T @ T^T
    {
        f32x4 aW[4] = {};
#pragma unroll
        for (int nt = 0; nt < 4; ++nt)
#pragma unroll
            for (int kk = 0; kk < 2; ++kk) {
                if (kk * 32 > hi) break;   // T[t][k] zero for k > t
                aW[nt] = __builtin_amdgcn_mfma_f32_16x16x32_bf16(
                    frag64(Tb, wave * 16, lane, kk), frag64(KT1b, nt * 16, lane, kk), aW[nt], 0, 0, 0);
            }
#pragma unroll
        for (int nt = 0; nt < 4; ++nt)
#pragma unroll
            for (int reg = 0; reg < 4; ++reg) {
                int r = wave * 16 + ((lane >> 4) << 2) + reg;
                int c = nt * 16 + (lane & 15);
                *(u16*)((char*)CHW + (size_t)bhc * 8192 + swz64(r, c)) = f2bf(aW[nt][reg]);
            }
    }
#pragma unroll
    for (int rt = 0; rt < 2; ++rt) {
        f32x4 aU[4] = {};
        int rb = (wave * 2 + rt) * 16;
#pragma unroll
        for (int nt = 0; nt < 4; ++nt)
#pragma unroll
            for (int kk = 0; kk < 2; ++kk) {
                if (kk * 32 > nt * 16 + 15) continue;  // T[c][k] zero for k > c
                aU[nt] = __builtin_amdgcn_mfma_f32_16x16x32_bf16(
                    frag64(VTb, rb, lane, kk), frag64(Tb, nt * 16, lane, kk), aU[nt], 0, 0, 0);
            }
#pragma unroll
        for (int nt = 0; nt < 4; ++nt)
#pragma unroll
            for (int reg = 0; reg < 4; ++reg) {
                int dv = rb + ((lane >> 4) << 2) + reg;
                int c = nt * 16 + (lane & 15);
                *(u16*)((char*)CHU0T + (size_t)bhc * 16384 + swz64(dv, c)) = f2bf(aU[nt][reg]);
            }
    }
}

// ---------------- chunked gated delta rule: stage 2 (sequential over 16 chunks; block = b,h,dv-half)
__global__ __launch_bounds__(256) void k_scan2(
    const u16* __restrict__ CHW, const u16* __restrict__ CHM, const u16* __restrict__ CHQc,
    const u16* __restrict__ CHKcT, const u16* __restrict__ CHU0T, const float* __restrict__ CHcC,
    float* __restrict__ O) {
    __shared__ __align__(16) u16 stg[2][5 * 4096];
    __shared__ __align__(16) u16 STb[4096], uTl[4096];
    __shared__ float ST[64 * 66];
    const int blk = blockIdx.x;
    const int bb = blk >> 5, h = (blk >> 1) & 15, dvh = blk & 1;
    const int bh = bb * 16 + h;
    const int tid = threadIdx.x, lane = tid & 63, wave = tid >> 6;

    for (int e = tid; e < 64 * 66; e += 256) ST[e] = 0.f;
    for (int e = tid; e < 4096; e += 256) STb[e] = 0;

    auto stage = [&](int buf, int ch) {
        const size_t base = (size_t)(bh * 16 + ch);
        const u16* srcs[5] = { CHW + base * 4096, CHM + base * 4096, CHQc + base * 4096,
                               CHKcT + base * 4096, CHU0T + base * 8192 + dvh * 4096 };
#pragma unroll
        for (int s = 0; s < 5; ++s)
#pragma unroll
            for (int r = 0; r < 2; ++r) {
                int ub = r * 256 + wave * 64;
                async16(srcs[s] + (size_t)(ub + lane) * 8, &stg[buf][s * 4096 + ub * 8]);
            }
    };
    stage(0, 0);
    for (int ch = 0; ch < 16; ++ch) {
        const int cur = ch & 1;
        asm volatile("s_waitcnt vmcnt(0)" ::: "memory");
        __syncthreads();
        if (ch < 15) stage(cur ^ 1, ch + 1);
        const u16* sW = &stg[cur][0];
        const u16* sM = &stg[cur][4096];
        const u16* sQc = &stg[cur][8192];
        const u16* sKcT = &stg[cur][12288];
        const u16* sU0 = &stg[cur][16384];
        // phase A: uT = U0T - (S0 W^T)    [rows dv]
        {
            f32x4 acc[4] = {};
#pragma unroll
            for (int nt = 0; nt < 4; ++nt)
#pragma unroll
                for (int kk = 0; kk < 2; ++kk)
                    acc[nt] = __builtin_amdgcn_mfma_f32_16x16x32_bf16(
                        frag64(STb, wave * 16, lane, kk), frag64(sW, nt * 16, lane, kk), acc[nt], 0, 0, 0);
#pragma unroll
            for (int nt = 0; nt < 4; ++nt)
#pragma unroll
                for (int reg = 0; reg < 4; ++reg) {
                    int dv = wave * 16 + ((lane >> 4) << 2) + reg;
                    int c = nt * 16 + (lane & 15);
                    int b = swz64(dv, c);
                    float u0 = bf2f(*(const u16*)((const char*)sU0 + b));
                    *(u16*)((char*)uTl + b) = f2bf(u0 - acc[nt][reg]);
                }
        }
        __syncthreads();
        // phase B: O = M@u + Qc@S0 (rows c); Sacc = u^T-rows-dv @ KcT (rows dv)
        f32x4 accO[4] = {}, accS[4] = {};
#pragma unroll
        for (int nt = 0; nt < 4; ++nt)
#pragma unroll
            for (int kk = 0; kk < 2; ++kk) {
                accO[nt] = __builtin_amdgcn_mfma_f32_16x16x32_bf16(
                    frag64(sM, wave * 16, lane, kk), frag64(uTl, nt * 16, lane, kk), accO[nt], 0, 0, 0);
                accO[nt] = __builtin_amdgcn_mfma_f32_16x16x32_bf16(
                    frag64(sQc, wave * 16, lane, kk), frag64(STb, nt * 16, lane, kk), accO[nt], 0, 0, 0);
                accS[nt] = __builtin_amdgcn_mfma_f32_16x16x32_bf16(
                    frag64(uTl, wave * 16, lane, kk), frag64(sKcT, nt * 16, lane, kk), accS[nt], 0, 0, 0);
            }
        __syncthreads();
        // phase C: write O; update state
        const float cC = CHcC[bh * 16 + ch];
#pragma unroll
        for (int nt = 0; nt < 4; ++nt)
#pragma unroll
            for (int reg = 0; reg < 4; ++reg) {
                int rr = wave * 16 + ((lane >> 4) << 2) + reg;
                int cc = nt * 16 + (lane & 15);
                O[((size_t)(bb * 1024 + ch * 64 + rr)) * 2048 + h * 128 + dvh * 64 + cc] = accO[nt][reg];
                float ns = cC * ST[rr * 66 + cc] + accS[nt][reg];
                ST[rr * 66 + cc] = ns;
                *(u16*)((char*)STb + swz64(rr, cc)) = f2bf(ns);
            }
    }
}

// ---------------- per-head RMSNorm(o) * gate * sigmoid(gate) -> bf16
__global__ __launch_bounds__(256) void k_gate(const float* __restrict__ O, const u16* __restrict__ P,
                                              const float* __restrict__ onw, u16* __restrict__ OG) {
    const int row = blockIdx.x;
    const int tid = threadIdx.x, lane = tid & 63, wave = tid >> 6;
#pragma unroll
    for (int p = 0; p < 4; ++p) {
        const int h = p * 4 + wave;
        const int dv = lane * 2;
        const float2 o2 = *(const float2*)&O[(size_t)row * 2048 + h * 128 + dv];
        float ss = o2.x * o2.x + o2.y * o2.y;
#pragma unroll
        for (int o = 1; o < 64; o <<= 1) ss += __shfl_xor(ss, o);
        const float rn = rsqrtf(ss * (1.f / 128.f) + 1e-6f);
        const float g0 = bf2f(P[(size_t)row * N1P + 4128 + h * 128 + dv]);
        const float g1 = bf2f(P[(size_t)row * N1P + 4128 + h * 128 + dv + 1]);
        const float r0 = o2.x * rn * onw[dv] * g0 * sigm(g0);
        const float r1 = o2.y * rn * onw[dv + 1] * g1 * sigm(g1);
        const uint32_t pk = (uint32_t)f2bf(r0) | ((uint32_t)f2bf(r1) << 16);
        *(uint32_t*)&OG[(size_t)row * 2048 + h * 128 + dv] = pk;
    }
}

// ---------------- silu(u1) * u3 -> bf16
__global__ __launch_bounds__(256) void k_silumul(const u16* __restrict__ U13, u16* __restrict__ Mm) {
    const int idx = blockIdx.x * 256 + threadIdx.x;
    const int row = idx / 704, c4 = idx % 704;
    const size_t b1 = (size_t)row * 5632 + c4 * 4;
    const uint2 ua = *(const uint2*)&U13[b1];
    const uint2 ub = *(const uint2*)&U13[b1 + 2816];
    float a0 = bf2f(ua.x & 0xffff), a1 = bf2f(ua.x >> 16), a2 = bf2f(ua.y & 0xffff), a3 = bf2f(ua.y >> 16);
    float b0 = bf2f(ub.x & 0xffff), b1f = bf2f(ub.x >> 16), b2 = bf2f(ub.y & 0xffff), b3 = bf2f(ub.y >> 16);
    const float r0 = a0 * sigm(a0) * b0, r1 = a1 * sigm(a1) * b1f;
    const float r2 = a2 * sigm(a2) * b2, r3 = a3 * sigm(a3) * b3;
    uint2 pk;
    pk.x = (uint32_t)f2bf(r0) | ((uint32_t)f2bf(r1) << 16);
    pk.y = (uint32_t)f2bf(r2) | ((uint32_t)f2bf(r3) << 16);
    *(uint2*)&Mm[(size_t)row * 2816 + c4 * 4] = pk;
}

extern "C" void kernel_launch(void* const* d_in, const int* in_sizes, int n_in,
                              void* d_out, int out_size, void* d_ws, size_t ws_size,
                              hipStream_t stream) {
    const float* x   = (const float*)d_in[0];
    const float* n1w = (const float*)d_in[1];
    const float* wq  = (const float*)d_in[2];
    const float* wk  = (const float*)d_in[3];
    const float* wv  = (const float*)d_in[4];
    const float* cq  = (const float*)d_in[5];
    const float* ck  = (const float*)d_in[6];
    const float* cv  = (const float*)d_in[7];
    const float* wb  = (const float*)d_in[8];
    const float* wa  = (const float*)d_in[9];
    const float* Alg = (const float*)d_in[10];
    const float* dtb = (const float*)d_in[11];
    const float* wg  = (const float*)d_in[12];
    const float* onw = (const float*)d_in[13];
    const float* wo  = (const float*)d_in[14];
    const float* n2w = (const float*)d_in[15];
    const float* w1  = (const float*)d_in[16];
    const float* w2  = (const float*)d_in[17];
    const float* w3  = (const float*)d_in[18];

    if (ws_size < 114819072ULL) return;

    char* ws = (char*)d_ws;
    u16*   WcatT = (u16*)(ws + 0);            // [6272][1024] bf16 (CHW/CHM/CHQc reuse)
    u16*   WoT   = (u16*)(ws + 12845056);     // [1024][2048]
    u16*   W13T  = (u16*)(ws + 17039360);     // [5632][1024]
    u16*   W2T   = (u16*)(ws + 28573696);     // [1024][2816]
    u16*   hA    = (u16*)(ws + 34340864);     // [2048][1024] (h2A reuse)
    u16*   P     = (u16*)(ws + 38535168);     // [2048][6272] (U13 reuse)
    u16*   Qb    = (u16*)(ws + 64225280);     // [2048][1024] bf16 (Mm reuse)
    u16*   Kb    = (u16*)(ws + 68419584);     // [2048][1024] bf16
    u16*   Vb    = (u16*)(ws + 72613888);     // [2048][2048] bf16 (OG reuse)
    float* Gl    = (float*)(ws + 81002496);   // [2048][16] log decay
    float* Bbf   = (float*)(ws + 81133568);   // [2048][16]
    float* O     = (float*)(ws + 81264640);   // [2048][2048] fp32 (X2 reuse)
    u16*   CHKcT = (u16*)(ws + 98041856);     // [512][64][64] bf16 image
    u16*   CHU0T = (u16*)(ws + 102236160);    // [512][128][64] bf16 image
    float* CHcC  = (float*)(ws + 110624768);  // [512]
    u16*   CHW   = WcatT;                     // [512][64][64] image
    u16*   CHM   = (u16*)(ws + 4194304);
    u16*   CHQc  = (u16*)(ws + 8388608);
    u16*   U13 = P;
    u16*   Mm  = Qb;
    u16*   OG  = Vb;
    float* X2  = O;
    u16*   h2A = hA;

    // fused weight transposes (fp32 [K][N] -> bf16 [N][K]) in one launch
    TJobs tj;
    tj.j[0] = { wq, WcatT, 1024, 1024,    0, 1024,     0, 32 };
    tj.j[1] = { wk, WcatT, 1024, 1024, 1024, 1024,  1024, 32 };
    tj.j[2] = { wv, WcatT, 1024, 2048, 2048, 2048,  2048, 64 };
    tj.j[3] = { wb, WcatT, 1024,   16, 4096,   16,  4096,  1 };
    tj.j[4] = { wa, WcatT, 1024,   16, 4112,   16,  4128,  1 };
    tj.j[5] = { wg, WcatT, 1024, 2048, 4128, 2144,  4160, 67 };
    tj.j[6] = { wo, WoT,   2048, 1024,    0, 1024,  6304, 32 };
    tj.j[7] = { w1, W13T,  1024, 2816,    0, 2816,  8352, 88 };
    tj.j[8] = { w3, W13T,  1024, 2816, 2816, 2816, 11168, 88 };
    tj.j[9] = { w2, W2T,   2816, 1024,    0, 1024, 13984, 32 };
    k_transpose_all<<<16800, dim3(32, 8), 0, stream>>>(tj, 10);

    k_rmsnorm<<<2048, 256, 0, stream>>>(x, n1w, hA);
    k_gemm<128, 2><<<dim3(16, 49), 256, 0, stream>>>(hA, WcatT, P, nullptr, N1P, 1024);

    k_conv<<<2048, 256, 0, stream>>>(P, cq, ck, cv, Alg, dtb, Qb, Kb, Vb, Gl, Bbf);

    k_scan1<<<512, 256, 0, stream>>>(Qb, Kb, Vb, Gl, Bbf, CHW, CHM, CHQc, CHKcT, CHU0T, CHcC);
    k_scan2<<<64, 256, 0, stream>>>(CHW, CHM, CHQc, CHKcT, CHU0T, CHcC, O);

    k_gate<<<2048, 256, 0, stream>>>(O, P, onw, OG);
    k_gemm<64, 1><<<dim3(32, 16), 256, 0, stream>>>(OG, WoT, X2, x, 1024, 2048);

    k_rmsnorm<<<2048, 256, 0, stream>>>(X2, n2w, h2A);
    k_gemm<128, 2><<<dim3(16, 44), 256, 0, stream>>>(h2A, W13T, U13, nullptr, 5632, 1024);
    k_silumul<<<5632, 256, 0, stream>>>(U13, Mm);
    k_gemm<64, 1><<<dim3(32, 16), 256, 0, stream>>>(Mm, W2T, (float*)d_out, X2, 1024, 2816);
}

// Round 7
// 263.031 us; speedup vs baseline: 3.2124x; 1.0486x over previous
//
#include <hip/hip_runtime.h>
#include <stdint.h>

typedef unsigned short u16;
typedef float f32x4 __attribute__((ext_vector_type(4)));
typedef __bf16 bf16x8 __attribute__((ext_vector_type(8)));
typedef unsigned short u16x8 __attribute__((ext_vector_type(8)));

#define N1P 6272   // padded concat width: q(1024)|k(1024)|v(2048)|b(16)|a(16)|g(2048)|pad(96)

__device__ __forceinline__ u16 f2bf(float f) {
    union { float f; uint32_t u; } v; v.f = f;
    uint32_t u = v.u;
    return (u16)((u + 0x7FFFu + ((u >> 16) & 1u)) >> 16);
}
__device__ __forceinline__ float bf2f(u16 h) {
    union { uint32_t u; float f; } v; v.u = ((uint32_t)h) << 16; return v.f;
}
__device__ __forceinline__ float sigm(float x) { return 1.f / (1.f + __expf(-x)); }

__device__ __forceinline__ void async16(const u16* g, u16* l) {
    __builtin_amdgcn_global_load_lds((const __attribute__((address_space(1))) void*)g,
                                     (__attribute__((address_space(3))) void*)l, 16, 0, 0);
}

// byte offset inside a [R][64] bf16 "swizzled image": 16B units XOR'd with row&7
__device__ __forceinline__ int swz64(int row, int col) {
    return row * 128 + ((((col >> 3) ^ (row & 7)) << 3) + (col & 7)) * 2;
}
// MFMA fragment read from a swizzled [R][64] bf16 image (rows rowbase..rowbase+15, K-offset kk*32)
__device__ __forceinline__ bf16x8 frag64(const u16* m, int rowbase, int lane, int kk) {
    const int row = rowbase + (lane & 15);
    const int unit = (lane >> 4) + (kk << 2);
    return *(const bf16x8*)((const char*)m + row * 128 + ((unit ^ (row & 7)) << 4));
}

// ---------------- fused transpose + fp32->bf16 convert (all 10 weight matrices, one launch)
struct TJob { const float* src; u16* dst; int rows, cols, rowOff, nOut, blkBase, gx; };
struct TJobs { TJob j[10]; };

__global__ __launch_bounds__(256) void k_transpose_all(TJobs jobs, int njobs) {
    __shared__ float tile[32][33];
    const int bid = blockIdx.x;
    int ji = 0;
#pragma unroll
    for (int i = 1; i < 10; ++i)
        if (i < njobs && bid >= jobs.j[i].blkBase) ji = i;
    const TJob J = jobs.j[ji];
    const int bx = bid - J.blkBase;
    const int n0 = (bx % J.gx) * 32, k0 = (bx / J.gx) * 32;
    const int tx = threadIdx.x, ty = threadIdx.y;  // 32x8
#pragma unroll
    for (int j = 0; j < 32; j += 8) {
        int r = k0 + ty + j, c = n0 + tx;
        tile[ty + j][tx] = (r < J.rows && c < J.cols) ? J.src[(size_t)r * J.cols + c] : 0.f;
    }
    __syncthreads();
#pragma unroll
    for (int j = 0; j < 32; j += 8) {
        int n = n0 + ty + j, k = k0 + tx;
        if (n < J.nOut) J.dst[(size_t)(J.rowOff + n) * J.rows + k] = f2bf(tile[tx][ty + j]);
    }
}

// ---------------- rmsnorm over D=1024, fp32 in -> bf16 out
__global__ __launch_bounds__(256) void k_rmsnorm(const float* __restrict__ x, const float* __restrict__ w,
                                                 u16* __restrict__ out) {
    const int row = blockIdx.x, tid = threadIdx.x, lane = tid & 63, wave = tid >> 6;
    const float4 v = ((const float4*)(x + (size_t)row * 1024))[tid];
    float ss = v.x * v.x + v.y * v.y + v.z * v.z + v.w * v.w;
#pragma unroll
    for (int o = 1; o < 64; o <<= 1) ss += __shfl_xor(ss, o);
    __shared__ float sred[4];
    if (lane == 0) sred[wave] = ss;
    __syncthreads();
    const float tot = sred[0] + sred[1] + sred[2] + sred[3];
    const float rn = rsqrtf(tot * (1.f / 1024.f) + 1e-6f);
    const float4 wv = ((const float4*)w)[tid];
    uint2 pk;
    pk.x = (uint32_t)f2bf(v.x * rn * wv.x) | ((uint32_t)f2bf(v.y * rn * wv.y) << 16);
    pk.y = (uint32_t)f2bf(v.z * rn * wv.z) | ((uint32_t)f2bf(v.w * rn * wv.w) << 16);
    *(uint2*)&out[(size_t)row * 1024 + tid * 4] = pk;
}

// ---------------- bf16 GEMM, A[M][K] row-major (M=2048), Bt[N][K] row-major, BK=64, swizzled LDS
// 8 waves (512 thr), double-buffered, issue-early staging, XCD-contiguous 1-D grid.
// TILE in {64,128}; EPI: 0 = fp32 store, 1 = fp32 + residual, 2 = bf16 store
template <int TILE, int EPI>
__global__ __launch_bounds__(512) void k_gemm(const u16* __restrict__ A, const u16* __restrict__ Bt,
                                              void* __restrict__ Cout, const float* __restrict__ Res,
                                              int N, int Kd) {
    __shared__ __align__(16) u16 As[2][TILE * 64];
    __shared__ __align__(16) u16 Bs[2][TILE * 64];
    constexpr int MB = 2048 / TILE;                  // block count along M (power of 2)
    const int q = (int)gridDim.x >> 3;               // grid divisible by 8
    const int bid = blockIdx.x;
    const int wg = (bid & 7) * q + (bid >> 3);       // XCD x owns contiguous wg chunk
    const int bm = wg & (MB - 1), bn = wg / MB;      // bm fastest -> B-panel locality per XCD
    const int tid = threadIdx.x, lane = tid & 63, wave = tid >> 6;
    const int wm = wave >> 2, wn = wave & 3;         // 2 x 4 wave grid
    constexpr int RS = TILE / 2, CS = TILE / 4;      // per-wave output span
    constexpr int FRM = RS / 16, FRN = CS / 16;
    constexpr int IS = TILE / 64;                    // issue rounds per matrix per K-step

    const int srow = wave * 8 + (lane >> 3);         // 0..63
    const int scol = ((lane & 7) ^ (lane >> 3)) * 8; // pre-swizzled source granule
    const u16* gA = A + (size_t)(bm * TILE + srow) * Kd + scol;
    const u16* gB = Bt + (size_t)(bn * TILE + srow) * Kd + scol;

    f32x4 acc[FRM][FRN] = {};
    const int NT = Kd >> 6;

    // prologue: stage tile 0 into buf 0
#pragma unroll
    for (int j = 0; j < IS; ++j) {
        async16(gA + (size_t)j * 64 * Kd, &As[0][j * 4096 + wave * 512]);
        async16(gB + (size_t)j * 64 * Kd, &Bs[0][j * 4096 + wave * 512]);
    }
    asm volatile("s_waitcnt vmcnt(0)" ::: "memory");
    __syncthreads();

    int buf = 0;
    for (int t = 0; t < NT; ++t) {
        if (t + 1 < NT) {                            // issue next-tile loads EARLY
            const int k0 = (t + 1) << 6;
#pragma unroll
            for (int j = 0; j < IS; ++j) {
                async16(gA + (size_t)j * 64 * Kd + k0, &As[buf ^ 1][j * 4096 + wave * 512]);
                async16(gB + (size_t)j * 64 * Kd + k0, &Bs[buf ^ 1][j * 4096 + wave * 512]);
            }
        }
#pragma unroll
        for (int kk = 0; kk < 2; ++kk) {             // compute current buffer
            bf16x8 af[FRM], bfr[FRN];
#pragma unroll
            for (int mi = 0; mi < FRM; ++mi) af[mi] = frag64(As[buf], wm * RS + mi * 16, lane, kk);
#pragma unroll
            for (int ni = 0; ni < FRN; ++ni) bfr[ni] = frag64(Bs[buf], wn * CS + ni * 16, lane, kk);
#pragma unroll
            for (int mi = 0; mi < FRM; ++mi)
#pragma unroll
                for (int ni = 0; ni < FRN; ++ni)
                    acc[mi][ni] = __builtin_amdgcn_mfma_f32_16x16x32_bf16(af[mi], bfr[ni], acc[mi][ni], 0, 0, 0);
        }
        asm volatile("s_waitcnt vmcnt(0)" ::: "memory");   // next-tile loads landed (hidden under MFMA)
        __syncthreads();
        buf ^= 1;
    }

    const int crow0 = bm * TILE + wm * RS;
    const int ccol0 = bn * TILE + wn * CS;
    const int rsub = (lane >> 4) * 4;
    const int csub = lane & 15;
#pragma unroll
    for (int mi = 0; mi < FRM; ++mi)
#pragma unroll
        for (int ni = 0; ni < FRN; ++ni) {
            const int c = ccol0 + ni * 16 + csub;
#pragma unroll
            for (int r = 0; r < 4; ++r) {
                const int rr = crow0 + mi * 16 + rsub + r;
                float v = acc[mi][ni][r];
                if (EPI == 2) {
                    ((u16*)Cout)[(size_t)rr * N + c] = f2bf(v);
                } else {
                    if (EPI == 1) v += Res[(size_t)rr * N + c];
                    ((float*)Cout)[(size_t)rr * N + c] = v;
                }
            }
        }
}

// ---------------- depthwise causal conv(4) + silu + l2norm(q,k) + beta / log-decay (vectorized x8)
__global__ __launch_bounds__(256) void k_conv(const u16* __restrict__ P, const float* __restrict__ cwq,
                                              const float* __restrict__ cwk, const float* __restrict__ cwv,
                                              const float* __restrict__ A_log, const float* __restrict__ dtb,
                                              u16* __restrict__ Qb, u16* __restrict__ Kb,
                                              u16* __restrict__ Vb, float* __restrict__ Gl,
                                              float* __restrict__ Bbuf) {
    const int row = blockIdx.x;  // b*1024 + t
    const int t = row & 1023;
    const int tid = threadIdx.x;
    const long prow = (long)row * N1P;
#pragma unroll
    for (int p = 0; p < 2; ++p) {
        const int g = p * 256 + tid;        // col-group of 8 (512 groups = 4096 cols)
        const int c = g * 8;
        u16x8 taps[4];
#pragma unroll
        for (int j = 0; j < 4; ++j) {
            const int tt = t - 3 + j;
            if (tt >= 0) taps[j] = *(const u16x8*)&P[prow + (long)(j - 3) * N1P + c];
            else         taps[j] = u16x8{};
        }
        const float* cw = (c < 1024) ? (cwq + c * 4)
                          : (c < 2048) ? (cwk + (c - 1024) * 4)
                                       : (cwv + (c - 2048) * 4);
        float y[8];
#pragma unroll
        for (int e = 0; e < 8; ++e) {
            const float4 w = ((const float4*)cw)[e];
            float v = bf2f(taps[0][e]) * w.x + bf2f(taps[1][e]) * w.y +
                      bf2f(taps[2][e]) * w.z + bf2f(taps[3][e]) * w.w;
            y[e] = v * sigm(v);
        }
        if (c < 2048) {
            float ss = 0.f;
#pragma unroll
            for (int e = 0; e < 8; ++e) ss += y[e] * y[e];
            ss += __shfl_xor(ss, 1); ss += __shfl_xor(ss, 2); ss += __shfl_xor(ss, 4);
            const float rn = rsqrtf(ss + 1e-6f);
            const float sc = (c < 1024) ? rn * 0.125f : rn;
            u16x8 o;
#pragma unroll
            for (int e = 0; e < 8; ++e) o[e] = f2bf(y[e] * sc);
            if (c < 1024) *(u16x8*)&Qb[(size_t)row * 1024 + c] = o;
            else          *(u16x8*)&Kb[(size_t)row * 1024 + (c - 1024)] = o;
        } else {
            u16x8 o;
#pragma unroll
            for (int e = 0; e < 8; ++e) o[e] = f2bf(y[e]);
            *(u16x8*)&Vb[(size_t)row * 2048 + (c - 2048)] = o;
        }
    }
    if (tid < 32) {
        const int h = tid & 15;
        const float val = bf2f(P[prow + 4096 + tid]);
        if (tid < 16) {
            Bbuf[(size_t)row * 16 + h] = sigm(val);
        } else {
            const float a = val + dtb[h];
            const float sp = (a > 15.f) ? a : log1pf(__expf(a));
            Gl[(size_t)row * 16 + h] = -__expf(A_log[h]) * sp;   // log decay
        }
    }
}

// ---------------- chunked gated delta rule: stage 1 (per b,h,chunk — fully parallel)
// T = (I+A)^{-1} = (I+M0)(I+M1)...(I+M5), M0 = -A, M_j = M_{j-1}^2 (exact, A nilpotent)
__global__ __launch_bounds__(256) void k_scan1(
    const u16* __restrict__ Qb, const u16* __restrict__ Kb, const u16* __restrict__ Vb,
    const float* __restrict__ Gl, const float* __restrict__ Bb,
    u16* __restrict__ CHW, u16* __restrict__ CHM, u16* __restrict__ CHQc,
    u16* __restrict__ CHKcT, u16* __restrict__ CHU0T, float* __restrict__ CHcC) {
    __shared__ __align__(16) char sm[66048];
    u16* Ql   = (u16*)(sm);            // 8KB   (phase<=2a; then low half of fp32 T master)
    u16* Kl   = (u16*)(sm + 8192);     // 8KB   (phase<=2a; then high half of T master)
    u16* VTb  = (u16*)(sm + 16384);    // 16KB
    u16* KT1b = (u16*)(sm + 32768);    // 8KB
    u16* Mim  = (u16*)(sm + 40960);    // 8KB   M_j image (in-place squared)
    u16* MTim = (u16*)(sm + 49152);    // 8KB   M_j^T image
    u16* Tb   = (u16*)(sm + 57344);    // 8KB   bf16 T image (per-wave-owned rows)
    float* Tl    = (float*)sm;         // 16KB fp32 T master, overlays Ql+Kl after 2a
    float* gcs   = (float*)(sm + 65536);
    float* betal = (float*)(sm + 65792);

    const int blk = blockIdx.x;                      // bb*256 + h*16 + ch
    const int bb = blk >> 8, h = (blk >> 4) & 15, ch = blk & 15;
    const int bhc = blk;
    const int tid = threadIdx.x, lane = tid & 63, wave = tid >> 6;
    const long rowbase = (long)bb * 1024 + ch * 64;

    // phase 0: stage K,Q swizzled; load per-row gate scalars
    if (tid < 64) {
        gcs[tid] = Gl[(rowbase + tid) * 16 + h];
        betal[tid] = Bb[(rowbase + tid) * 16 + h];
    }
    for (int u = tid; u < 512; u += 256) {
        int r = u >> 3, c8 = u & 7;
        uint4 kv = *(const uint4*)&Kb[(rowbase + r) * 1024 + h * 64 + c8 * 8];
        uint4 qv = *(const uint4*)&Qb[(rowbase + r) * 1024 + h * 64 + c8 * 8];
        int b = r * 128 + ((c8 ^ (r & 7)) << 4);
        *(uint4*)((char*)Kl + b) = kv;
        *(uint4*)((char*)Ql + b) = qv;
    }
    __syncthreads();
    // phase 1: cumsum (wave 0); VTb build; QK^T / KK^T
    if (wave == 0) {
        float g = gcs[lane];
#pragma unroll
        for (int off = 1; off < 64; off <<= 1) {
            float n = __shfl_up(g, off, 64);
            if (lane >= off) g += n;
        }
        gcs[lane] = g;
    }
    for (int u = tid; u < 1024; u += 256) {          // VTb[dv][c] = beta_c * V[c][dv]
        int r = u >> 4, c8 = u & 15;
        u16x8 vv = *(const u16x8*)&Vb[(rowbase + r) * 2048 + h * 128 + c8 * 8];
        float bsc = betal[r];
#pragma unroll
        for (int j = 0; j < 8; ++j) {
            int dv = c8 * 8 + j;
            *(u16*)((char*)VTb + swz64(dv, r)) = f2bf(bf2f(vv[j]) * bsc);
        }
    }
    f32x4 aQK[4] = {}, aKK[4] = {};
#pragma unroll
    for (int nt = 0; nt < 4; ++nt)
#pragma unroll
        for (int kk = 0; kk < 2; ++kk) {
            bf16x8 bq = frag64(Kl, nt * 16, lane, kk);
            aQK[nt] = __builtin_amdgcn_mfma_f32_16x16x32_bf16(frag64(Ql, wave * 16, lane, kk), bq, aQK[nt], 0, 0, 0);
            aKK[nt] = __builtin_amdgcn_mfma_f32_16x16x32_bf16(frag64(Kl, wave * 16, lane, kk), bq, aKK[nt], 0, 0, 0);
        }
    __syncthreads();   // gcs + VTb published

    // phase 2a: CHM, M0 = -A images, CHQc, KT1b, CHKcT (reads Ql/Kl)
    const float gcsC = gcs[63];
    float am[4][4];    // keep -A values for phase 2b
#pragma unroll
    for (int nt = 0; nt < 4; ++nt)
#pragma unroll
        for (int reg = 0; reg < 4; ++reg) {
            int t = wave * 16 + ((lane >> 4) << 2) + reg;
            int i = nt * 16 + (lane & 15);
            float dec = __expf(gcs[t] - gcs[i]);
            float mv = (i <= t) ? dec * aQK[nt][reg] : 0.f;
            *(u16*)((char*)CHM + (size_t)bhc * 8192 + swz64(t, i)) = f2bf(mv);
            float a = (i < t) ? betal[t] * dec * aKK[nt][reg] : 0.f;
            am[nt][reg] = -a;
            u16 amb = f2bf(-a);
            *(u16*)((char*)Mim + swz64(t, i)) = amb;
            *(u16*)((char*)MTim + swz64(i, t)) = amb;
        }
    for (int e = tid; e < 4096; e += 256) {
        int r = e >> 6, c = e & 63;
        int ib = swz64(r, c);
        float qv = bf2f(*(const u16*)((const char*)Ql + ib)) * __expf(gcs[r]);
        *(u16*)((char*)CHQc + (size_t)bhc * 8192 + ib) = f2bf(qv);
        float kv = bf2f(*(const u16*)((const char*)Kl + ib));
        int ob = swz64(c, r);
        *(u16*)((char*)KT1b + ob) = f2bf(kv * betal[r] * __expf(gcs[r]));
        *(u16*)((char*)CHKcT + (size_t)bhc * 8192 + ob) = f2bf(kv * __expf(gcsC - gcs[r]));
    }
    if (tid == 0) CHcC[bhc] = __expf(gcsC);
    __syncthreads();   // Ql/Kl dead; Tl overlay becomes safe

    // phase 2b: T0 = I + M0 = I - A  (fp32 master + bf16 image, own rows)
#pragma unroll
    for (int nt = 0; nt < 4; ++nt)
#pragma unroll
        for (int reg = 0; reg < 4; ++reg) {
            int t = wave * 16 + ((lane >> 4) << 2) + reg;
            int i = nt * 16 + (lane & 15);
            float tv = (t == i) ? 1.f : am[nt][reg];
            Tl[t * 64 + i] = tv;
            *(u16*)((char*)Tb + swz64(t, i)) = f2bf(tv);
        }
    __syncthreads();

    // phase 3: doubling. stage j: M <- M^2 (in place), then T <- T + T*M.
    const int hi = wave * 16 + 15;
#pragma unroll
    for (int j = 1; j <= 5; ++j) {
        // square M (read Mim own rows as A-op, MTim all rows as B-op)
        f32x4 aM[4] = {};
#pragma unroll
        for (int nt = 0; nt < 4; ++nt) {
            if (nt * 16 > hi - (1 << j)) continue;
#pragma unroll
            for (int kk = 0; kk < 2; ++kk) {
                if (kk * 32 > hi) break;
                aM[nt] = __builtin_amdgcn_mfma_f32_16x16x32_bf16(
                    frag64(Mim, wave * 16, lane, kk), frag64(MTim, nt * 16, lane, kk), aM[nt], 0, 0, 0);
            }
        }
        __syncthreads();   // all reads of M_{j-1} done
        // write M_j in place (ALL entries — masked zeros, no stale data)
#pragma unroll
        for (int nt = 0; nt < 4; ++nt)
#pragma unroll
            for (int reg = 0; reg < 4; ++reg) {
                int t = wave * 16 + ((lane >> 4) << 2) + reg;
                int i = nt * 16 + (lane & 15);
                float mv = (t - i >= (1 << j)) ? aM[nt][reg] : 0.f;
                u16 mb = f2bf(mv);
                *(u16*)((char*)Mim + swz64(t, i)) = mb;
                *(u16*)((char*)MTim + swz64(i, t)) = mb;
            }
        __syncthreads();   // M_j published
        // T update: aT = T (fp32 master) + T*M_j ; own rows only -> no barrier needed after
        f32x4 aT[4];
#pragma unroll
        for (int nt = 0; nt < 4; ++nt)
#pragma unroll
            for (int reg = 0; reg < 4; ++reg) {
                int t = wave * 16 + ((lane >> 4) << 2) + reg;
                int i = nt * 16 + (lane & 15);
                aT[nt][reg] = Tl[t * 64 + i];
            }
#pragma unroll
        for (int nt = 0; nt < 4; ++nt) {
            if (nt * 16 > hi - (1 << j)) continue;
#pragma unroll
            for (int kk = 0; kk < 2; ++kk) {
                if (kk * 32 > hi) break;
                aT[nt] = __builtin_amdgcn_mfma_f32_16x16x32_bf16(
                    frag64(Tb, wave * 16, lane, kk), frag64(MTim, nt * 16, lane, kk), aT[nt], 0, 0, 0);
            }
        }
#pragma unroll
        for (int nt = 0; nt < 4; ++nt)
#pragma unroll
            for (int reg = 0; reg < 4; ++reg) {
                int t = wave * 16 + ((lane >> 4) << 2) + reg;
                int i = nt * 16 + (lane & 15);
                Tl[t * 64 + i] = aT[nt][reg];
                *(u16*)((char*)Tb + swz64(t, i)) = f2bf(aT[nt][reg]);
            }
    }
    __syncthreads();   // U0T below reads other waves' Tb rows

    // final: W = T @ (beta*c*K);  U0T = (beta*V)^T @ T^T
    {
        f32x4 aW[4] = {};
#pragma unroll
        for (int nt = 0; nt < 4; ++nt)
#pragma unroll
            for (int kk = 0; kk < 2; ++kk) {
                if (kk * 32 > hi) break;   // T[t][k] zero for k > t
                aW[nt] = __builtin_amdgcn_mfma_f32_16x16x32_bf16(
                    frag64(Tb, wave * 16, lane, kk), frag64(KT1b, nt * 16, lane, kk), aW[nt], 0, 0, 0);
            }
#pragma unroll
        for (int nt = 0; nt < 4; ++nt)
#pragma unroll
            for (int reg = 0; reg < 4; ++reg) {
                int r = wave * 16 + ((lane >> 4) << 2) + reg;
                int c = nt * 16 + (lane & 15);
                *(u16*)((char*)CHW + (size_t)bhc * 8192 + swz64(r, c)) = f2bf(aW[nt][reg]);
            }
    }
#pragma unroll
    for (int rt = 0; rt < 2; ++rt) {
        f32x4 aU[4] = {};
        int rb = (wave * 2 + rt) * 16;
#pragma unroll
        for (int nt = 0; nt < 4; ++nt)
#pragma unroll
            for (int kk = 0; kk < 2; ++kk) {
                if (kk * 32 > nt * 16 + 15) continue;  // T[c][k] zero for k > c
                aU[nt] = __builtin_amdgcn_mfma_f32_16x16x32_bf16(
                    frag64(VTb, rb, lane, kk), frag64(Tb, nt * 16, lane, kk), aU[nt], 0, 0, 0);
            }
#pragma unroll
        for (int nt = 0; nt < 4; ++nt)
#pragma unroll
            for (int reg = 0; reg < 4; ++reg) {
                int dv = rb + ((lane >> 4) << 2) + reg;
                int c = nt * 16 + (lane & 15);
                *(u16*)((char*)CHU0T + (size_t)bhc * 16384 + swz64(dv, c)) = f2bf(aU[nt][reg]);
            }
    }
}

// ---------------- chunked gated delta rule: stage 2 (sequential over 16 chunks; block = b,h,dv-half)
__global__ __launch_bounds__(256) void k_scan2(
    const u16* __restrict__ CHW, const u16* __restrict__ CHM, const u16* __restrict__ CHQc,
    const u16* __restrict__ CHKcT, const u16* __restrict__ CHU0T, const float* __restrict__ CHcC,
    float* __restrict__ O) {
    __shared__ __align__(16) u16 stg[2][5 * 4096];
    __shared__ __align__(16) u16 STb[4096], uTl[4096];
    __shared__ float ST[64 * 66];
    const int blk = blockIdx.x;
    const int bb = blk >> 5, h = (blk >> 1) & 15, dvh = blk & 1;
    const int bh = bb * 16 + h;
    const int tid = threadIdx.x, lane = tid & 63, wave = tid >> 6;

    for (int e = tid; e < 64 * 66; e += 256) ST[e] = 0.f;
    for (int e = tid; e < 4096; e += 256) STb[e] = 0;

    auto stage = [&](int buf, int ch) {
        const size_t base = (size_t)(bh * 16 + ch);
        const u16* srcs[5] = { CHW + base * 4096, CHM + base * 4096, CHQc + base * 4096,
                               CHKcT + base * 4096, CHU0T + base * 8192 + dvh * 4096 };
#pragma unroll
        for (int s = 0; s < 5; ++s)
#pragma unroll
            for (int r = 0; r < 2; ++r) {
                int ub = r * 256 + wave * 64;
                async16(srcs[s] + (size_t)(ub + lane) * 8, &stg[buf][s * 4096 + ub * 8]);
            }
    };
    stage(0, 0);
    for (int ch = 0; ch < 16; ++ch) {
        const int cur = ch & 1;
        asm volatile("s_waitcnt vmcnt(0)" ::: "memory");
        __syncthreads();
        if (ch < 15) stage(cur ^ 1, ch + 1);
        const u16* sW = &stg[cur][0];
        const u16* sM = &stg[cur][4096];
        const u16* sQc = &stg[cur][8192];
        const u16* sKcT = &stg[cur][12288];
        const u16* sU0 = &stg[cur][16384];
        // phase A: uT = U0T - (S0 W^T)    [rows dv]
        {
            f32x4 acc[4] = {};
#pragma unroll
            for (int nt = 0; nt < 4; ++nt)
#pragma unroll
                for (int kk = 0; kk < 2; ++kk)
                    acc[nt] = __builtin_amdgcn_mfma_f32_16x16x32_bf16(
                        frag64(STb, wave * 16, lane, kk), frag64(sW, nt * 16, lane, kk), acc[nt], 0, 0, 0);
#pragma unroll
            for (int nt = 0; nt < 4; ++nt)
#pragma unroll
                for (int reg = 0; reg < 4; ++reg) {
                    int dv = wave * 16 + ((lane >> 4) << 2) + reg;
                    int c = nt * 16 + (lane & 15);
                    int b = swz64(dv, c);
                    float u0 = bf2f(*(const u16*)((const char*)sU0 + b));
                    *(u16*)((char*)uTl + b) = f2bf(u0 - acc[nt][reg]);
                }
        }
        __syncthreads();
        // phase B: O = M@u + Qc@S0 (rows c); Sacc = u^T-rows-dv @ KcT (rows dv)
        f32x4 accO[4] = {}, accS[4] = {};
#pragma unroll
        for (int nt = 0; nt < 4; ++nt)
#pragma unroll
            for (int kk = 0; kk < 2; ++kk) {
                accO[nt] = __builtin_amdgcn_mfma_f32_16x16x32_bf16(
                    frag64(sM, wave * 16, lane, kk), frag64(uTl, nt * 16, lane, kk), accO[nt], 0, 0, 0);
                accO[nt] = __builtin_amdgcn_mfma_f32_16x16x32_bf16(
                    frag64(sQc, wave * 16, lane, kk), frag64(STb, nt * 16, lane, kk), accO[nt], 0, 0, 0);
                accS[nt] = __builtin_amdgcn_mfma_f32_16x16x32_bf16(
                    frag64(uTl, wave * 16, lane, kk), frag64(sKcT, nt * 16, lane, kk), accS[nt], 0, 0, 0);
            }
        __syncthreads();
        // phase C: write O; update state
        const float cC = CHcC[bh * 16 + ch];
#pragma unroll
        for (int nt = 0; nt < 4; ++nt)
#pragma unroll
            for (int reg = 0; reg < 4; ++reg) {
                int rr = wave * 16 + ((lane >> 4) << 2) + reg;
                int cc = nt * 16 + (lane & 15);
                O[((size_t)(bb * 1024 + ch * 64 + rr)) * 2048 + h * 128 + dvh * 64 + cc] = accO[nt][reg];
                float ns = cC * ST[rr * 66 + cc] + accS[nt][reg];
                ST[rr * 66 + cc] = ns;
                *(u16*)((char*)STb + swz64(rr, cc)) = f2bf(ns);
            }
    }
}

// ---------------- per-head RMSNorm(o) * gate * sigmoid(gate) -> bf16
__global__ __launch_bounds__(256) void k_gate(const float* __restrict__ O, const u16* __restrict__ P,
                                              const float* __restrict__ onw, u16* __restrict__ OG) {
    const int row = blockIdx.x;
    const int tid = threadIdx.x, lane = tid & 63, wave = tid >> 6;
#pragma unroll
    for (int p = 0; p < 4; ++p) {
        const int h = p * 4 + wave;
        const int dv = lane * 2;
        const float2 o2 = *(const float2*)&O[(size_t)row * 2048 + h * 128 + dv];
        float ss = o2.x * o2.x + o2.y * o2.y;
#pragma unroll
        for (int o = 1; o < 64; o <<= 1) ss += __shfl_xor(ss, o);
        const float rn = rsqrtf(ss * (1.f / 128.f) + 1e-6f);
        const float g0 = bf2f(P[(size_t)row * N1P + 4128 + h * 128 + dv]);
        const float g1 = bf2f(P[(size_t)row * N1P + 4128 + h * 128 + dv + 1]);
        const float r0 = o2.x * rn * onw[dv] * g0 * sigm(g0);
        const float r1 = o2.y * rn * onw[dv + 1] * g1 * sigm(g1);
        const uint32_t pk = (uint32_t)f2bf(r0) | ((uint32_t)f2bf(r1) << 16);
        *(uint32_t*)&OG[(size_t)row * 2048 + h * 128 + dv] = pk;
    }
}

// ---------------- silu(u1) * u3 -> bf16
__global__ __launch_bounds__(256) void k_silumul(const u16* __restrict__ U13, u16* __restrict__ Mm) {
    const int idx = blockIdx.x * 256 + threadIdx.x;
    const int row = idx / 704, c4 = idx % 704;
    const size_t b1 = (size_t)row * 5632 + c4 * 4;
    const uint2 ua = *(const uint2*)&U13[b1];
    const uint2 ub = *(const uint2*)&U13[b1 + 2816];
    float a0 = bf2f(ua.x & 0xffff), a1 = bf2f(ua.x >> 16), a2 = bf2f(ua.y & 0xffff), a3 = bf2f(ua.y >> 16);
    float b0 = bf2f(ub.x & 0xffff), b1f = bf2f(ub.x >> 16), b2 = bf2f(ub.y & 0xffff), b3 = bf2f(ub.y >> 16);
    const float r0 = a0 * sigm(a0) * b0, r1 = a1 * sigm(a1) * b1f;
    const float r2 = a2 * sigm(a2) * b2, r3 = a3 * sigm(a3) * b3;
    uint2 pk;
    pk.x = (uint32_t)f2bf(r0) | ((uint32_t)f2bf(r1) << 16);
    pk.y = (uint32_t)f2bf(r2) | ((uint32_t)f2bf(r3) << 16);
    *(uint2*)&Mm[(size_t)row * 2816 + c4 * 4] = pk;
}

extern "C" void kernel_launch(void* const* d_in, const int* in_sizes, int n_in,
                              void* d_out, int out_size, void* d_ws, size_t ws_size,
                              hipStream_t stream) {
    const float* x   = (const float*)d_in[0];
    const float* n1w = (const float*)d_in[1];
    const float* wq  = (const float*)d_in[2];
    const float* wk  = (const float*)d_in[3];
    const float* wv  = (const float*)d_in[4];
    const float* cq  = (const float*)d_in[5];
    const float* ck  = (const float*)d_in[6];
    const float* cv  = (const float*)d_in[7];
    const float* wb  = (const float*)d_in[8];
    const float* wa  = (const float*)d_in[9];
    const float* Alg = (const float*)d_in[10];
    const float* dtb = (const float*)d_in[11];
    const float* wg  = (const float*)d_in[12];
    const float* onw = (const float*)d_in[13];
    const float* wo  = (const float*)d_in[14];
    const float* n2w = (const float*)d_in[15];
    const float* w1  = (const float*)d_in[16];
    const float* w2  = (const float*)d_in[17];
    const float* w3  = (const float*)d_in[18];

    if (ws_size < 114819072ULL) return;

    char* ws = (char*)d_ws;
    u16*   WcatT = (u16*)(ws + 0);            // [6272][1024] bf16 (CHW/CHM/CHQc reuse)
    u16*   WoT   = (u16*)(ws + 12845056);     // [1024][2048]
    u16*   W13T  = (u16*)(ws + 17039360);     // [5632][1024]
    u16*   W2T   = (u16*)(ws + 28573696);     // [1024][2816]
    u16*   hA    = (u16*)(ws + 34340864);     // [2048][1024] (h2A reuse)
    u16*   P     = (u16*)(ws + 38535168);     // [2048][6272] (U13 reuse)
    u16*   Qb    = (u16*)(ws + 64225280);     // [2048][1024] bf16 (Mm reuse)
    u16*   Kb    = (u16*)(ws + 68419584);     // [2048][1024] bf16
    u16*   Vb    = (u16*)(ws + 72613888);     // [2048][2048] bf16 (OG reuse)
    float* Gl    = (float*)(ws + 81002496);   // [2048][16] log decay
    float* Bbf   = (float*)(ws + 81133568);   // [2048][16]
    float* O     = (float*)(ws + 81264640);   // [2048][2048] fp32 (X2 reuse)
    u16*   CHKcT = (u16*)(ws + 98041856);     // [512][64][64] bf16 image
    u16*   CHU0T = (u16*)(ws + 102236160);    // [512][128][64] bf16 image
    float* CHcC  = (float*)(ws + 110624768);  // [512]
    u16*   CHW   = WcatT;                     // [512][64][64] image
    u16*   CHM   = (u16*)(ws + 4194304);
    u16*   CHQc  = (u16*)(ws + 8388608);
    u16*   U13 = P;
    u16*   Mm  = Qb;
    u16*   OG  = Vb;
    float* X2  = O;
    u16*   h2A = hA;

    // fused weight transposes (fp32 [K][N] -> bf16 [N][K]) in one launch
    TJobs tj;
    tj.j[0] = { wq, WcatT, 1024, 1024,    0, 1024,     0, 32 };
    tj.j[1] = { wk, WcatT, 1024, 1024, 1024, 1024,  1024, 32 };
    tj.j[2] = { wv, WcatT, 1024, 2048, 2048, 2048,  2048, 64 };
    tj.j[3] = { wb, WcatT, 1024,   16, 4096,   16,  4096,  1 };
    tj.j[4] = { wa, WcatT, 1024,   16, 4112,   16,  4128,  1 };
    tj.j[5] = { wg, WcatT, 1024, 2048, 4128, 2144,  4160, 67 };
    tj.j[6] = { wo, WoT,   2048, 1024,    0, 1024,  6304, 32 };
    tj.j[7] = { w1, W13T,  1024, 2816,    0, 2816,  8352, 88 };
    tj.j[8] = { w3, W13T,  1024, 2816, 2816, 2816, 11168, 88 };
    tj.j[9] = { w2, W2T,   2816, 1024,    0, 1024, 13984, 32 };
    k_transpose_all<<<16800, dim3(32, 8), 0, stream>>>(tj, 10);

    k_rmsnorm<<<2048, 256, 0, stream>>>(x, n1w, hA);
    k_gemm<128, 2><<<784, 512, 0, stream>>>(hA, WcatT, P, nullptr, N1P, 1024);

    k_conv<<<2048, 256, 0, stream>>>(P, cq, ck, cv, Alg, dtb, Qb, Kb, Vb, Gl, Bbf);

    k_scan1<<<512, 256, 0, stream>>>(Qb, Kb, Vb, Gl, Bbf, CHW, CHM, CHQc, CHKcT, CHU0T, CHcC);
    k_scan2<<<64, 256, 0, stream>>>(CHW, CHM, CHQc, CHKcT, CHU0T, CHcC, O);

    k_gate<<<2048, 256, 0, stream>>>(O, P, onw, OG);
    k_gemm<64, 1><<<512, 512, 0, stream>>>(OG, WoT, X2, x, 1024, 2048);

    k_rmsnorm<<<2048, 256, 0, stream>>>(X2, n2w, h2A);
    k_gemm<128, 2><<<704, 512, 0, stream>>>(h2A, W13T, U13, nullptr, 5632, 1024);
    k_silumul<<<5632, 256, 0, stream>>>(U13, Mm);
    k_gemm<64, 1><<<512, 512, 0, stream>>>(Mm, W2T, (float*)d_out, X2, 1024, 2816);
}

// Round 8
// 260.846 us; speedup vs baseline: 3.2393x; 1.0084x over previous
//
#include <hip/hip_runtime.h>
#include <stdint.h>

typedef unsigned short u16;
typedef float f32x4 __attribute__((ext_vector_type(4)));
typedef __bf16 bf16x8 __attribute__((ext_vector_type(8)));
typedef unsigned short u16x8 __attribute__((ext_vector_type(8)));

#define N1P 6272   // padded concat width: q(1024)|k(1024)|v(2048)|b(16)|a(16)|g(2048)|pad(96)

__device__ __forceinline__ u16 f2bf(float f) {
    union { float f; uint32_t u; } v; v.f = f;
    uint32_t u = v.u;
    return (u16)((u + 0x7FFFu + ((u >> 16) & 1u)) >> 16);
}
__device__ __forceinline__ float bf2f(u16 h) {
    union { uint32_t u; float f; } v; v.u = ((uint32_t)h) << 16; return v.f;
}
__device__ __forceinline__ float sigm(float x) { return 1.f / (1.f + __expf(-x)); }

__device__ __forceinline__ void async16(const u16* g, u16* l) {
    __builtin_amdgcn_global_load_lds((const __attribute__((address_space(1))) void*)g,
                                     (__attribute__((address_space(3))) void*)l, 16, 0, 0);
}

// byte offset inside a [R][64] bf16 "swizzled image": 16B units XOR'd with row&7
__device__ __forceinline__ int swz64(int row, int col) {
    return row * 128 + ((((col >> 3) ^ (row & 7)) << 3) + (col & 7)) * 2;
}
// MFMA fragment read from a swizzled [R][64] bf16 image (rows rowbase..rowbase+15, K-offset kk*32)
__device__ __forceinline__ bf16x8 frag64(const u16* m, int rowbase, int lane, int kk) {
    const int row = rowbase + (lane & 15);
    const int unit = (lane >> 4) + (kk << 2);
    return *(const bf16x8*)((const char*)m + row * 128 + ((unit ^ (row & 7)) << 4));
}

// ---------------- fused transpose + fp32->bf16 convert (all 10 weight matrices, one launch)
// dst[(rowOff + n*rowStride)*rows + k] = src[k*cols + n]
struct TJob { const float* src; u16* dst; int rows, cols, rowOff, rowStride, nOut, blkBase, gx; };
struct TJobs { TJob j[10]; };

__global__ __launch_bounds__(256) void k_transpose_all(TJobs jobs, int njobs) {
    __shared__ float tile[32][33];
    const int bid = blockIdx.x;
    int ji = 0;
#pragma unroll
    for (int i = 1; i < 10; ++i)
        if (i < njobs && bid >= jobs.j[i].blkBase) ji = i;
    const TJob J = jobs.j[ji];
    const int bx = bid - J.blkBase;
    const int n0 = (bx % J.gx) * 32, k0 = (bx / J.gx) * 32;
    const int tx = threadIdx.x, ty = threadIdx.y;  // 32x8
#pragma unroll
    for (int j = 0; j < 32; j += 8) {
        int r = k0 + ty + j, c = n0 + tx;
        tile[ty + j][tx] = (r < J.rows && c < J.cols) ? J.src[(size_t)r * J.cols + c] : 0.f;
    }
    __syncthreads();
#pragma unroll
    for (int j = 0; j < 32; j += 8) {
        int n = n0 + ty + j, k = k0 + tx;
        if (n < J.nOut) J.dst[(size_t)(J.rowOff + n * J.rowStride) * J.rows + k] = f2bf(tile[tx][ty + j]);
    }
}

// ---------------- rmsnorm over D=1024, fp32 in -> bf16 out
__global__ __launch_bounds__(256) void k_rmsnorm(const float* __restrict__ x, const float* __restrict__ w,
                                                 u16* __restrict__ out) {
    const int row = blockIdx.x, tid = threadIdx.x, lane = tid & 63, wave = tid >> 6;
    const float4 v = ((const float4*)(x + (size_t)row * 1024))[tid];
    float ss = v.x * v.x + v.y * v.y + v.z * v.z + v.w * v.w;
#pragma unroll
    for (int o = 1; o < 64; o <<= 1) ss += __shfl_xor(ss, o);
    __shared__ float sred[4];
    if (lane == 0) sred[wave] = ss;
    __syncthreads();
    const float tot = sred[0] + sred[1] + sred[2] + sred[3];
    const float rn = rsqrtf(tot * (1.f / 1024.f) + 1e-6f);
    const float4 wv = ((const float4*)w)[tid];
    uint2 pk;
    pk.x = (uint32_t)f2bf(v.x * rn * wv.x) | ((uint32_t)f2bf(v.y * rn * wv.y) << 16);
    pk.y = (uint32_t)f2bf(v.z * rn * wv.z) | ((uint32_t)f2bf(v.w * rn * wv.w) << 16);
    *(uint2*)&out[(size_t)row * 1024 + tid * 4] = pk;
}

// ---------------- bf16 GEMM, A[M][K] row-major (M=2048), Bt[N][K] row-major, BK=64, swizzled LDS
// 8 waves (512 thr), double-buffered, issue-early staging, XCD-contiguous 1-D grid.
// TILE in {64,128}; EPI: 1 = fp32 + residual, 2 = bf16 store (LDS-coalesced),
//                        3 = fused silu(u1)*u3 with w1/w3-interleaved B (LDS-coalesced bf16)
template <int TILE, int EPI>
__global__ __launch_bounds__(512) void k_gemm(const u16* __restrict__ A, const u16* __restrict__ Bt,
                                              void* __restrict__ Cout, const float* __restrict__ Res,
                                              int N, int Kd) {
    __shared__ __align__(16) u16 As[2][TILE * 64];
    __shared__ __align__(16) u16 Bs[2][TILE * 64];
    constexpr int MB = 2048 / TILE;                  // block count along M (power of 2)
    const int q = (int)gridDim.x >> 3;               // grid divisible by 8
    const int bid = blockIdx.x;
    const int wg = (bid & 7) * q + (bid >> 3);       // XCD x owns contiguous wg chunk
    const int bm = wg & (MB - 1), bn = wg / MB;      // bm fastest -> B-panel locality per XCD
    const int tid = threadIdx.x, lane = tid & 63, wave = tid >> 6;
    const int wm = wave >> 2, wn = wave & 3;         // 2 x 4 wave grid
    constexpr int RS = TILE / 2, CS = TILE / 4;      // per-wave output span
    constexpr int FRM = RS / 16, FRN = CS / 16;
    constexpr int IS = TILE / 64;                    // issue rounds per matrix per K-step

    const int srow = wave * 8 + (lane >> 3);         // 0..63
    const int scol = ((lane & 7) ^ (lane >> 3)) * 8; // pre-swizzled source granule
    const u16* gA = A + (size_t)(bm * TILE + srow) * Kd + scol;
    const u16* gB = Bt + (size_t)(bn * TILE + srow) * Kd + scol;

    f32x4 acc[FRM][FRN] = {};
    const int NT = Kd >> 6;

    // prologue: stage tile 0 into buf 0
#pragma unroll
    for (int j = 0; j < IS; ++j) {
        async16(gA + (size_t)j * 64 * Kd, &As[0][j * 4096 + wave * 512]);
        async16(gB + (size_t)j * 64 * Kd, &Bs[0][j * 4096 + wave * 512]);
    }
    asm volatile("s_waitcnt vmcnt(0)" ::: "memory");
    __syncthreads();

    int buf = 0;
    for (int t = 0; t < NT; ++t) {
        if (t + 1 < NT) {                            // issue next-tile loads EARLY
            const int k0 = (t + 1) << 6;
#pragma unroll
            for (int j = 0; j < IS; ++j) {
                async16(gA + (size_t)j * 64 * Kd + k0, &As[buf ^ 1][j * 4096 + wave * 512]);
                async16(gB + (size_t)j * 64 * Kd + k0, &Bs[buf ^ 1][j * 4096 + wave * 512]);
            }
        }
#pragma unroll
        for (int kk = 0; kk < 2; ++kk) {             // compute current buffer
            bf16x8 af[FRM], bfr[FRN];
#pragma unroll
            for (int mi = 0; mi < FRM; ++mi) af[mi] = frag64(As[buf], wm * RS + mi * 16, lane, kk);
#pragma unroll
            for (int ni = 0; ni < FRN; ++ni) bfr[ni] = frag64(Bs[buf], wn * CS + ni * 16, lane, kk);
#pragma unroll
            for (int mi = 0; mi < FRM; ++mi)
#pragma unroll
                for (int ni = 0; ni < FRN; ++ni)
                    acc[mi][ni] = __builtin_amdgcn_mfma_f32_16x16x32_bf16(af[mi], bfr[ni], acc[mi][ni], 0, 0, 0);
        }
        asm volatile("s_waitcnt vmcnt(0)" ::: "memory");   // next-tile loads landed (hidden under MFMA)
        __syncthreads();
        buf ^= 1;
    }

    const int rsub = (lane >> 4) * 4;
    const int csub = lane & 15;

    if constexpr (EPI == 1) {
        const int crow0 = bm * TILE + wm * RS;
        const int ccol0 = bn * TILE + wn * CS;
#pragma unroll
        for (int mi = 0; mi < FRM; ++mi)
#pragma unroll
            for (int ni = 0; ni < FRN; ++ni) {
                const int c = ccol0 + ni * 16 + csub;
#pragma unroll
                for (int r = 0; r < 4; ++r) {
                    const int rr = crow0 + mi * 16 + rsub + r;
                    ((float*)Cout)[(size_t)rr * N + c] = acc[mi][ni][r] + Res[(size_t)rr * N + c];
                }
            }
    } else if constexpr (EPI == 2) {
        // bf16 out via LDS for coalesced 16B stores (tile 128x128 = 32KB, reuses As)
        u16* ctile = (u16*)As;
#pragma unroll
        for (int mi = 0; mi < FRM; ++mi)
#pragma unroll
            for (int ni = 0; ni < FRN; ++ni)
#pragma unroll
                for (int r = 0; r < 4; ++r)
                    ctile[(wm * 64 + mi * 16 + rsub + r) * 128 + wn * 32 + ni * 16 + csub] =
                        f2bf(acc[mi][ni][r]);
        __syncthreads();
#pragma unroll
        for (int k = 0; k < 4; ++k) {
            const int f = (tid + k * 512) * 8;
            const int r = f >> 7, c = f & 127;
            *(u16x8*)&((u16*)Cout)[(size_t)(bm * 128 + r) * N + bn * 128 + c] = *(const u16x8*)&ctile[f];
        }
    } else {
        // EPI==3: B rows interleaved (even = w1 col, odd = w3 col); out col = B-row/2
        u16* ctile = (u16*)As;
#pragma unroll
        for (int mi = 0; mi < FRM; ++mi)
#pragma unroll
            for (int ni = 0; ni < FRN; ++ni)
#pragma unroll
                for (int r = 0; r < 4; ++r) {
                    const float v = acc[mi][ni][r];
                    const float p = __shfl_xor(v, 1);
                    const float u1 = (lane & 1) ? p : v;
                    const float u3 = (lane & 1) ? v : p;
                    const float res = u1 * sigm(u1) * u3;
                    if (!(lane & 1))
                        ctile[(wm * 64 + mi * 16 + rsub + r) * 64 + ((wn * 32 + ni * 16 + csub) >> 1)] =
                            f2bf(res);
                }
        __syncthreads();
#pragma unroll
        for (int k = 0; k < 2; ++k) {
            const int f = (tid + k * 512) * 8;
            const int r = f >> 6, c = f & 63;
            *(u16x8*)&((u16*)Cout)[(size_t)(bm * 128 + r) * N + bn * 64 + c] = *(const u16x8*)&ctile[f];
        }
    }
}

// ---------------- depthwise causal conv(4) + silu + l2norm(q,k) + beta / log-decay (vectorized x8)
__global__ __launch_bounds__(256) void k_conv(const u16* __restrict__ P, const float* __restrict__ cwq,
                                              const float* __restrict__ cwk, const float* __restrict__ cwv,
                                              const float* __restrict__ A_log, const float* __restrict__ dtb,
                                              u16* __restrict__ Qb, u16* __restrict__ Kb,
                                              u16* __restrict__ Vb, float* __restrict__ Gl,
                                              float* __restrict__ Bbuf) {
    const int row = blockIdx.x;  // b*1024 + t
    const int t = row & 1023;
    const int tid = threadIdx.x;
    const long prow = (long)row * N1P;
#pragma unroll
    for (int p = 0; p < 2; ++p) {
        const int g = p * 256 + tid;        // col-group of 8 (512 groups = 4096 cols)
        const int c = g * 8;
        u16x8 taps[4];
#pragma unroll
        for (int j = 0; j < 4; ++j) {
            const int tt = t - 3 + j;
            if (tt >= 0) taps[j] = *(const u16x8*)&P[prow + (long)(j - 3) * N1P + c];
            else         taps[j] = u16x8{};
        }
        const float* cw = (c < 1024) ? (cwq + c * 4)
                          : (c < 2048) ? (cwk + (c - 1024) * 4)
                                       : (cwv + (c - 2048) * 4);
        float y[8];
#pragma unroll
        for (int e = 0; e < 8; ++e) {
            const float4 w = ((const float4*)cw)[e];
            float v = bf2f(taps[0][e]) * w.x + bf2f(taps[1][e]) * w.y +
                      bf2f(taps[2][e]) * w.z + bf2f(taps[3][e]) * w.w;
            y[e] = v * sigm(v);
        }
        if (c < 2048) {
            float ss = 0.f;
#pragma unroll
            for (int e = 0; e < 8; ++e) ss += y[e] * y[e];
            ss += __shfl_xor(ss, 1); ss += __shfl_xor(ss, 2); ss += __shfl_xor(ss, 4);
            const float rn = rsqrtf(ss + 1e-6f);
            const float sc = (c < 1024) ? rn * 0.125f : rn;
            u16x8 o;
#pragma unroll
            for (int e = 0; e < 8; ++e) o[e] = f2bf(y[e] * sc);
            if (c < 1024) *(u16x8*)&Qb[(size_t)row * 1024 + c] = o;
            else          *(u16x8*)&Kb[(size_t)row * 1024 + (c - 1024)] = o;
        } else {
            u16x8 o;
#pragma unroll
            for (int e = 0; e < 8; ++e) o[e] = f2bf(y[e]);
            *(u16x8*)&Vb[(size_t)row * 2048 + (c - 2048)] = o;
        }
    }
    if (tid < 32) {
        const int h = tid & 15;
        const float val = bf2f(P[prow + 4096 + tid]);
        if (tid < 16) {
            Bbuf[(size_t)row * 16 + h] = sigm(val);
        } else {
            const float a = val + dtb[h];
            const float sp = (a > 15.f) ? a : log1pf(__expf(a));
            Gl[(size_t)row * 16 + h] = -__expf(A_log[h]) * sp;   // log decay
        }
    }
}

// ---------------- chunked gated delta rule: stage 1 (per b,h,chunk — fully parallel)
// T = (I+A)^{-1} = (I+M0)(I+M1)...(I+M5), M0 = -A, M_j = M_{j-1}^2 (exact, A nilpotent)
__global__ __launch_bounds__(256) void k_scan1(
    const u16* __restrict__ Qb, const u16* __restrict__ Kb, const u16* __restrict__ Vb,
    const float* __restrict__ Gl, const float* __restrict__ Bb,
    u16* __restrict__ CHW, u16* __restrict__ CHM, u16* __restrict__ CHQc,
    u16* __restrict__ CHKcT, u16* __restrict__ CHU0T, float* __restrict__ CHcC) {
    __shared__ __align__(16) char sm[66048];
    u16* Ql   = (u16*)(sm);            // 8KB   (phase<=2a; then low half of fp32 T master)
    u16* Kl   = (u16*)(sm + 8192);     // 8KB   (phase<=2a; then high half of T master)
    u16* VTb  = (u16*)(sm + 16384);    // 16KB
    u16* KT1b = (u16*)(sm + 32768);    // 8KB
    u16* Mim  = (u16*)(sm + 40960);    // 8KB   M_j image (in-place squared)
    u16* MTim = (u16*)(sm + 49152);    // 8KB   M_j^T image
    u16* Tb   = (u16*)(sm + 57344);    // 8KB   bf16 T image (per-wave-owned rows)
    float* Tl    = (float*)sm;         // 16KB fp32 T master, overlays Ql+Kl after 2a
    float* gcs   = (float*)(sm + 65536);
    float* betal = (float*)(sm + 65792);

    const int blk = blockIdx.x;                      // bb*256 + h*16 + ch
    const int bb = blk >> 8, h = (blk >> 4) & 15, ch = blk & 15;
    const int bhc = blk;
    const int tid = threadIdx.x, lane = tid & 63, wave = tid >> 6;
    const long rowbase = (long)bb * 1024 + ch * 64;

    // phase 0: stage K,Q swizzled; load per-row gate scalars
    if (tid < 64) {
        gcs[tid] = Gl[(rowbase + tid) * 16 + h];
        betal[tid] = Bb[(rowbase + tid) * 16 + h];
    }
    for (int u = tid; u < 512; u += 256) {
        int r = u >> 3, c8 = u & 7;
        uint4 kv = *(const uint4*)&Kb[(rowbase + r) * 1024 + h * 64 + c8 * 8];
        uint4 qv = *(const uint4*)&Qb[(rowbase + r) * 1024 + h * 64 + c8 * 8];
        int b = r * 128 + ((c8 ^ (r & 7)) << 4);
        *(uint4*)((char*)Kl + b) = kv;
        *(uint4*)((char*)Ql + b) = qv;
    }
    __syncthreads();
    // phase 1: cumsum (wave 0); VTb build; QK^T / KK^T
    if (wave == 0) {
        float g = gcs[lane];
#pragma unroll
        for (int off = 1; off < 64; off <<= 1) {
            float n = __shfl_up(g, off, 64);
            if (lane >= off) g += n;
        }
        gcs[lane] = g;
    }
    for (int u = tid; u < 1024; u += 256) {          // VTb[dv][c] = beta_c * V[c][dv]
        int r = u >> 4, c8 = u & 15;
        u16x8 vv = *(const u16x8*)&Vb[(rowbase + r) * 2048 + h * 128 + c8 * 8];
        float bsc = betal[r];
#pragma unroll
        for (int j = 0; j < 8; ++j) {
            int dv = c8 * 8 + j;
            *(u16*)((char*)VTb + swz64(dv, r)) = f2bf(bf2f(vv[j]) * bsc);
        }
    }
    f32x4 aQK[4] = {}, aKK[4] = {};
#pragma unroll
    for (int nt = 0; nt < 4; ++nt)
#pragma unroll
        for (int kk = 0; kk < 2; ++kk) {
            bf16x8 bq = frag64(Kl, nt * 16, lane, kk);
            aQK[nt] = __builtin_amdgcn_mfma_f32_16x16x32_bf16(frag64(Ql, wave * 16, lane, kk), bq, aQK[nt], 0, 0, 0);
            aKK[nt] = __builtin_amdgcn_mfma_f32_16x16x32_bf16(frag64(Kl, wave * 16, lane, kk), bq, aKK[nt], 0, 0, 0);
        }
    __syncthreads();   // gcs + VTb published

    // phase 2a: CHM, M0 = -A images, CHQc, KT1b, CHKcT (reads Ql/Kl)
    const float gcsC = gcs[63];
    float am[4][4];    // keep -A values for phase 2b
#pragma unroll
    for (int nt = 0; nt < 4; ++nt)
#pragma unroll
        for (int reg = 0; reg < 4; ++reg) {
            int t = wave * 16 + ((lane >> 4) << 2) + reg;
            int i = nt * 16 + (lane & 15);
            float dec = __expf(gcs[t] - gcs[i]);
            float mv = (i <= t) ? dec * aQK[nt][reg] : 0.f;
            *(u16*)((char*)CHM + (size_t)bhc * 8192 + swz64(t, i)) = f2bf(mv);
            float a = (i < t) ? betal[t] * dec * aKK[nt][reg] : 0.f;
            am[nt][reg] = -a;
            u16 amb = f2bf(-a);
            *(u16*)((char*)Mim + swz64(t, i)) = amb;
            *(u16*)((char*)MTim + swz64(i, t)) = amb;
        }
    for (int e = tid; e < 4096; e += 256) {
        int r = e >> 6, c = e & 63;
        int ib = swz64(r, c);
        float qv = bf2f(*(const u16*)((const char*)Ql + ib)) * __expf(gcs[r]);
        *(u16*)((char*)CHQc + (size_t)bhc * 8192 + ib) = f2bf(qv);
        float kv = bf2f(*(const u16*)((const char*)Kl + ib));
        int ob = swz64(c, r);
        *(u16*)((char*)KT1b + ob) = f2bf(kv * betal[r] * __expf(gcs[r]));
        *(u16*)((char*)CHKcT + (size_t)bhc * 8192 + ob) = f2bf(kv * __expf(gcsC - gcs[r]));
    }
    if (tid == 0) CHcC[bhc] = __expf(gcsC);
    __syncthreads();   // Ql/Kl dead; Tl overlay becomes safe

    // phase 2b: T0 = I + M0 = I - A  (fp32 master + bf16 image, own rows)
#pragma unroll
    for (int nt = 0; nt < 4; ++nt)
#pragma unroll
        for (int reg = 0; reg < 4; ++reg) {
            int t = wave * 16 + ((lane >> 4) << 2) + reg;
            int i = nt * 16 + (lane & 15);
            float tv = (t == i) ? 1.f : am[nt][reg];
            Tl[t * 64 + i] = tv;
            *(u16*)((char*)Tb + swz64(t, i)) = f2bf(tv);
        }
    __syncthreads();

    // phase 3: doubling. stage j: M <- M^2 (in place), then T <- T + T*M.
    const int hi = wave * 16 + 15;
#pragma unroll
    for (int j = 1; j <= 5; ++j) {
        // square M (read Mim own rows as A-op, MTim all rows as B-op)
        f32x4 aM[4] = {};
#pragma unroll
        for (int nt = 0; nt < 4; ++nt) {
            if (nt * 16 > hi - (1 << j)) continue;
#pragma unroll
            for (int kk = 0; kk < 2; ++kk) {
                if (kk * 32 > hi) break;
                aM[nt] = __builtin_amdgcn_mfma_f32_16x16x32_bf16(
                    frag64(Mim, wave * 16, lane, kk), frag64(MTim, nt * 16, lane, kk), aM[nt], 0, 0, 0);
            }
        }
        __syncthreads();   // all reads of M_{j-1} done
        // write M_j in place (ALL entries — masked zeros, no stale data)
#pragma unroll
        for (int nt = 0; nt < 4; ++nt)
#pragma unroll
            for (int reg = 0; reg < 4; ++reg) {
                int t = wave * 16 + ((lane >> 4) << 2) + reg;
                int i = nt * 16 + (lane & 15);
                float mv = (t - i >= (1 << j)) ? aM[nt][reg] : 0.f;
                u16 mb = f2bf(mv);
                *(u16*)((char*)Mim + swz64(t, i)) = mb;
                *(u16*)((char*)MTim + swz64(i, t)) = mb;
            }
        __syncthreads();   // M_j published
        // T update: aT = T (fp32 master) + T*M_j ; own rows only -> no barrier needed after
        f32x4 aT[4];
#pragma unroll
        for (int nt = 0; nt < 4; ++nt)
#pragma unroll
            for (int reg = 0; reg < 4; ++reg) {
                int t = wave * 16 + ((lane >> 4) << 2) + reg;
                int i = nt * 16 + (lane & 15);
                aT[nt][reg] = Tl[t * 64 + i];
            }
#pragma unroll
        for (int nt = 0; nt < 4; ++nt) {
            if (nt * 16 > hi - (1 << j)) continue;
#pragma unroll
            for (int kk = 0; kk < 2; ++kk) {
                if (kk * 32 > hi) break;
                aT[nt] = __builtin_amdgcn_mfma_f32_16x16x32_bf16(
                    frag64(Tb, wave * 16, lane, kk), frag64(MTim, nt * 16, lane, kk), aT[nt], 0, 0, 0);
            }
        }
#pragma unroll
        for (int nt = 0; nt < 4; ++nt)
#pragma unroll
            for (int reg = 0; reg < 4; ++reg) {
                int t = wave * 16 + ((lane >> 4) << 2) + reg;
                int i = nt * 16 + (lane & 15);
                Tl[t * 64 + i] = aT[nt][reg];
                *(u16*)((char*)Tb + swz64(t, i)) = f2bf(aT[nt][reg]);
            }
    }
    __syncthreads();   // U0T below reads other waves' Tb rows

    // final: W = T @ (beta*c*K);  U0T = (beta*V)^T @ T^T
    {
        f32x4 aW[4] = {};
#pragma unroll
        for (int nt = 0; nt < 4; ++nt)
#pragma unroll
            for (int kk = 0; kk < 2; ++kk) {
                if (kk * 32 > hi) break;   // T[t][k] zero for k > t
                aW[nt] = __builtin_amdgcn_mfma_f32_16x16x32_bf16(
                    frag64(Tb, wave * 16, lane, kk), frag64(KT1b, nt * 16, lane, kk), aW[nt], 0, 0, 0);
            }
#pragma unroll
        for (int nt = 0; nt < 4; ++nt)
#pragma unroll
            for (int reg = 0; reg < 4; ++reg) {
                int r = wave * 16 + ((lane >> 4) << 2) + reg;
                int c = nt * 16 + (lane & 15);
                *(u16*)((char*)CHW + (size_t)bhc * 8192 + swz64(r, c)) = f2bf(aW[nt][reg]);
            }
    }
#pragma unroll
    for (int rt = 0; rt < 2; ++rt) {
        f32x4 aU[4] = {};
        int rb = (wave * 2 + rt) * 16;
#pragma unroll
        for (int nt = 0; nt < 4; ++nt)
#pragma unroll
            for (int kk = 0; kk < 2; ++kk) {
                if (kk * 32 > nt * 16 + 15) continue;  // T[c][k] zero for k > c
                aU[nt] = __builtin_amdgcn_mfma_f32_16x16x32_bf16(
                    frag64(VTb, rb, lane, kk), frag64(Tb, nt * 16, lane, kk), aU[nt], 0, 0, 0);
            }
#pragma unroll
        for (int nt = 0; nt < 4; ++nt)
#pragma unroll
            for (int reg = 0; reg < 4; ++reg) {
                int dv = rb + ((lane >> 4) << 2) + reg;
                int c = nt * 16 + (lane & 15);
                *(u16*)((char*)CHU0T + (size_t)bhc * 16384 + swz64(dv, c)) = f2bf(aU[nt][reg]);
            }
    }
}

// ---------------- chunked gated delta rule: stage 2 (sequential over 16 chunks; block = b,h,dv-half)
__global__ __launch_bounds__(256) void k_scan2(
    const u16* __restrict__ CHW, const u16* __restrict__ CHM, const u16* __restrict__ CHQc,
    const u16* __restrict__ CHKcT, const u16* __restrict__ CHU0T, const float* __restrict__ CHcC,
    float* __restrict__ O) {
    __shared__ __align__(16) u16 stg[2][5 * 4096];
    __shared__ __align__(16) u16 STb[4096], uTl[4096];
    __shared__ float ST[64 * 66];
    const int blk = blockIdx.x;
    const int bb = blk >> 5, h = (blk >> 1) & 15, dvh = blk & 1;
    const int bh = bb * 16 + h;
    const int tid = threadIdx.x, lane = tid & 63, wave = tid >> 6;

    for (int e = tid; e < 64 * 66; e += 256) ST[e] = 0.f;
    for (int e = tid; e < 4096; e += 256) STb[e] = 0;

    auto stage = [&](int buf, int ch) {
        const size_t base = (size_t)(bh * 16 + ch);
        const u16* srcs[5] = { CHW + base * 4096, CHM + base * 4096, CHQc + base * 4096,
                               CHKcT + base * 4096, CHU0T + base * 8192 + dvh * 4096 };
#pragma unroll
        for (int s = 0; s < 5; ++s)
#pragma unroll
            for (int r = 0; r < 2; ++r) {
                int ub = r * 256 + wave * 64;
                async16(srcs[s] + (size_t)(ub + lane) * 8, &stg[buf][s * 4096 + ub * 8]);
            }
    };
    stage(0, 0);
    for (int ch = 0; ch < 16; ++ch) {
        const int cur = ch & 1;
        asm volatile("s_waitcnt vmcnt(0)" ::: "memory");
        __syncthreads();
        if (ch < 15) stage(cur ^ 1, ch + 1);
        const u16* sW = &stg[cur][0];
        const u16* sM = &stg[cur][4096];
        const u16* sQc = &stg[cur][8192];
        const u16* sKcT = &stg[cur][12288];
        const u16* sU0 = &stg[cur][16384];
        // phase A: uT = U0T - (S0 W^T)    [rows dv]
        {
            f32x4 acc[4] = {};
#pragma unroll
            for (int nt = 0; nt < 4; ++nt)
#pragma unroll
                for (int kk = 0; kk < 2; ++kk)
                    acc[nt] = __builtin_amdgcn_mfma_f32_16x16x32_bf16(
                        frag64(STb, wave * 16, lane, kk), frag64(sW, nt * 16, lane, kk), acc[nt], 0, 0, 0);
#pragma unroll
            for (int nt = 0; nt < 4; ++nt)
#pragma unroll
                for (int reg = 0; reg < 4; ++reg) {
                    int dv = wave * 16 + ((lane >> 4) << 2) + reg;
                    int c = nt * 16 + (lane & 15);
                    int b = swz64(dv, c);
                    float u0 = bf2f(*(const u16*)((const char*)sU0 + b));
                    *(u16*)((char*)uTl + b) = f2bf(u0 - acc[nt][reg]);
                }
        }
        __syncthreads();
        // phase B: O = M@u + Qc@S0 (rows c); Sacc = u^T-rows-dv @ KcT (rows dv)
        f32x4 accO[4] = {}, accS[4] = {};
#pragma unroll
        for (int nt = 0; nt < 4; ++nt)
#pragma unroll
            for (int kk = 0; kk < 2; ++kk) {
                accO[nt] = __builtin_amdgcn_mfma_f32_16x16x32_bf16(
                    frag64(sM, wave * 16, lane, kk), frag64(uTl, nt * 16, lane, kk), accO[nt], 0, 0, 0);
                accO[nt] = __builtin_amdgcn_mfma_f32_16x16x32_bf16(
                    frag64(sQc, wave * 16, lane, kk), frag64(STb, nt * 16, lane, kk), accO[nt], 0, 0, 0);
                accS[nt] = __builtin_amdgcn_mfma_f32_16x16x32_bf16(
                    frag64(uTl, wave * 16, lane, kk), frag64(sKcT, nt * 16, lane, kk), accS[nt], 0, 0, 0);
            }
        __syncthreads();
        // phase C: write O; update state
        const float cC = CHcC[bh * 16 + ch];
#pragma unroll
        for (int nt = 0; nt < 4; ++nt)
#pragma unroll
            for (int reg = 0; reg < 4; ++reg) {
                int rr = wave * 16 + ((lane >> 4) << 2) + reg;
                int cc = nt * 16 + (lane & 15);
                O[((size_t)(bb * 1024 + ch * 64 + rr)) * 2048 + h * 128 + dvh * 64 + cc] = accO[nt][reg];
                float ns = cC * ST[rr * 66 + cc] + accS[nt][reg];
                ST[rr * 66 + cc] = ns;
                *(u16*)((char*)STb + swz64(rr, cc)) = f2bf(ns);
            }
    }
}

// ---------------- per-head RMSNorm(o) * gate * sigmoid(gate) -> bf16
__global__ __launch_bounds__(256) void k_gate(const float* __restrict__ O, const u16* __restrict__ P,
                                              const float* __restrict__ onw, u16* __restrict__ OG) {
    const int row = blockIdx.x;
    const int tid = threadIdx.x, lane = tid & 63, wave = tid >> 6;
#pragma unroll
    for (int p = 0; p < 4; ++p) {
        const int h = p * 4 + wave;
        const int dv = lane * 2;
        const float2 o2 = *(const float2*)&O[(size_t)row * 2048 + h * 128 + dv];
        float ss = o2.x * o2.x + o2.y * o2.y;
#pragma unroll
        for (int o = 1; o < 64; o <<= 1) ss += __shfl_xor(ss, o);
        const float rn = rsqrtf(ss * (1.f / 128.f) + 1e-6f);
        const float g0 = bf2f(P[(size_t)row * N1P + 4128 + h * 128 + dv]);
        const float g1 = bf2f(P[(size_t)row * N1P + 4128 + h * 128 + dv + 1]);
        const float r0 = o2.x * rn * onw[dv] * g0 * sigm(g0);
        const float r1 = o2.y * rn * onw[dv + 1] * g1 * sigm(g1);
        const uint32_t pk = (uint32_t)f2bf(r0) | ((uint32_t)f2bf(r1) << 16);
        *(uint32_t*)&OG[(size_t)row * 2048 + h * 128 + dv] = pk;
    }
}

extern "C" void kernel_launch(void* const* d_in, const int* in_sizes, int n_in,
                              void* d_out, int out_size, void* d_ws, size_t ws_size,
                              hipStream_t stream) {
    const float* x   = (const float*)d_in[0];
    const float* n1w = (const float*)d_in[1];
    const float* wq  = (const float*)d_in[2];
    const float* wk  = (const float*)d_in[3];
    const float* wv  = (const float*)d_in[4];
    const float* cq  = (const float*)d_in[5];
    const float* ck  = (const float*)d_in[6];
    const float* cv  = (const float*)d_in[7];
    const float* wb  = (const float*)d_in[8];
    const float* wa  = (const float*)d_in[9];
    const float* Alg = (const float*)d_in[10];
    const float* dtb = (const float*)d_in[11];
    const float* wg  = (const float*)d_in[12];
    const float* onw = (const float*)d_in[13];
    const float* wo  = (const float*)d_in[14];
    const float* n2w = (const float*)d_in[15];
    const float* w1  = (const float*)d_in[16];
    const float* w2  = (const float*)d_in[17];
    const float* w3  = (const float*)d_in[18];

    if (ws_size < 114819072ULL) return;

    char* ws = (char*)d_ws;
    u16*   WcatT = (u16*)(ws + 0);            // [6272][1024] bf16 (CHW/CHM/CHQc reuse)
    u16*   WoT   = (u16*)(ws + 12845056);     // [1024][2048]
    u16*   W13T  = (u16*)(ws + 17039360);     // [5632][1024] interleaved w1/w3 rows
    u16*   W2T   = (u16*)(ws + 28573696);     // [1024][2816]
    u16*   hA    = (u16*)(ws + 34340864);     // [2048][1024] (h2A reuse)
    u16*   P     = (u16*)(ws + 38535168);     // [2048][6272]
    u16*   Qb    = (u16*)(ws + 64225280);     // [2048][1024] bf16 (Mm reuse)
    u16*   Kb    = (u16*)(ws + 68419584);     // [2048][1024] bf16
    u16*   Vb    = (u16*)(ws + 72613888);     // [2048][2048] bf16 (OG reuse)
    float* Gl    = (float*)(ws + 81002496);   // [2048][16] log decay
    float* Bbf   = (float*)(ws + 81133568);   // [2048][16]
    float* O     = (float*)(ws + 81264640);   // [2048][2048] fp32 (X2 reuse)
    u16*   CHKcT = (u16*)(ws + 98041856);     // [512][64][64] bf16 image
    u16*   CHU0T = (u16*)(ws + 102236160);    // [512][128][64] bf16 image
    float* CHcC  = (float*)(ws + 110624768);  // [512]
    u16*   CHW   = WcatT;                     // [512][64][64] image
    u16*   CHM   = (u16*)(ws + 4194304);
    u16*   CHQc  = (u16*)(ws + 8388608);
    u16*   Mm  = Qb;                          // [2048][2816] bf16 (spans Qb/Kb/part of Vb — all dead by then)
    u16*   OG  = Vb;
    float* X2  = O;
    u16*   h2A = hA;

    // fused weight transposes (fp32 [K][N] -> bf16 [N][K]) in one launch
    TJobs tj;
    tj.j[0] = { wq, WcatT, 1024, 1024,    0, 1, 1024,     0, 32 };
    tj.j[1] = { wk, WcatT, 1024, 1024, 1024, 1, 1024,  1024, 32 };
    tj.j[2] = { wv, WcatT, 1024, 2048, 2048, 1, 2048,  2048, 64 };
    tj.j[3] = { wb, WcatT, 1024,   16, 4096, 1,   16,  4096,  1 };
    tj.j[4] = { wa, WcatT, 1024,   16, 4112, 1,   16,  4128,  1 };
    tj.j[5] = { wg, WcatT, 1024, 2048, 4128, 1, 2144,  4160, 67 };
    tj.j[6] = { wo, WoT,   2048, 1024,    0, 1, 1024,  6304, 32 };
    tj.j[7] = { w1, W13T,  1024, 2816,    0, 2, 2816,  8352, 88 };   // even rows
    tj.j[8] = { w3, W13T,  1024, 2816,    1, 2, 2816, 11168, 88 };   // odd rows
    tj.j[9] = { w2, W2T,   2816, 1024,    0, 1, 1024, 13984, 32 };
    k_transpose_all<<<16800, dim3(32, 8), 0, stream>>>(tj, 10);

    k_rmsnorm<<<2048, 256, 0, stream>>>(x, n1w, hA);
    k_gemm<128, 2><<<784, 512, 0, stream>>>(hA, WcatT, P, nullptr, N1P, 1024);

    k_conv<<<2048, 256, 0, stream>>>(P, cq, ck, cv, Alg, dtb, Qb, Kb, Vb, Gl, Bbf);

    k_scan1<<<512, 256, 0, stream>>>(Qb, Kb, Vb, Gl, Bbf, CHW, CHM, CHQc, CHKcT, CHU0T, CHcC);
    k_scan2<<<64, 256, 0, stream>>>(CHW, CHM, CHQc, CHKcT, CHU0T, CHcC, O);

    k_gate<<<2048, 256, 0, stream>>>(O, P, onw, OG);
    k_gemm<64, 1><<<512, 512, 0, stream>>>(OG, WoT, X2, x, 1024, 2048);

    k_rmsnorm<<<2048, 256, 0, stream>>>(X2, n2w, h2A);
    k_gemm<128, 3><<<704, 512, 0, stream>>>(h2A, W13T, Mm, nullptr, 2816, 1024);  // fused silu(u1)*u3
    k_gemm<64, 1><<<512, 512, 0, stream>>>(Mm, W2T, (float*)d_out, X2, 1024, 2816);
}

// Round 9
// 247.539 us; speedup vs baseline: 3.4135x; 1.0538x over previous
//
#include <hip/hip_runtime.h>
#include <stdint.h>

typedef unsigned short u16;
typedef float f32x4 __attribute__((ext_vector_type(4)));
typedef __bf16 bf16x8 __attribute__((ext_vector_type(8)));
typedef unsigned short u16x8 __attribute__((ext_vector_type(8)));

#define N1P 6272   // padded concat width: q(1024)|k(1024)|v(2048)|b(16)|a(16)|g(2048)|pad(96)

__device__ __forceinline__ u16 f2bf(float f) {
    union { float f; uint32_t u; } v; v.f = f;
    uint32_t u = v.u;
    return (u16)((u + 0x7FFFu + ((u >> 16) & 1u)) >> 16);
}
__device__ __forceinline__ float bf2f(u16 h) {
    union { uint32_t u; float f; } v; v.u = ((uint32_t)h) << 16; return v.f;
}
__device__ __forceinline__ float sigm(float x) { return 1.f / (1.f + __expf(-x)); }

__device__ __forceinline__ void async16(const u16* g, u16* l) {
    __builtin_amdgcn_global_load_lds((const __attribute__((address_space(1))) void*)g,
                                     (__attribute__((address_space(3))) void*)l, 16, 0, 0);
}

// byte offset inside a [R][64] bf16 "swizzled image": 16B units XOR'd with row&7
__device__ __forceinline__ int swz64(int row, int col) {
    return row * 128 + ((((col >> 3) ^ (row & 7)) << 3) + (col & 7)) * 2;
}
// MFMA fragment read from a swizzled [R][64] bf16 image (rows rowbase..rowbase+15, K-offset kk*32)
__device__ __forceinline__ bf16x8 frag64(const u16* m, int rowbase, int lane, int kk) {
    const int row = rowbase + (lane & 15);
    const int unit = (lane >> 4) + (kk << 2);
    return *(const bf16x8*)((const char*)m + row * 128 + ((unit ^ (row & 7)) << 4));
}

// ---------------- fused transpose + fp32->bf16 convert (all 10 weight matrices, one launch)
// mode 0: dst row = rowOff + n*rowStride ; mode 1: dst row = rowOff + (n>>4)*32 + (n&15)
struct TJob { const float* src; u16* dst; int rows, cols, rowOff, rowStride, nOut, blkBase, gx, mode; };
struct TJobs { TJob j[10]; };

__global__ __launch_bounds__(256) void k_transpose_all(TJobs jobs, int njobs) {
    __shared__ float tile[32][33];
    const int bid = blockIdx.x;
    int ji = 0;
#pragma unroll
    for (int i = 1; i < 10; ++i)
        if (i < njobs && bid >= jobs.j[i].blkBase) ji = i;
    const TJob J = jobs.j[ji];
    const int bx = bid - J.blkBase;
    const int n0 = (bx % J.gx) * 32, k0 = (bx / J.gx) * 32;
    const int tx = threadIdx.x, ty = threadIdx.y;  // 32x8
#pragma unroll
    for (int j = 0; j < 32; j += 8) {
        int r = k0 + ty + j, c = n0 + tx;
        tile[ty + j][tx] = (r < J.rows && c < J.cols) ? J.src[(size_t)r * J.cols + c] : 0.f;
    }
    __syncthreads();
#pragma unroll
    for (int j = 0; j < 32; j += 8) {
        int n = n0 + ty + j, k = k0 + tx;
        if (n < J.nOut) {
            int drow = (J.mode == 0) ? (J.rowOff + n * J.rowStride)
                                     : (J.rowOff + ((n >> 4) << 5) + (n & 15));
            J.dst[(size_t)drow * J.rows + k] = f2bf(tile[tx][ty + j]);
        }
    }
}

// ---------------- rmsnorm over D=1024, fp32 in -> bf16 out
__global__ __launch_bounds__(256) void k_rmsnorm(const float* __restrict__ x, const float* __restrict__ w,
                                                 u16* __restrict__ out) {
    const int row = blockIdx.x, tid = threadIdx.x, lane = tid & 63, wave = tid >> 6;
    const float4 v = ((const float4*)(x + (size_t)row * 1024))[tid];
    float ss = v.x * v.x + v.y * v.y + v.z * v.z + v.w * v.w;
#pragma unroll
    for (int o = 1; o < 64; o <<= 1) ss += __shfl_xor(ss, o);
    __shared__ float sred[4];
    if (lane == 0) sred[wave] = ss;
    __syncthreads();
    const float tot = sred[0] + sred[1] + sred[2] + sred[3];
    const float rn = rsqrtf(tot * (1.f / 1024.f) + 1e-6f);
    const float4 wv = ((const float4*)w)[tid];
    uint2 pk;
    pk.x = (uint32_t)f2bf(v.x * rn * wv.x) | ((uint32_t)f2bf(v.y * rn * wv.y) << 16);
    pk.y = (uint32_t)f2bf(v.z * rn * wv.z) | ((uint32_t)f2bf(v.w * rn * wv.w) << 16);
    *(uint2*)&out[(size_t)row * 1024 + tid * 4] = pk;
}

// ---------------- bf16 GEMM, A[M][K] row-major (M=2048), Bt[N][K] row-major, BK=64, swizzled LDS
// 8 waves (512 thr), double-buffered, issue-early staging, XCD-contiguous 1-D grid.
// EPI: 1 = fp32 + residual (LDS+float4), 2 = bf16 (LDS-coalesced),
//      3 = fused silu(u1)*u3, B group-16-interleaved (no shuffles)
template <int TILE, int EPI>
__global__ __launch_bounds__(512) void k_gemm(const u16* __restrict__ A, const u16* __restrict__ Bt,
                                              void* __restrict__ Cout, const float* __restrict__ Res,
                                              int N, int Kd) {
    __shared__ __align__(16) char smem[TILE * 512];            // As(2) | Bs(2)
    u16* Asb = (u16*)smem;                                     // [2][TILE*64]
    u16* Bsb = (u16*)(smem + TILE * 256);
    constexpr int MB = 2048 / TILE;                  // block count along M (power of 2)
    const int q = (int)gridDim.x >> 3;               // grid divisible by 8
    const int bid = blockIdx.x;
    const int wg = (bid & 7) * q + (bid >> 3);       // XCD x owns contiguous wg chunk
    const int bm = wg & (MB - 1), bn = wg / MB;      // bm fastest -> B-panel locality per XCD
    const int tid = threadIdx.x, lane = tid & 63, wave = tid >> 6;
    const int wm = wave >> 2, wn = wave & 3;         // 2 x 4 wave grid
    constexpr int RS = TILE / 2, CS = TILE / 4;      // per-wave output span
    constexpr int FRM = RS / 16, FRN = CS / 16;
    constexpr int IS = TILE / 64;                    // issue rounds per matrix per K-step

    const int srow = wave * 8 + (lane >> 3);         // 0..63
    const int scol = ((lane & 7) ^ (lane >> 3)) * 8; // pre-swizzled source granule
    const u16* gA = A + (size_t)(bm * TILE + srow) * Kd + scol;
    const u16* gB = Bt + (size_t)(bn * TILE + srow) * Kd + scol;

    f32x4 acc[FRM][FRN] = {};
    const int NT = Kd >> 6;

    // prologue: stage tile 0 into buf 0
#pragma unroll
    for (int j = 0; j < IS; ++j) {
        async16(gA + (size_t)j * 64 * Kd, Asb + j * 4096 + wave * 512);
        async16(gB + (size_t)j * 64 * Kd, Bsb + j * 4096 + wave * 512);
    }
    asm volatile("s_waitcnt vmcnt(0)" ::: "memory");
    __syncthreads();

    int buf = 0;
    for (int t = 0; t < NT; ++t) {
        if (t + 1 < NT) {                            // issue next-tile loads EARLY
            const int k0 = (t + 1) << 6;
            const int bo = (buf ^ 1) * TILE * 64;
#pragma unroll
            for (int j = 0; j < IS; ++j) {
                async16(gA + (size_t)j * 64 * Kd + k0, Asb + bo + j * 4096 + wave * 512);
                async16(gB + (size_t)j * 64 * Kd + k0, Bsb + bo + j * 4096 + wave * 512);
            }
        }
        const u16* Ab = Asb + buf * TILE * 64;
        const u16* Bb = Bsb + buf * TILE * 64;
#pragma unroll
        for (int kk = 0; kk < 2; ++kk) {             // compute current buffer
            bf16x8 af[FRM], bfr[FRN];
#pragma unroll
            for (int mi = 0; mi < FRM; ++mi) af[mi] = frag64(Ab, wm * RS + mi * 16, lane, kk);
#pragma unroll
            for (int ni = 0; ni < FRN; ++ni) bfr[ni] = frag64(Bb, wn * CS + ni * 16, lane, kk);
#pragma unroll
            for (int mi = 0; mi < FRM; ++mi)
#pragma unroll
                for (int ni = 0; ni < FRN; ++ni)
                    acc[mi][ni] = __builtin_amdgcn_mfma_f32_16x16x32_bf16(af[mi], bfr[ni], acc[mi][ni], 0, 0, 0);
        }
        asm volatile("s_waitcnt vmcnt(0)" ::: "memory");   // next-tile loads landed (hidden under MFMA)
        __syncthreads();
        buf ^= 1;
    }

    const int rsub = (lane >> 4) * 4;
    const int csub = lane & 15;

    if constexpr (EPI == 1) {
        // fp32 + residual via padded LDS tile, float4 loads/stores (TILE=64)
        float* ctile = (float*)smem;                 // [64][68]
#pragma unroll
        for (int mi = 0; mi < FRM; ++mi)
#pragma unroll
            for (int ni = 0; ni < FRN; ++ni)
#pragma unroll
                for (int r = 0; r < 4; ++r)
                    ctile[(wm * 32 + mi * 16 + rsub + r) * 68 + wn * 16 + ni * 16 + csub] = acc[mi][ni][r];
        __syncthreads();
#pragma unroll
        for (int k = 0; k < 2; ++k) {
            const int f = (tid + k * 512) * 4;
            const int r = f >> 6, c = f & 63;
            float4 v = *(const float4*)&ctile[r * 68 + c];
            const float4 rv = *(const float4*)&Res[(size_t)(bm * 64 + r) * N + bn * 64 + c];
            v.x += rv.x; v.y += rv.y; v.z += rv.z; v.w += rv.w;
            *(float4*)&((float*)Cout)[(size_t)(bm * 64 + r) * N + bn * 64 + c] = v;
        }
    } else if constexpr (EPI == 2) {
        // bf16 out via padded LDS for coalesced 16B stores (TILE=128)
        u16* ctile = (u16*)smem;                     // [128][132]
#pragma unroll
        for (int mi = 0; mi < FRM; ++mi)
#pragma unroll
            for (int ni = 0; ni < FRN; ++ni)
#pragma unroll
                for (int r = 0; r < 4; ++r)
                    ctile[(wm * 64 + mi * 16 + rsub + r) * 132 + wn * 32 + ni * 16 + csub] =
                        f2bf(acc[mi][ni][r]);
        __syncthreads();
#pragma unroll
        for (int k = 0; k < 4; ++k) {
            const int f = (tid + k * 512) * 8;
            const int r = f >> 7, c = f & 127;
            *(u16x8*)&((u16*)Cout)[(size_t)(bm * 128 + r) * N + bn * 128 + c] =
                *(const u16x8*)&ctile[r * 132 + c];
        }
    } else {
        // EPI==3: B rows group-16 interleaved: ni=0 frag = u1, ni=1 frag = u3, same out col.
        u16* ctile = (u16*)smem;                     // [128][68]
#pragma unroll
        for (int mi = 0; mi < FRM; ++mi)
#pragma unroll
            for (int r = 0; r < 4; ++r) {
                const float u1 = acc[mi][0][r];
                const float u3 = acc[mi][1][r];
                ctile[(wm * 64 + mi * 16 + rsub + r) * 68 + wn * 16 + csub] =
                    f2bf(u1 * sigm(u1) * u3);
            }
        __syncthreads();
#pragma unroll
        for (int k = 0; k < 2; ++k) {
            const int f = (tid + k * 512) * 8;
            const int r = f >> 6, c = f & 63;
            *(u16x8*)&((u16*)Cout)[(size_t)(bm * 128 + r) * N + bn * 64 + c] =
                *(const u16x8*)&ctile[r * 68 + c];
        }
    }
}

// ---------------- depthwise causal conv(4) + silu + l2norm(q,k) + beta / log-decay (vectorized x8)
// XCD-contiguous row swizzle: consecutive rows (sharing conv taps) stay in one XCD's L2.
__global__ __launch_bounds__(256) void k_conv(const u16* __restrict__ P, const float* __restrict__ cwq,
                                              const float* __restrict__ cwk, const float* __restrict__ cwv,
                                              const float* __restrict__ A_log, const float* __restrict__ dtb,
                                              u16* __restrict__ Qb, u16* __restrict__ Kb,
                                              u16* __restrict__ Vb, float* __restrict__ Gl,
                                              float* __restrict__ Bbuf) {
    const int bid = blockIdx.x;
    const int row = (bid & 7) * 256 + (bid >> 3);  // b*1024 + t
    const int t = row & 1023;
    const int tid = threadIdx.x;
    const long prow = (long)row * N1P;
#pragma unroll
    for (int p = 0; p < 2; ++p) {
        const int g = p * 256 + tid;        // col-group of 8 (512 groups = 4096 cols)
        const int c = g * 8;
        u16x8 taps[4];
#pragma unroll
        for (int j = 0; j < 4; ++j) {
            const int tt = t - 3 + j;
            if (tt >= 0) taps[j] = *(const u16x8*)&P[prow + (long)(j - 3) * N1P + c];
            else         taps[j] = u16x8{};
        }
        const float* cw = (c < 1024) ? (cwq + c * 4)
                          : (c < 2048) ? (cwk + (c - 1024) * 4)
                                       : (cwv + (c - 2048) * 4);
        float y[8];
#pragma unroll
        for (int e = 0; e < 8; ++e) {
            const float4 w = ((const float4*)cw)[e];
            float v = bf2f(taps[0][e]) * w.x + bf2f(taps[1][e]) * w.y +
                      bf2f(taps[2][e]) * w.z + bf2f(taps[3][e]) * w.w;
            y[e] = v * sigm(v);
        }
        if (c < 2048) {
            float ss = 0.f;
#pragma unroll
            for (int e = 0; e < 8; ++e) ss += y[e] * y[e];
            ss += __shfl_xor(ss, 1); ss += __shfl_xor(ss, 2); ss += __shfl_xor(ss, 4);
            const float rn = rsqrtf(ss + 1e-6f);
            const float sc = (c < 1024) ? rn * 0.125f : rn;
            u16x8 o;
#pragma unroll
            for (int e = 0; e < 8; ++e) o[e] = f2bf(y[e] * sc);
            if (c < 1024) *(u16x8*)&Qb[(size_t)row * 1024 + c] = o;
            else          *(u16x8*)&Kb[(size_t)row * 1024 + (c - 1024)] = o;
        } else {
            u16x8 o;
#pragma unroll
            for (int e = 0; e < 8; ++e) o[e] = f2bf(y[e]);
            *(u16x8*)&Vb[(size_t)row * 2048 + (c - 2048)] = o;
        }
    }
    if (tid < 32) {
        const int h = tid & 15;
        const float val = bf2f(P[prow + 4096 + tid]);
        if (tid < 16) {
            Bbuf[(size_t)row * 16 + h] = sigm(val);
        } else {
            const float a = val + dtb[h];
            const float sp = (a > 15.f) ? a : log1pf(__expf(a));
            Gl[(size_t)row * 16 + h] = -__expf(A_log[h]) * sp;   // log decay
        }
    }
}

// ---------------- chunked gated delta rule: stage 1 (per b,h,chunk — fully parallel)
// T = (I+A)^{-1} = (I+M0)(I+M1)...(I+M5), M0 = -A, M_j = M_{j-1}^2 (exact, A nilpotent)
__global__ __launch_bounds__(256) void k_scan1(
    const u16* __restrict__ Qb, const u16* __restrict__ Kb, const u16* __restrict__ Vb,
    const float* __restrict__ Gl, const float* __restrict__ Bb,
    u16* __restrict__ CHW, u16* __restrict__ CHM, u16* __restrict__ CHQc,
    u16* __restrict__ CHKcT, u16* __restrict__ CHU0T, float* __restrict__ CHcC) {
    __shared__ __align__(16) char sm[66048];
    u16* Ql   = (u16*)(sm);            // 8KB   (phase<=2a; then low half of fp32 T master)
    u16* Kl   = (u16*)(sm + 8192);     // 8KB   (phase<=2a; then high half of T master)
    u16* VTb  = (u16*)(sm + 16384);    // 16KB
    u16* KT1b = (u16*)(sm + 32768);    // 8KB
    u16* Mim  = (u16*)(sm + 40960);    // 8KB   M_j image (in-place squared)
    u16* MTim = (u16*)(sm + 49152);    // 8KB   M_j^T image
    u16* Tb   = (u16*)(sm + 57344);    // 8KB   bf16 T image (per-wave-owned rows)
    float* Tl    = (float*)sm;         // 16KB fp32 T master, overlays Ql+Kl after 2a
    float* gcs   = (float*)(sm + 65536);
    float* betal = (float*)(sm + 65792);

    const int blk = blockIdx.x;                      // bb*256 + h*16 + ch
    const int bb = blk >> 8, h = (blk >> 4) & 15, ch = blk & 15;
    const int bhc = blk;
    const int tid = threadIdx.x, lane = tid & 63, wave = tid >> 6;
    const long rowbase = (long)bb * 1024 + ch * 64;

    // phase 0: stage K,Q swizzled; load per-row gate scalars
    if (tid < 64) {
        gcs[tid] = Gl[(rowbase + tid) * 16 + h];
        betal[tid] = Bb[(rowbase + tid) * 16 + h];
    }
    for (int u = tid; u < 512; u += 256) {
        int r = u >> 3, c8 = u & 7;
        uint4 kv = *(const uint4*)&Kb[(rowbase + r) * 1024 + h * 64 + c8 * 8];
        uint4 qv = *(const uint4*)&Qb[(rowbase + r) * 1024 + h * 64 + c8 * 8];
        int b = r * 128 + ((c8 ^ (r & 7)) << 4);
        *(uint4*)((char*)Kl + b) = kv;
        *(uint4*)((char*)Ql + b) = qv;
    }
    __syncthreads();
    // phase 1: cumsum (wave 0); VTb build; QK^T / KK^T
    if (wave == 0) {
        float g = gcs[lane];
#pragma unroll
        for (int off = 1; off < 64; off <<= 1) {
            float n = __shfl_up(g, off, 64);
            if (lane >= off) g += n;
        }
        gcs[lane] = g;
    }
    for (int u = tid; u < 1024; u += 256) {          // VTb[dv][c] = beta_c * V[c][dv]
        int r = u >> 4, c8 = u & 15;
        u16x8 vv = *(const u16x8*)&Vb[(rowbase + r) * 2048 + h * 128 + c8 * 8];
        float bsc = betal[r];
#pragma unroll
        for (int j = 0; j < 8; ++j) {
            int dv = c8 * 8 + j;
            *(u16*)((char*)VTb + swz64(dv, r)) = f2bf(bf2f(vv[j]) * bsc);
        }
    }
    f32x4 aQK[4] = {}, aKK[4] = {};
#pragma unroll
    for (int nt = 0; nt < 4; ++nt)
#pragma unroll
        for (int kk = 0; kk < 2; ++kk) {
            bf16x8 bq = frag64(Kl, nt * 16, lane, kk);
            aQK[nt] = __builtin_amdgcn_mfma_f32_16x16x32_bf16(frag64(Ql, wave * 16, lane, kk), bq, aQK[nt], 0, 0, 0);
            aKK[nt] = __builtin_amdgcn_mfma_f32_16x16x32_bf16(frag64(Kl, wave * 16, lane, kk), bq, aKK[nt], 0, 0, 0);
        }
    __syncthreads();   // gcs + VTb published

    // phase 2a: CHM, M0 = -A images, CHQc, KT1b, CHKcT (reads Ql/Kl)
    const float gcsC = gcs[63];
    float am[4][4];    // keep -A values for phase 2b
#pragma unroll
    for (int nt = 0; nt < 4; ++nt)
#pragma unroll
        for (int reg = 0; reg < 4; ++reg) {
            int t = wave * 16 + ((lane >> 4) << 2) + reg;
            int i = nt * 16 + (lane & 15);
            float dec = __expf(gcs[t] - gcs[i]);
            float mv = (i <= t) ? dec * aQK[nt][reg] : 0.f;
            *(u16*)((char*)CHM + (size_t)bhc * 8192 + swz64(t, i)) = f2bf(mv);
            float a = (i < t) ? betal[t] * dec * aKK[nt][reg] : 0.f;
            am[nt][reg] = -a;
            u16 amb = f2bf(-a);
            *(u16*)((char*)Mim + swz64(t, i)) = amb;
            *(u16*)((char*)MTim + swz64(i, t)) = amb;
        }
    for (int e = tid; e < 4096; e += 256) {
        int r = e >> 6, c = e & 63;
        int ib = swz64(r, c);
        float qv = bf2f(*(const u16*)((const char*)Ql + ib)) * __expf(gcs[r]);
        *(u16*)((char*)CHQc + (size_t)bhc * 8192 + ib) = f2bf(qv);
        float kv = bf2f(*(const u16*)((const char*)Kl + ib));
        int ob = swz64(c, r);
        *(u16*)((char*)KT1b + ob) = f2bf(kv * betal[r] * __expf(gcs[r]));
        *(u16*)((char*)CHKcT + (size_t)bhc * 8192 + ob) = f2bf(kv * __expf(gcsC - gcs[r]));
    }
    if (tid == 0) CHcC[bhc] = __expf(gcsC);
    __syncthreads();   // Ql/Kl dead; Tl overlay becomes safe

    // phase 2b: T0 = I + M0 = I - A  (fp32 master + bf16 image, own rows)
#pragma unroll
    for (int nt = 0; nt < 4; ++nt)
#pragma unroll
        for (int reg = 0; reg < 4; ++reg) {
            int t = wave * 16 + ((lane >> 4) << 2) + reg;
            int i = nt * 16 + (lane & 15);
            float tv = (t == i) ? 1.f : am[nt][reg];
            Tl[t * 64 + i] = tv;
            *(u16*)((char*)Tb + swz64(t, i)) = f2bf(tv);
        }
    __syncthreads();

    // phase 3: doubling. stage j: M <- M^2 (in place), then T <- T + T*M.
    const int hi = wave * 16 + 15;
#pragma unroll
    for (int j = 1; j <= 5; ++j) {
        // square M (read Mim own rows as A-op, MTim all rows as B-op)
        f32x4 aM[4] = {};
#pragma unroll
        for (int nt = 0; nt < 4; ++nt) {
            if (nt * 16 > hi - (1 << j)) continue;
#pragma unroll
            for (int kk = 0; kk < 2; ++kk) {
                if (kk * 32 > hi) break;
                aM[nt] = __builtin_amdgcn_mfma_f32_16x16x32_bf16(
                    frag64(Mim, wave * 16, lane, kk), frag64(MTim, nt * 16, lane, kk), aM[nt], 0, 0, 0);
            }
        }
        __syncthreads();   // all reads of M_{j-1} done
        // write M_j in place (ALL entries — masked zeros, no stale data)
#pragma unroll
        for (int nt = 0; nt < 4; ++nt)
#pragma unroll
            for (int reg = 0; reg < 4; ++reg) {
                int t = wave * 16 + ((lane >> 4) << 2) + reg;
                int i = nt * 16 + (lane & 15);
                float mv = (t - i >= (1 << j)) ? aM[nt][reg] : 0.f;
                u16 mb = f2bf(mv);
                *(u16*)((char*)Mim + swz64(t, i)) = mb;
                *(u16*)((char*)MTim + swz64(i, t)) = mb;
            }
        __syncthreads();   // M_j published
        // T update: aT = T (fp32 master) + T*M_j ; own rows only -> no barrier needed after
        f32x4 aT[4];
#pragma unroll
        for (int nt = 0; nt < 4; ++nt)
#pragma unroll
            for (int reg = 0; reg < 4; ++reg) {
                int t = wave * 16 + ((lane >> 4) << 2) + reg;
                int i = nt * 16 + (lane & 15);
                aT[nt][reg] = Tl[t * 64 + i];
            }
#pragma unroll
        for (int nt = 0; nt < 4; ++nt) {
            if (nt * 16 > hi - (1 << j)) continue;
#pragma unroll
            for (int kk = 0; kk < 2; ++kk) {
                if (kk * 32 > hi) break;
                aT[nt] = __builtin_amdgcn_mfma_f32_16x16x32_bf16(
                    frag64(Tb, wave * 16, lane, kk), frag64(MTim, nt * 16, lane, kk), aT[nt], 0, 0, 0);
            }
        }
#pragma unroll
        for (int nt = 0; nt < 4; ++nt)
#pragma unroll
            for (int reg = 0; reg < 4; ++reg) {
                int t = wave * 16 + ((lane >> 4) << 2) + reg;
                int i = nt * 16 + (lane & 15);
                Tl[t * 64 + i] = aT[nt][reg];
                *(u16*)((char*)Tb + swz64(t, i)) = f2bf(aT[nt][reg]);
            }
    }
    __syncthreads();   // U0T below reads other waves' Tb rows

    // final: W = T @ (beta*c*K);  U0T = (beta*V)^T @ T^T
    {
        f32x4 aW[4] = {};
#pragma unroll
        for (int nt = 0; nt < 4; ++nt)
#pragma unroll
            for (int kk = 0; kk < 2; ++kk) {
                if (kk * 32 > hi) break;   // T[t][k] zero for k > t
                aW[nt] = __builtin_amdgcn_mfma_f32_16x16x32_bf16(
                    frag64(Tb, wave * 16, lane, kk), frag64(KT1b, nt * 16, lane, kk), aW[nt], 0, 0, 0);
            }
#pragma unroll
        for (int nt = 0; nt < 4; ++nt)
#pragma unroll
            for (int reg = 0; reg < 4; ++reg) {
                int r = wave * 16 + ((lane >> 4) << 2) + reg;
                int c = nt * 16 + (lane & 15);
                *(u16*)((char*)CHW + (size_t)bhc * 8192 + swz64(r, c)) = f2bf(aW[nt][reg]);
            }
    }
#pragma unroll
    for (int rt = 0; rt < 2; ++rt) {
        f32x4 aU[4] = {};
        int rb = (wave * 2 + rt) * 16;
#pragma unroll
        for (int nt = 0; nt < 4; ++nt)
#pragma unroll
            for (int kk = 0; kk < 2; ++kk) {
                if (kk * 32 > nt * 16 + 15) continue;  // T[c][k] zero for k > c
                aU[nt] = __builtin_amdgcn_mfma_f32_16x16x32_bf16(
                    frag64(VTb, rb, lane, kk), frag64(Tb, nt * 16, lane, kk), aU[nt], 0, 0, 0);
            }
#pragma unroll
        for (int nt = 0; nt < 4; ++nt)
#pragma unroll
            for (int reg = 0; reg < 4; ++reg) {
                int dv = rb + ((lane >> 4) << 2) + reg;
                int c = nt * 16 + (lane & 15);
                *(u16*)((char*)CHU0T + (size_t)bhc * 16384 + swz64(dv, c)) = f2bf(aU[nt][reg]);
            }
    }
}

// ---------------- chunked gated delta rule: stage 2 (sequential over 16 chunks; block = b,h,dv-half)
__global__ __launch_bounds__(256) void k_scan2(
    const u16* __restrict__ CHW, const u16* __restrict__ CHM, const u16* __restrict__ CHQc,
    const u16* __restrict__ CHKcT, const u16* __restrict__ CHU0T, const float* __restrict__ CHcC,
    float* __restrict__ O) {
    __shared__ __align__(16) u16 stg[2][5 * 4096];
    __shared__ __align__(16) u16 STb[4096], uTl[4096];
    __shared__ float ST[64 * 66];
    const int blk = blockIdx.x;
    const int bb = blk >> 5, h = (blk >> 1) & 15, dvh = blk & 1;
    const int bh = bb * 16 + h;
    const int tid = threadIdx.x, lane = tid & 63, wave = tid >> 6;

    for (int e = tid; e < 64 * 66; e += 256) ST[e] = 0.f;
    for (int e = tid; e < 4096; e += 256) STb[e] = 0;

    auto stage = [&](int buf, int ch) {
        const size_t base = (size_t)(bh * 16 + ch);
        const u16* srcs[5] = { CHW + base * 4096, CHM + base * 4096, CHQc + base * 4096,
                               CHKcT + base * 4096, CHU0T + base * 8192 + dvh * 4096 };
#pragma unroll
        for (int s = 0; s < 5; ++s)
#pragma unroll
            for (int r = 0; r < 2; ++r) {
                int ub = r * 256 + wave * 64;
                async16(srcs[s] + (size_t)(ub + lane) * 8, &stg[buf][s * 4096 + ub * 8]);
            }
    };
    stage(0, 0);
    for (int ch = 0; ch < 16; ++ch) {
        const int cur = ch & 1;
        asm volatile("s_waitcnt vmcnt(0)" ::: "memory");
        __syncthreads();
        if (ch < 15) stage(cur ^ 1, ch + 1);
        const u16* sW = &stg[cur][0];
        const u16* sM = &stg[cur][4096];
        const u16* sQc = &stg[cur][8192];
        const u16* sKcT = &stg[cur][12288];
        const u16* sU0 = &stg[cur][16384];
        // phase A: uT = U0T - (S0 W^T)    [rows dv]
        {
            f32x4 acc[4] = {};
#pragma unroll
            for (int nt = 0; nt < 4; ++nt)
#pragma unroll
                for (int kk = 0; kk < 2; ++kk)
                    acc[nt] = __builtin_amdgcn_mfma_f32_16x16x32_bf16(
                        frag64(STb, wave * 16, lane, kk), frag64(sW, nt * 16, lane, kk), acc[nt], 0, 0, 0);
#pragma unroll
            for (int nt = 0; nt < 4; ++nt)
#pragma unroll
                for (int reg = 0; reg < 4; ++reg) {
                    int dv = wave * 16 + ((lane >> 4) << 2) + reg;
                    int c = nt * 16 + (lane & 15);
                    int b = swz64(dv, c);
                    float u0 = bf2f(*(const u16*)((const char*)sU0 + b));
                    *(u16*)((char*)uTl + b) = f2bf(u0 - acc[nt][reg]);
                }
        }
        __syncthreads();
        // phase B: O = M@u + Qc@S0 (rows c); Sacc = u^T-rows-dv @ KcT (rows dv)
        f32x4 accO[4] = {}, accS[4] = {};
#pragma unroll
        for (int nt = 0; nt < 4; ++nt)
#pragma unroll
            for (int kk = 0; kk < 2; ++kk) {
                accO[nt] = __builtin_amdgcn_mfma_f32_16x16x32_bf16(
                    frag64(sM, wave * 16, lane, kk), frag64(uTl, nt * 16, lane, kk), accO[nt], 0, 0, 0);
                accO[nt] = __builtin_amdgcn_mfma_f32_16x16x32_bf16(
                    frag64(sQc, wave * 16, lane, kk), frag64(STb, nt * 16, lane, kk), accO[nt], 0, 0, 0);
                accS[nt] = __builtin_amdgcn_mfma_f32_16x16x32_bf16(
                    frag64(uTl, wave * 16, lane, kk), frag64(sKcT, nt * 16, lane, kk), accS[nt], 0, 0, 0);
            }
        __syncthreads();
        // phase C: write O; update state
        const float cC = CHcC[bh * 16 + ch];
#pragma unroll
        for (int nt = 0; nt < 4; ++nt)
#pragma unroll
            for (int reg = 0; reg < 4; ++reg) {
                int rr = wave * 16 + ((lane >> 4) << 2) + reg;
                int cc = nt * 16 + (lane & 15);
                O[((size_t)(bb * 1024 + ch * 64 + rr)) * 2048 + h * 128 + dvh * 64 + cc] = accO[nt][reg];
                float ns = cC * ST[rr * 66 + cc] + accS[nt][reg];
                ST[rr * 66 + cc] = ns;
                *(u16*)((char*)STb + swz64(rr, cc)) = f2bf(ns);
            }
    }
}

// ---------------- per-head RMSNorm(o) * gate * sigmoid(gate) -> bf16
__global__ __launch_bounds__(256) void k_gate(const float* __restrict__ O, const u16* __restrict__ P,
                                              const float* __restrict__ onw, u16* __restrict__ OG) {
    const int row = blockIdx.x;
    const int tid = threadIdx.x, lane = tid & 63, wave = tid >> 6;
#pragma unroll
    for (int p = 0; p < 4; ++p) {
        const int h = p * 4 + wave;
        const int dv = lane * 2;
        const float2 o2 = *(const float2*)&O[(size_t)row * 2048 + h * 128 + dv];
        float ss = o2.x * o2.x + o2.y * o2.y;
#pragma unroll
        for (int o = 1; o < 64; o <<= 1) ss += __shfl_xor(ss, o);
        const float rn = rsqrtf(ss * (1.f / 128.f) + 1e-6f);
        const float g0 = bf2f(P[(size_t)row * N1P + 4128 + h * 128 + dv]);
        const float g1 = bf2f(P[(size_t)row * N1P + 4128 + h * 128 + dv + 1]);
        const float r0 = o2.x * rn * onw[dv] * g0 * sigm(g0);
        const float r1 = o2.y * rn * onw[dv + 1] * g1 * sigm(g1);
        const uint32_t pk = (uint32_t)f2bf(r0) | ((uint32_t)f2bf(r1) << 16);
        *(uint32_t*)&OG[(size_t)row * 2048 + h * 128 + dv] = pk;
    }
}

extern "C" void kernel_launch(void* const* d_in, const int* in_sizes, int n_in,
                              void* d_out, int out_size, void* d_ws, size_t ws_size,
                              hipStream_t stream) {
    const float* x   = (const float*)d_in[0];
    const float* n1w = (const float*)d_in[1];
    const float* wq  = (const float*)d_in[2];
    const float* wk  = (const float*)d_in[3];
    const float* wv  = (const float*)d_in[4];
    const float* cq  = (const float*)d_in[5];
    const float* ck  = (const float*)d_in[6];
    const float* cv  = (const float*)d_in[7];
    const float* wb  = (const float*)d_in[8];
    const float* wa  = (const float*)d_in[9];
    const float* Alg = (const float*)d_in[10];
    const float* dtb = (const float*)d_in[11];
    const float* wg  = (const float*)d_in[12];
    const float* onw = (const float*)d_in[13];
    const float* wo  = (const float*)d_in[14];
    const float* n2w = (const float*)d_in[15];
    const float* w1  = (const float*)d_in[16];
    const float* w2  = (const float*)d_in[17];
    const float* w3  = (const float*)d_in[18];

    if (ws_size < 114819072ULL) return;

    char* ws = (char*)d_ws;
    u16*   WcatT = (u16*)(ws + 0);            // [6272][1024] bf16 (CHW/CHM/CHQc reuse)
    u16*   WoT   = (u16*)(ws + 12845056);     // [1024][2048]
    u16*   W13T  = (u16*)(ws + 17039360);     // [5632][1024] group-16 interleaved w1/w3
    u16*   W2T   = (u16*)(ws + 28573696);     // [1024][2816]
    u16*   hA    = (u16*)(ws + 34340864);     // [2048][1024] (h2A reuse)
    u16*   P     = (u16*)(ws + 38535168);     // [2048][6272]
    u16*   Qb    = (u16*)(ws + 64225280);     // [2048][1024] bf16 (Mm reuse)
    u16*   Kb    = (u16*)(ws + 68419584);     // [2048][1024] bf16
    u16*   Vb    = (u16*)(ws + 72613888);     // [2048][2048] bf16 (OG reuse)
    float* Gl    = (float*)(ws + 81002496);   // [2048][16] log decay
    float* Bbf   = (float*)(ws + 81133568);   // [2048][16]
    float* O     = (float*)(ws + 81264640);   // [2048][2048] fp32 (X2 reuse)
    u16*   CHKcT = (u16*)(ws + 98041856);     // [512][64][64] bf16 image
    u16*   CHU0T = (u16*)(ws + 102236160);    // [512][128][64] bf16 image
    float* CHcC  = (float*)(ws + 110624768);  // [512]
    u16*   CHW   = WcatT;                     // [512][64][64] image
    u16*   CHM   = (u16*)(ws + 4194304);
    u16*   CHQc  = (u16*)(ws + 8388608);
    u16*   Mm  = Qb;                          // [2048][2816] bf16 (spans Qb/Kb/part of Vb — dead by then)
    u16*   OG  = Vb;
    float* X2  = O;
    u16*   h2A = hA;

    // fused weight transposes (fp32 [K][N] -> bf16 [N][K]) in one launch
    TJobs tj;
    tj.j[0] = { wq, WcatT, 1024, 1024,    0, 1, 1024,     0, 32, 0 };
    tj.j[1] = { wk, WcatT, 1024, 1024, 1024, 1, 1024,  1024, 32, 0 };
    tj.j[2] = { wv, WcatT, 1024, 2048, 2048, 1, 2048,  2048, 64, 0 };
    tj.j[3] = { wb, WcatT, 1024,   16, 4096, 1,   16,  4096,  1, 0 };
    tj.j[4] = { wa, WcatT, 1024,   16, 4112, 1,   16,  4128,  1, 0 };
    tj.j[5] = { wg, WcatT, 1024, 2048, 4128, 1, 2144,  4160, 67, 0 };
    tj.j[6] = { wo, WoT,   2048, 1024,    0, 1, 1024,  6304, 32, 0 };
    tj.j[7] = { w1, W13T,  1024, 2816,    0, 1, 2816,  8352, 88, 1 };   // group-16 even
    tj.j[8] = { w3, W13T,  1024, 2816,   16, 1, 2816, 11168, 88, 1 };   // group-16 odd
    tj.j[9] = { w2, W2T,   2816, 1024,    0, 1, 1024, 13984, 32, 0 };
    k_transpose_all<<<16800, dim3(32, 8), 0, stream>>>(tj, 10);

    k_rmsnorm<<<2048, 256, 0, stream>>>(x, n1w, hA);
    k_gemm<128, 2><<<784, 512, 0, stream>>>(hA, WcatT, P, nullptr, N1P, 1024);

    k_conv<<<2048, 256, 0, stream>>>(P, cq, ck, cv, Alg, dtb, Qb, Kb, Vb, Gl, Bbf);

    k_scan1<<<512, 256, 0, stream>>>(Qb, Kb, Vb, Gl, Bbf, CHW, CHM, CHQc, CHKcT, CHU0T, CHcC);
    k_scan2<<<64, 256, 0, stream>>>(CHW, CHM, CHQc, CHKcT, CHU0T, CHcC, O);

    k_gate<<<2048, 256, 0, stream>>>(O, P, onw, OG);
    k_gemm<64, 1><<<512, 512, 0, stream>>>(OG, WoT, X2, x, 1024, 2048);

    k_rmsnorm<<<2048, 256, 0, stream>>>(X2, n2w, h2A);
    k_gemm<128, 3><<<704, 512, 0, stream>>>(h2A, W13T, Mm, nullptr, 2816, 1024);  // fused silu(u1)*u3
    k_gemm<64, 1><<<512, 512, 0, stream>>>(Mm, W2T, (float*)d_out, X2, 1024, 2816);
}

// Round 10
// 242.283 us; speedup vs baseline: 3.4875x; 1.0217x over previous
//
#include <hip/hip_runtime.h>
#include <stdint.h>

typedef unsigned short u16;
typedef float f32x4 __attribute__((ext_vector_type(4)));
typedef __bf16 bf16x8 __attribute__((ext_vector_type(8)));
typedef unsigned short u16x8 __attribute__((ext_vector_type(8)));

#define N1P 6400   // padded concat width: q(1024)|k(1024)|v(2048)|b(16)|a(16)|g(2048)|pad(224)

__device__ __forceinline__ u16 f2bf(float f) {
    union { float f; uint32_t u; } v; v.f = f;
    uint32_t u = v.u;
    return (u16)((u + 0x7FFFu + ((u >> 16) & 1u)) >> 16);
}
__device__ __forceinline__ float bf2f(u16 h) {
    union { uint32_t u; float f; } v; v.u = ((uint32_t)h) << 16; return v.f;
}
__device__ __forceinline__ float sigm(float x) { return 1.f / (1.f + __expf(-x)); }

__device__ __forceinline__ void async16(const u16* g, u16* l) {
    __builtin_amdgcn_global_load_lds((const __attribute__((address_space(1))) void*)g,
                                     (__attribute__((address_space(3))) void*)l, 16, 0, 0);
}

// byte offset inside a [R][64] bf16 "swizzled image": 16B units XOR'd with row&7
__device__ __forceinline__ int swz64(int row, int col) {
    return row * 128 + ((((col >> 3) ^ (row & 7)) << 3) + (col & 7)) * 2;
}
// MFMA fragment read from a swizzled [R][64] bf16 image (rows rowbase..rowbase+15, K-offset kk*32)
__device__ __forceinline__ bf16x8 frag64(const u16* m, int rowbase, int lane, int kk) {
    const int row = rowbase + (lane & 15);
    const int unit = (lane >> 4) + (kk << 2);
    return *(const bf16x8*)((const char*)m + row * 128 + ((unit ^ (row & 7)) << 4));
}

// ---------------- fused transpose + fp32->bf16 convert (all 10 weight matrices, one launch)
// mode 0: dst row = rowOff + n*rowStride ; mode 1: dst row = rowOff + (n>>4)*32 + (n&15)
struct TJob { const float* src; u16* dst; int rows, cols, rowOff, rowStride, nOut, blkBase, gx, mode; };
struct TJobs { TJob j[10]; };

__global__ __launch_bounds__(256) void k_transpose_all(TJobs jobs, int njobs) {
    __shared__ float tile[32][33];
    const int bid = blockIdx.x;
    int ji = 0;
#pragma unroll
    for (int i = 1; i < 10; ++i)
        if (i < njobs && bid >= jobs.j[i].blkBase) ji = i;
    const TJob J = jobs.j[ji];
    const int bx = bid - J.blkBase;
    const int n0 = (bx % J.gx) * 32, k0 = (bx / J.gx) * 32;
    const int tx = threadIdx.x, ty = threadIdx.y;  // 32x8
#pragma unroll
    for (int j = 0; j < 32; j += 8) {
        int r = k0 + ty + j, c = n0 + tx;
        tile[ty + j][tx] = (r < J.rows && c < J.cols) ? J.src[(size_t)r * J.cols + c] : 0.f;
    }
    __syncthreads();
#pragma unroll
    for (int j = 0; j < 32; j += 8) {
        int n = n0 + ty + j, k = k0 + tx;
        if (n < J.nOut) {
            int drow = (J.mode == 0) ? (J.rowOff + n * J.rowStride)
                                     : (J.rowOff + ((n >> 4) << 5) + (n & 15));
            J.dst[(size_t)drow * J.rows + k] = f2bf(tile[tx][ty + j]);
        }
    }
}

// ---------------- rmsnorm over D=1024, fp32 in -> bf16 out
__global__ __launch_bounds__(256) void k_rmsnorm(const float* __restrict__ x, const float* __restrict__ w,
                                                 u16* __restrict__ out) {
    const int row = blockIdx.x, tid = threadIdx.x, lane = tid & 63, wave = tid >> 6;
    const float4 v = ((const float4*)(x + (size_t)row * 1024))[tid];
    float ss = v.x * v.x + v.y * v.y + v.z * v.z + v.w * v.w;
#pragma unroll
    for (int o = 1; o < 64; o <<= 1) ss += __shfl_xor(ss, o);
    __shared__ float sred[4];
    if (lane == 0) sred[wave] = ss;
    __syncthreads();
    const float tot = sred[0] + sred[1] + sred[2] + sred[3];
    const float rn = rsqrtf(tot * (1.f / 1024.f) + 1e-6f);
    const float4 wv = ((const float4*)w)[tid];
    uint2 pk;
    pk.x = (uint32_t)f2bf(v.x * rn * wv.x) | ((uint32_t)f2bf(v.y * rn * wv.y) << 16);
    pk.y = (uint32_t)f2bf(v.z * rn * wv.z) | ((uint32_t)f2bf(v.w * rn * wv.w) << 16);
    *(uint2*)&out[(size_t)row * 1024 + tid * 4] = pk;
}

// ---------------- 256x256 8-phase GEMM (T2+T3+T4+T5), BK=64, 8 waves (2Mx4N), wave tile 128x64.
// A[2048][Kd] bf16 row-major, Bt[N'][Kd] bf16 row-major. Kd must be multiple of 128.
// EPI 2 = bf16 store (width N); EPI 3 = fused silu(u1)*u3, B group-16-interleaved (out width N)
template <int EPI>
__global__ __launch_bounds__(512, 2) void k_gemm256(const u16* __restrict__ A, const u16* __restrict__ Bt,
                                                    u16* __restrict__ Cout, int N, int Kd) {
    __shared__ __align__(16) u16 L[65536];   // 128KB: buf{0,1} x (A 256x64 | B 256x64) swizzled images
    const int q8 = (int)gridDim.x >> 3;
    const int bid = blockIdx.x;
    const int wg = (bid & 7) * q8 + (bid >> 3);      // XCD-contiguous
    const int bm = wg & 7, bn = wg >> 3;             // M blocks = 2048/256 = 8
    const int tid = threadIdx.x, lane = tid & 63, wave = tid >> 6;
    const int wm = wave >> 2, wn = wave & 3;         // 2 x 4 wave grid

    const int scol = ((tid & 7) ^ ((tid >> 3) & 7)) * 8;  // pre-swizzled source granule
    const u16* gA = A + (size_t)(bm * 256 + (tid >> 3)) * Kd + scol;
    const u16* gB = Bt + (size_t)(bn * 256 + (tid >> 3)) * Kd + scol;
    u16* dstT = L + tid * 8;

    const int NT = Kd >> 6;
    const int NI = NT >> 1;

    auto issue = [&](const u16* g, int mtx, int kt, int h) {   // one half-tile = 2 gloads/thread
        u16* d = dstT + (kt & 1) * 32768 + mtx * 16384 + h * 8192;
        const u16* s = g + (size_t)(h * 128) * Kd + kt * 64;
        async16(s, d);
        async16(s + (size_t)64 * Kd, d + 4096);
    };

    // prologue: B(0),A(0) -> buf0 ; B(1) -> buf1 ; A(1) arrives via steady-state p0/p1 issues
    issue(gB, 1, 0, 0); issue(gB, 1, 0, 1);
    issue(gA, 0, 0, 0); issue(gA, 0, 0, 1);
    issue(gB, 1, 1, 0); issue(gB, 1, 1, 1);
    asm volatile("s_waitcnt vmcnt(4)" ::: "memory");   // tile0 landed
    __builtin_amdgcn_s_barrier();

    f32x4 acc[8][4] = {};
    bf16x8 bq[4][2];

    for (int i = 0; i < NI; ++i) {
        const int kt0 = 2 * i;
#pragma unroll
        for (int p = 0; p < 8; ++p) {
            const int half = p >> 2;                 // 0: tile 2i (buf0), 1: tile 2i+1 (buf1)
            const int q = p & 3;                     // C-quadrant (mi pair)
            const u16* Ab = L + half * 32768;
            const u16* Bb = L + half * 32768 + 16384;
            // ds-load register subtile (B cached for whole K-tile at q==0)
            if (q == 0) {
#pragma unroll
                for (int ni = 0; ni < 4; ++ni)
#pragma unroll
                    for (int kk = 0; kk < 2; ++kk)
                        bq[ni][kk] = frag64(Bb, wn * 64 + ni * 16, lane, kk);
            }
            bf16x8 af[2][2];
#pragma unroll
            for (int j = 0; j < 2; ++j)
#pragma unroll
                for (int kk = 0; kk < 2; ++kk)
                    af[j][kk] = frag64(Ab, wm * 128 + (2 * q + j) * 16, lane, kk);
            // prefetch issues (regions proven free >=1 barrier earlier)
            if (p == 0) { if (kt0 + 1 < NT) issue(gA, 0, kt0 + 1, 0); }
            if (p == 1) { if (kt0 + 1 < NT) issue(gA, 0, kt0 + 1, 1);
                          if (kt0 + 2 < NT) issue(gB, 1, kt0 + 2, 0); }
            if (p == 2) { if (kt0 + 2 < NT) issue(gB, 1, kt0 + 2, 1); }
            if (p == 4) { if (kt0 + 2 < NT) issue(gA, 0, kt0 + 2, 0); }
            if (p == 5) { if (kt0 + 2 < NT) issue(gA, 0, kt0 + 2, 1);
                          if (kt0 + 3 < NT) issue(gB, 1, kt0 + 3, 0); }
            if (p == 6) { if (kt0 + 3 < NT) issue(gB, 1, kt0 + 3, 1); }
            // counted waits: confirm tile 2i+1 at p3, tile 2i+2 at p7 (consumed after 2 barriers)
            if (p == 3) { if (i + 1 < NI) { asm volatile("s_waitcnt vmcnt(4)" ::: "memory"); }
                          else            { asm volatile("s_waitcnt vmcnt(0)" ::: "memory"); } }
            if (p == 7) { if (i + 1 < NI) { asm volatile("s_waitcnt vmcnt(4)" ::: "memory"); } }
            __builtin_amdgcn_s_barrier();
            __builtin_amdgcn_s_setprio(1);
#pragma unroll
            for (int j = 0; j < 2; ++j)
#pragma unroll
                for (int ni = 0; ni < 4; ++ni)
#pragma unroll
                    for (int kk = 0; kk < 2; ++kk)
                        acc[2 * q + j][ni] = __builtin_amdgcn_mfma_f32_16x16x32_bf16(
                            af[j][kk], bq[ni][kk], acc[2 * q + j][ni], 0, 0, 0);
            __builtin_amdgcn_s_setprio(0);
            __builtin_amdgcn_s_barrier();
        }
    }

    const int rsub = (lane >> 4) * 4, csub = lane & 15;
    if constexpr (EPI == 2) {
        u16* ct = L;                                 // [128][264] staged per wm-round
#pragma unroll
        for (int r = 0; r < 2; ++r) {
            if (wm == r) {
#pragma unroll
                for (int mi = 0; mi < 8; ++mi)
#pragma unroll
                    for (int ni = 0; ni < 4; ++ni)
#pragma unroll
                        for (int rr = 0; rr < 4; ++rr)
                            ct[(mi * 16 + rsub + rr) * 264 + wn * 64 + ni * 16 + csub] =
                                f2bf(acc[mi][ni][rr]);
            }
            __syncthreads();
#pragma unroll
            for (int k = 0; k < 8; ++k) {
                const int f = (tid + k * 512) * 8;
                const int r2 = f >> 8, c = f & 255;
                *(u16x8*)&Cout[(size_t)(bm * 256 + r * 128 + r2) * N + bn * 256 + c] =
                    *(const u16x8*)&ct[r2 * 264 + c];
            }
            __syncthreads();
        }
    } else {
        // EPI==3: ni pair {2g,2g+1} = (u1,u3) of same out cols; out width N, block out 256x128
        u16* ct = L;                                 // [256][132]
#pragma unroll
        for (int mi = 0; mi < 8; ++mi)
#pragma unroll
            for (int g = 0; g < 2; ++g)
#pragma unroll
                for (int rr = 0; rr < 4; ++rr) {
                    const float u1 = acc[mi][2 * g][rr];
                    const float u3 = acc[mi][2 * g + 1][rr];
                    ct[(wm * 128 + mi * 16 + rsub + rr) * 132 + wn * 32 + g * 16 + csub] =
                        f2bf(u1 * sigm(u1) * u3);
                }
        __syncthreads();
#pragma unroll
        for (int k = 0; k < 8; ++k) {
            const int f = (tid + k * 512) * 8;
            const int r2 = f >> 7, c = f & 127;
            *(u16x8*)&Cout[(size_t)(bm * 256 + r2) * N + bn * 128 + c] =
                *(const u16x8*)&ct[r2 * 132 + c];
        }
    }
}

// ---------------- 2-phase bf16 GEMM (skinny N): TILE=64, 8 waves, dbuf, fp32 + residual epilogue
template <int TILE, int EPI>
__global__ __launch_bounds__(512) void k_gemm(const u16* __restrict__ A, const u16* __restrict__ Bt,
                                              void* __restrict__ Cout, const float* __restrict__ Res,
                                              int N, int Kd) {
    __shared__ __align__(16) char smem[TILE * 512];            // As(2) | Bs(2)
    u16* Asb = (u16*)smem;                                     // [2][TILE*64]
    u16* Bsb = (u16*)(smem + TILE * 256);
    constexpr int MB = 2048 / TILE;
    const int q = (int)gridDim.x >> 3;
    const int bid = blockIdx.x;
    const int wg = (bid & 7) * q + (bid >> 3);
    const int bm = wg & (MB - 1), bn = wg / MB;
    const int tid = threadIdx.x, lane = tid & 63, wave = tid >> 6;
    const int wm = wave >> 2, wn = wave & 3;
    constexpr int RS = TILE / 2, CS = TILE / 4;
    constexpr int FRM = RS / 16, FRN = CS / 16;
    constexpr int IS = TILE / 64;

    const int srow = wave * 8 + (lane >> 3);
    const int scol = ((lane & 7) ^ (lane >> 3)) * 8;
    const u16* gA = A + (size_t)(bm * TILE + srow) * Kd + scol;
    const u16* gB = Bt + (size_t)(bn * TILE + srow) * Kd + scol;

    f32x4 acc[FRM][FRN] = {};
    const int NT = Kd >> 6;

#pragma unroll
    for (int j = 0; j < IS; ++j) {
        async16(gA + (size_t)j * 64 * Kd, Asb + j * 4096 + wave * 512);
        async16(gB + (size_t)j * 64 * Kd, Bsb + j * 4096 + wave * 512);
    }
    asm volatile("s_waitcnt vmcnt(0)" ::: "memory");
    __syncthreads();

    int buf = 0;
    for (int t = 0; t < NT; ++t) {
        if (t + 1 < NT) {
            const int k0 = (t + 1) << 6;
            const int bo = (buf ^ 1) * TILE * 64;
#pragma unroll
            for (int j = 0; j < IS; ++j) {
                async16(gA + (size_t)j * 64 * Kd + k0, Asb + bo + j * 4096 + wave * 512);
                async16(gB + (size_t)j * 64 * Kd + k0, Bsb + bo + j * 4096 + wave * 512);
            }
        }
        const u16* Ab = Asb + buf * TILE * 64;
        const u16* Bb = Bsb + buf * TILE * 64;
#pragma unroll
        for (int kk = 0; kk < 2; ++kk) {
            bf16x8 af[FRM], bfr[FRN];
#pragma unroll
            for (int mi = 0; mi < FRM; ++mi) af[mi] = frag64(Ab, wm * RS + mi * 16, lane, kk);
#pragma unroll
            for (int ni = 0; ni < FRN; ++ni) bfr[ni] = frag64(Bb, wn * CS + ni * 16, lane, kk);
#pragma unroll
            for (int mi = 0; mi < FRM; ++mi)
#pragma unroll
                for (int ni = 0; ni < FRN; ++ni)
                    acc[mi][ni] = __builtin_amdgcn_mfma_f32_16x16x32_bf16(af[mi], bfr[ni], acc[mi][ni], 0, 0, 0);
        }
        asm volatile("s_waitcnt vmcnt(0)" ::: "memory");
        __syncthreads();
        buf ^= 1;
    }

    const int rsub = (lane >> 4) * 4;
    const int csub = lane & 15;
    // EPI == 1: fp32 + residual via padded LDS tile, float4 loads/stores (TILE=64)
    float* ctile = (float*)smem;                 // [64][68]
#pragma unroll
    for (int mi = 0; mi < FRM; ++mi)
#pragma unroll
        for (int ni = 0; ni < FRN; ++ni)
#pragma unroll
            for (int r = 0; r < 4; ++r)
                ctile[(wm * 32 + mi * 16 + rsub + r) * 68 + wn * 16 + ni * 16 + csub] = acc[mi][ni][r];
    __syncthreads();
#pragma unroll
    for (int k = 0; k < 2; ++k) {
        const int f = (tid + k * 512) * 4;
        const int r = f >> 6, c = f & 63;
        float4 v = *(const float4*)&ctile[r * 68 + c];
        const float4 rv = *(const float4*)&Res[(size_t)(bm * 64 + r) * N + bn * 64 + c];
        v.x += rv.x; v.y += rv.y; v.z += rv.z; v.w += rv.w;
        *(float4*)&((float*)Cout)[(size_t)(bm * 64 + r) * N + bn * 64 + c] = v;
    }
}

// ---------------- depthwise causal conv(4) + silu + l2norm(q,k) + beta / log-decay (vectorized x8)
__global__ __launch_bounds__(256) void k_conv(const u16* __restrict__ P, const float* __restrict__ cwq,
                                              const float* __restrict__ cwk, const float* __restrict__ cwv,
                                              const float* __restrict__ A_log, const float* __restrict__ dtb,
                                              u16* __restrict__ Qb, u16* __restrict__ Kb,
                                              u16* __restrict__ Vb, float* __restrict__ Gl,
                                              float* __restrict__ Bbuf) {
    const int bid = blockIdx.x;
    const int row = (bid & 7) * 256 + (bid >> 3);  // b*1024 + t
    const int t = row & 1023;
    const int tid = threadIdx.x;
    const long prow = (long)row * N1P;
#pragma unroll
    for (int p = 0; p < 2; ++p) {
        const int g = p * 256 + tid;
        const int c = g * 8;
        u16x8 taps[4];
#pragma unroll
        for (int j = 0; j < 4; ++j) {
            const int tt = t - 3 + j;
            if (tt >= 0) taps[j] = *(const u16x8*)&P[prow + (long)(j - 3) * N1P + c];
            else         taps[j] = u16x8{};
        }
        const float* cw = (c < 1024) ? (cwq + c * 4)
                          : (c < 2048) ? (cwk + (c - 1024) * 4)
                                       : (cwv + (c - 2048) * 4);
        float y[8];
#pragma unroll
        for (int e = 0; e < 8; ++e) {
            const float4 w = ((const float4*)cw)[e];
            float v = bf2f(taps[0][e]) * w.x + bf2f(taps[1][e]) * w.y +
                      bf2f(taps[2][e]) * w.z + bf2f(taps[3][e]) * w.w;
            y[e] = v * sigm(v);
        }
        if (c < 2048) {
            float ss = 0.f;
#pragma unroll
            for (int e = 0; e < 8; ++e) ss += y[e] * y[e];
            ss += __shfl_xor(ss, 1); ss += __shfl_xor(ss, 2); ss += __shfl_xor(ss, 4);
            const float rn = rsqrtf(ss + 1e-6f);
            const float sc = (c < 1024) ? rn * 0.125f : rn;
            u16x8 o;
#pragma unroll
            for (int e = 0; e < 8; ++e) o[e] = f2bf(y[e] * sc);
            if (c < 1024) *(u16x8*)&Qb[(size_t)row * 1024 + c] = o;
            else          *(u16x8*)&Kb[(size_t)row * 1024 + (c - 1024)] = o;
        } else {
            u16x8 o;
#pragma unroll
            for (int e = 0; e < 8; ++e) o[e] = f2bf(y[e]);
            *(u16x8*)&Vb[(size_t)row * 2048 + (c - 2048)] = o;
        }
    }
    if (tid < 32) {
        const int h = tid & 15;
        const float val = bf2f(P[prow + 4096 + tid]);
        if (tid < 16) {
            Bbuf[(size_t)row * 16 + h] = sigm(val);
        } else {
            const float a = val + dtb[h];
            const float sp = (a > 15.f) ? a : log1pf(__expf(a));
            Gl[(size_t)row * 16 + h] = -__expf(A_log[h]) * sp;   // log decay
        }
    }
}

// ---------------- chunked gated delta rule: stage 1 (per b,h,chunk — fully parallel)
// T = (I+A)^{-1} = (I+M0)(I+M1)...(I+M5), M0 = -A, M_j = M_{j-1}^2 (exact, A nilpotent)
__global__ __launch_bounds__(256) void k_scan1(
    const u16* __restrict__ Qb, const u16* __restrict__ Kb, const u16* __restrict__ Vb,
    const float* __restrict__ Gl, const float* __restrict__ Bb,
    u16* __restrict__ CHW, u16* __restrict__ CHM, u16* __restrict__ CHQc,
    u16* __restrict__ CHKcT, u16* __restrict__ CHU0T, float* __restrict__ CHcC) {
    __shared__ __align__(16) char sm[66048];
    u16* Ql   = (u16*)(sm);            // 8KB   (phase<=2a; then low half of fp32 T master)
    u16* Kl   = (u16*)(sm + 8192);     // 8KB   (phase<=2a; then high half of T master)
    u16* VTb  = (u16*)(sm + 16384);    // 16KB
    u16* KT1b = (u16*)(sm + 32768);    // 8KB
    u16* Mim  = (u16*)(sm + 40960);    // 8KB   M_j image (in-place squared)
    u16* MTim = (u16*)(sm + 49152);    // 8KB   M_j^T image
    u16* Tb   = (u16*)(sm + 57344);    // 8KB   bf16 T image (per-wave-owned rows)
    float* Tl    = (float*)sm;         // 16KB fp32 T master, overlays Ql+Kl after 2a
    float* gcs   = (float*)(sm + 65536);
    float* betal = (float*)(sm + 65792);

    const int blk = blockIdx.x;                      // bb*256 + h*16 + ch
    const int bb = blk >> 8, h = (blk >> 4) & 15, ch = blk & 15;
    const int bhc = blk;
    const int tid = threadIdx.x, lane = tid & 63, wave = tid >> 6;
    const long rowbase = (long)bb * 1024 + ch * 64;

    if (tid < 64) {
        gcs[tid] = Gl[(rowbase + tid) * 16 + h];
        betal[tid] = Bb[(rowbase + tid) * 16 + h];
    }
    for (int u = tid; u < 512; u += 256) {
        int r = u >> 3, c8 = u & 7;
        uint4 kv = *(const uint4*)&Kb[(rowbase + r) * 1024 + h * 64 + c8 * 8];
        uint4 qv = *(const uint4*)&Qb[(rowbase + r) * 1024 + h * 64 + c8 * 8];
        int b = r * 128 + ((c8 ^ (r & 7)) << 4);
        *(uint4*)((char*)Kl + b) = kv;
        *(uint4*)((char*)Ql + b) = qv;
    }
    __syncthreads();
    if (wave == 0) {
        float g = gcs[lane];
#pragma unroll
        for (int off = 1; off < 64; off <<= 1) {
            float n = __shfl_up(g, off, 64);
            if (lane >= off) g += n;
        }
        gcs[lane] = g;
    }
    for (int u = tid; u < 1024; u += 256) {          // VTb[dv][c] = beta_c * V[c][dv]
        int r = u >> 4, c8 = u & 15;
        u16x8 vv = *(const u16x8*)&Vb[(rowbase + r) * 2048 + h * 128 + c8 * 8];
        float bsc = betal[r];
#pragma unroll
        for (int j = 0; j < 8; ++j) {
            int dv = c8 * 8 + j;
            *(u16*)((char*)VTb + swz64(dv, r)) = f2bf(bf2f(vv[j]) * bsc);
        }
    }
    f32x4 aQK[4] = {}, aKK[4] = {};
#pragma unroll
    for (int nt = 0; nt < 4; ++nt)
#pragma unroll
        for (int kk = 0; kk < 2; ++kk) {
            bf16x8 bq = frag64(Kl, nt * 16, lane, kk);
            aQK[nt] = __builtin_amdgcn_mfma_f32_16x16x32_bf16(frag64(Ql, wave * 16, lane, kk), bq, aQK[nt], 0, 0, 0);
            aKK[nt] = __builtin_amdgcn_mfma_f32_16x16x32_bf16(frag64(Kl, wave * 16, lane, kk), bq, aKK[nt], 0, 0, 0);
        }
    __syncthreads();   // gcs + VTb published

    const float gcsC = gcs[63];
    float am[4][4];
#pragma unroll
    for (int nt = 0; nt < 4; ++nt)
#pragma unroll
        for (int reg = 0; reg < 4; ++reg) {
            int t = wave * 16 + ((lane >> 4) << 2) + reg;
            int i = nt * 16 + (lane & 15);
            float dec = __expf(gcs[t] - gcs[i]);
            float mv = (i <= t) ? dec * aQK[nt][reg] : 0.f;
            *(u16*)((char*)CHM + (size_t)bhc * 8192 + swz64(t, i)) = f2bf(mv);
            float a = (i < t) ? betal[t] * dec * aKK[nt][reg] : 0.f;
            am[nt][reg] = -a;
            u16 amb = f2bf(-a);
            *(u16*)((char*)Mim + swz64(t, i)) = amb;
            *(u16*)((char*)MTim + swz64(i, t)) = amb;
        }
    for (int e = tid; e < 4096; e += 256) {
        int r = e >> 6, c = e & 63;
        int ib = swz64(r, c);
        float qv = bf2f(*(const u16*)((const char*)Ql + ib)) * __expf(gcs[r]);
        *(u16*)((char*)CHQc + (size_t)bhc * 8192 + ib) = f2bf(qv);
        float kv = bf2f(*(const u16*)((const char*)Kl + ib));
        int ob = swz64(c, r);
        *(u16*)((char*)KT1b + ob) = f2bf(kv * betal[r] * __expf(gcs[r]));
        *(u16*)((char*)CHKcT + (size_t)bhc * 8192 + ob) = f2bf(kv * __expf(gcsC - gcs[r]));
    }
    if (tid == 0) CHcC[bhc] = __expf(gcsC);
    __syncthreads();   // Ql/Kl dead; Tl overlay becomes safe

#pragma unroll
    for (int nt = 0; nt < 4; ++nt)
#pragma unroll
        for (int reg = 0; reg < 4; ++reg) {
            int t = wave * 16 + ((lane >> 4) << 2) + reg;
            int i = nt * 16 + (lane & 15);
            float tv = (t == i) ? 1.f : am[nt][reg];
            Tl[t * 64 + i] = tv;
            *(u16*)((char*)Tb + swz64(t, i)) = f2bf(tv);
        }
    __syncthreads();

    const int hi = wave * 16 + 15;
#pragma unroll
    for (int j = 1; j <= 5; ++j) {
        f32x4 aM[4] = {};
#pragma unroll
        for (int nt = 0; nt < 4; ++nt) {
            if (nt * 16 > hi - (1 << j)) continue;
#pragma unroll
            for (int kk = 0; kk < 2; ++kk) {
                if (kk * 32 > hi) break;
                aM[nt] = __builtin_amdgcn_mfma_f32_16x16x32_bf16(
                    frag64(Mim, wave * 16, lane, kk), frag64(MTim, nt * 16, lane, kk), aM[nt], 0, 0, 0);
            }
        }
        __syncthreads();
#pragma unroll
        for (int nt = 0; nt < 4; ++nt)
#pragma unroll
            for (int reg = 0; reg < 4; ++reg) {
                int t = wave * 16 + ((lane >> 4) << 2) + reg;
                int i = nt * 16 + (lane & 15);
                float mv = (t - i >= (1 << j)) ? aM[nt][reg] : 0.f;
                u16 mb = f2bf(mv);
                *(u16*)((char*)Mim + swz64(t, i)) = mb;
                *(u16*)((char*)MTim + swz64(i, t)) = mb;
            }
        __syncthreads();
        f32x4 aT[4];
#pragma unroll
        for (int nt = 0; nt < 4; ++nt)
#pragma unroll
            for (int reg = 0; reg < 4; ++reg) {
                int t = wave * 16 + ((lane >> 4) << 2) + reg;
                int i = nt * 16 + (lane & 15);
                aT[nt][reg] = Tl[t * 64 + i];
            }
#pragma unroll
        for (int nt = 0; nt < 4; ++nt) {
            if (nt * 16 > hi - (1 << j)) continue;
#pragma unroll
            for (int kk = 0; kk < 2; ++kk) {
                if (kk * 32 > hi) break;
                aT[nt] = __builtin_amdgcn_mfma_f32_16x16x32_bf16(
                    frag64(Tb, wave * 16, lane, kk), frag64(MTim, nt * 16, lane, kk), aT[nt], 0, 0, 0);
            }
        }
#pragma unroll
        for (int nt = 0; nt < 4; ++nt)
#pragma unroll
            for (int reg = 0; reg < 4; ++reg) {
                int t = wave * 16 + ((lane >> 4) << 2) + reg;
                int i = nt * 16 + (lane & 15);
                Tl[t * 64 + i] = aT[nt][reg];
                *(u16*)((char*)Tb + swz64(t, i)) = f2bf(aT[nt][reg]);
            }
    }
    __syncthreads();

    {
        f32x4 aW[4] = {};
#pragma unroll
        for (int nt = 0; nt < 4; ++nt)
#pragma unroll
            for (int kk = 0; kk < 2; ++kk) {
                if (kk * 32 > hi) break;
                aW[nt] = __builtin_amdgcn_mfma_f32_16x16x32_bf16(
                    frag64(Tb, wave * 16, lane, kk), frag64(KT1b, nt * 16, lane, kk), aW[nt], 0, 0, 0);
            }
#pragma unroll
        for (int nt = 0; nt < 4; ++nt)
#pragma unroll
            for (int reg = 0; reg < 4; ++reg) {
                int r = wave * 16 + ((lane >> 4) << 2) + reg;
                int c = nt * 16 + (lane & 15);
                *(u16*)((char*)CHW + (size_t)bhc * 8192 + swz64(r, c)) = f2bf(aW[nt][reg]);
            }
    }
#pragma unroll
    for (int rt = 0; rt < 2; ++rt) {
        f32x4 aU[4] = {};
        int rb = (wave * 2 + rt) * 16;
#pragma unroll
        for (int nt = 0; nt < 4; ++nt)
#pragma unroll
            for (int kk = 0; kk < 2; ++kk) {
                if (kk * 32 > nt * 16 + 15) continue;
                aU[nt] = __builtin_amdgcn_mfma_f32_16x16x32_bf16(
                    frag64(VTb, rb, lane, kk), frag64(Tb, nt * 16, lane, kk), aU[nt], 0, 0, 0);
            }
#pragma unroll
        for (int nt = 0; nt < 4; ++nt)
#pragma unroll
            for (int reg = 0; reg < 4; ++reg) {
                int dv = rb + ((lane >> 4) << 2) + reg;
                int c = nt * 16 + (lane & 15);
                *(u16*)((char*)CHU0T + (size_t)bhc * 16384 + swz64(dv, c)) = f2bf(aU[nt][reg]);
            }
    }
}

// ---------------- chunked gated delta rule: stage 2 (sequential over 16 chunks; block = b,h,dv-half)
__global__ __launch_bounds__(256) void k_scan2(
    const u16* __restrict__ CHW, const u16* __restrict__ CHM, const u16* __restrict__ CHQc,
    const u16* __restrict__ CHKcT, const u16* __restrict__ CHU0T, const float* __restrict__ CHcC,
    float* __restrict__ O) {
    __shared__ __align__(16) u16 stg[2][5 * 4096];
    __shared__ __align__(16) u16 STb[4096], uTl[4096];
    __shared__ float ST[64 * 66];
    const int blk = blockIdx.x;
    const int bb = blk >> 5, h = (blk >> 1) & 15, dvh = blk & 1;
    const int bh = bb * 16 + h;
    const int tid = threadIdx.x, lane = tid & 63, wave = tid >> 6;

    for (int e = tid; e < 64 * 66; e += 256) ST[e] = 0.f;
    for (int e = tid; e < 4096; e += 256) STb[e] = 0;

    auto stage = [&](int buf, int ch) {
        const size_t base = (size_t)(bh * 16 + ch);
        const u16* srcs[5] = { CHW + base * 4096, CHM + base * 4096, CHQc + base * 4096,
                               CHKcT + base * 4096, CHU0T + base * 8192 + dvh * 4096 };
#pragma unroll
        for (int s = 0; s < 5; ++s)
#pragma unroll
            for (int r = 0; r < 2; ++r) {
                int ub = r * 256 + wave * 64;
                async16(srcs[s] + (size_t)(ub + lane) * 8, &stg[buf][s * 4096 + ub * 8]);
            }
    };
    stage(0, 0);
    for (int ch = 0; ch < 16; ++ch) {
        const int cur = ch & 1;
        asm volatile("s_waitcnt vmcnt(0)" ::: "memory");
        __syncthreads();
        if (ch < 15) stage(cur ^ 1, ch + 1);
        const u16* sW = &stg[cur][0];
        const u16* sM = &stg[cur][4096];
        const u16* sQc = &stg[cur][8192];
        const u16* sKcT = &stg[cur][12288];
        const u16* sU0 = &stg[cur][16384];
        {
            f32x4 acc[4] = {};
#pragma unroll
            for (int nt = 0; nt < 4; ++nt)
#pragma unroll
                for (int kk = 0; kk < 2; ++kk)
                    acc[nt] = __builtin_amdgcn_mfma_f32_16x16x32_bf16(
                        frag64(STb, wave * 16, lane, kk), frag64(sW, nt * 16, lane, kk), acc[nt], 0, 0, 0);
#pragma unroll
            for (int nt = 0; nt < 4; ++nt)
#pragma unroll
                for (int reg = 0; reg < 4; ++reg) {
                    int dv = wave * 16 + ((lane >> 4) << 2) + reg;
                    int c = nt * 16 + (lane & 15);
                    int b = swz64(dv, c);
                    float u0 = bf2f(*(const u16*)((const char*)sU0 + b));
                    *(u16*)((char*)uTl + b) = f2bf(u0 - acc[nt][reg]);
                }
        }
        __syncthreads();
        f32x4 accO[4] = {}, accS[4] = {};
#pragma unroll
        for (int nt = 0; nt < 4; ++nt)
#pragma unroll
            for (int kk = 0; kk < 2; ++kk) {
                accO[nt] = __builtin_amdgcn_mfma_f32_16x16x32_bf16(
                    frag64(sM, wave * 16, lane, kk), frag64(uTl, nt * 16, lane, kk), accO[nt], 0, 0, 0);
                accO[nt] = __builtin_amdgcn_mfma_f32_16x16x32_bf16(
                    frag64(sQc, wave * 16, lane, kk), frag64(STb, nt * 16, lane, kk), accO[nt], 0, 0, 0);
                accS[nt] = __builtin_amdgcn_mfma_f32_16x16x32_bf16(
                    frag64(uTl, wave * 16, lane, kk), frag64(sKcT, nt * 16, lane, kk), accS[nt], 0, 0, 0);
            }
        __syncthreads();
        const float cC = CHcC[bh * 16 + ch];
#pragma unroll
        for (int nt = 0; nt < 4; ++nt)
#pragma unroll
            for (int reg = 0; reg < 4; ++reg) {
                int rr = wave * 16 + ((lane >> 4) << 2) + reg;
                int cc = nt * 16 + (lane & 15);
                O[((size_t)(bb * 1024 + ch * 64 + rr)) * 2048 + h * 128 + dvh * 64 + cc] = accO[nt][reg];
                float ns = cC * ST[rr * 66 + cc] + accS[nt][reg];
                ST[rr * 66 + cc] = ns;
                *(u16*)((char*)STb + swz64(rr, cc)) = f2bf(ns);
            }
    }
}

// ---------------- per-head RMSNorm(o) * gate * sigmoid(gate) -> bf16
__global__ __launch_bounds__(256) void k_gate(const float* __restrict__ O, const u16* __restrict__ P,
                                              const float* __restrict__ onw, u16* __restrict__ OG) {
    const int row = blockIdx.x;
    const int tid = threadIdx.x, lane = tid & 63, wave = tid >> 6;
#pragma unroll
    for (int p = 0; p < 4; ++p) {
        const int h = p * 4 + wave;
        const int dv = lane * 2;
        const float2 o2 = *(const float2*)&O[(size_t)row * 2048 + h * 128 + dv];
        float ss = o2.x * o2.x + o2.y * o2.y;
#pragma unroll
        for (int o = 1; o < 64; o <<= 1) ss += __shfl_xor(ss, o);
        const float rn = rsqrtf(ss * (1.f / 128.f) + 1e-6f);
        const float g0 = bf2f(P[(size_t)row * N1P + 4128 + h * 128 + dv]);
        const float g1 = bf2f(P[(size_t)row * N1P + 4128 + h * 128 + dv + 1]);
        const float r0 = o2.x * rn * onw[dv] * g0 * sigm(g0);
        const float r1 = o2.y * rn * onw[dv + 1] * g1 * sigm(g1);
        const uint32_t pk = (uint32_t)f2bf(r0) | ((uint32_t)f2bf(r1) << 16);
        *(uint32_t*)&OG[(size_t)row * 2048 + h * 128 + dv] = pk;
    }
}

extern "C" void kernel_launch(void* const* d_in, const int* in_sizes, int n_in,
                              void* d_out, int out_size, void* d_ws, size_t ws_size,
                              hipStream_t stream) {
    const float* x   = (const float*)d_in[0];
    const float* n1w = (const float*)d_in[1];
    const float* wq  = (const float*)d_in[2];
    const float* wk  = (const float*)d_in[3];
    const float* wv  = (const float*)d_in[4];
    const float* cq  = (const float*)d_in[5];
    const float* ck  = (const float*)d_in[6];
    const float* cv  = (const float*)d_in[7];
    const float* wb  = (const float*)d_in[8];
    const float* wa  = (const float*)d_in[9];
    const float* Alg = (const float*)d_in[10];
    const float* dtb = (const float*)d_in[11];
    const float* wg  = (const float*)d_in[12];
    const float* onw = (const float*)d_in[13];
    const float* wo  = (const float*)d_in[14];
    const float* n2w = (const float*)d_in[15];
    const float* w1  = (const float*)d_in[16];
    const float* w2  = (const float*)d_in[17];
    const float* w3  = (const float*)d_in[18];

    if (ws_size < 111413248ULL) return;

    char* ws = (char*)d_ws;
    u16*   WcatT = (u16*)(ws + 0);            // [6400][1024] bf16 (CHW/CHM/CHQc reuse)
    u16*   WoT   = (u16*)(ws + 13107200);     // [2048][1024]
    u16*   W13T  = (u16*)(ws + 17301504);     // [5632][1024] group-16 interleaved w1/w3
    u16*   W2T   = (u16*)(ws + 28835840);     // [1024][2816]
    u16*   hA    = (u16*)(ws + 34603008);     // [2048][1024] (h2A reuse)
    u16*   P     = (u16*)(ws + 38797312);     // [2048][6400]
    u16*   Qb    = (u16*)(ws + 65011712);     // [2048][1024] bf16 (Mm reuse)
    u16*   Kb    = (u16*)(ws + 69206016);     // [2048][1024] bf16
    u16*   Vb    = (u16*)(ws + 73400320);     // [2048][2048] bf16 (OG reuse)
    float* Gl    = (float*)(ws + 81788928);   // [2048][16] log decay
    float* Bbf   = (float*)(ws + 81920000);   // [2048][16]
    float* O     = (float*)(ws + 82051072);   // [2048][2048] fp32 (X2 reuse)
    u16*   CHKcT = (u16*)(ws + 98828288);     // [512][64][64] bf16 image
    u16*   CHU0T = (u16*)(ws + 103022592);    // [512][128][64] bf16 image
    float* CHcC  = (float*)(ws + 111411200);  // [512]
    u16*   CHW   = WcatT;                     // [512][64][64] image
    u16*   CHM   = (u16*)(ws + 4194304);
    u16*   CHQc  = (u16*)(ws + 8388608);
    u16*   Mm  = Qb;                          // [2048][2816] bf16 (Qb/Kb/Vb dead by then)
    u16*   OG  = Vb;
    float* X2  = O;
    u16*   h2A = hA;

    // fused weight transposes (fp32 [K][N] -> bf16 [N][K]) in one launch
    TJobs tj;
    tj.j[0] = { wq, WcatT, 1024, 1024,    0, 1, 1024,     0, 32, 0 };
    tj.j[1] = { wk, WcatT, 1024, 1024, 1024, 1, 1024,  1024, 32, 0 };
    tj.j[2] = { wv, WcatT, 1024, 2048, 2048, 1, 2048,  2048, 64, 0 };
    tj.j[3] = { wb, WcatT, 1024,   16, 4096, 1,   16,  4096,  1, 0 };
    tj.j[4] = { wa, WcatT, 1024,   16, 4112, 1,   16,  4128,  1, 0 };
    tj.j[5] = { wg, WcatT, 1024, 2048, 4128, 1, 2272,  4160, 71, 0 };  // pads rows to 6400 with zeros
    tj.j[6] = { wo, WoT,   2048, 1024,    0, 1, 1024,  6432, 32, 0 };
    tj.j[7] = { w1, W13T,  1024, 2816,    0, 1, 2816,  8480, 88, 1 };  // group-16 even
    tj.j[8] = { w3, W13T,  1024, 2816,   16, 1, 2816, 11296, 88, 1 };  // group-16 odd
    tj.j[9] = { w2, W2T,   2816, 1024,    0, 1, 1024, 14112, 32, 0 };
    k_transpose_all<<<16928, dim3(32, 8), 0, stream>>>(tj, 10);

    k_rmsnorm<<<2048, 256, 0, stream>>>(x, n1w, hA);
    k_gemm256<2><<<200, 512, 0, stream>>>(hA, WcatT, P, N1P, 1024);

    k_conv<<<2048, 256, 0, stream>>>(P, cq, ck, cv, Alg, dtb, Qb, Kb, Vb, Gl, Bbf);

    k_scan1<<<512, 256, 0, stream>>>(Qb, Kb, Vb, Gl, Bbf, CHW, CHM, CHQc, CHKcT, CHU0T, CHcC);
    k_scan2<<<64, 256, 0, stream>>>(CHW, CHM, CHQc, CHKcT, CHU0T, CHcC, O);

    k_gate<<<2048, 256, 0, stream>>>(O, P, onw, OG);
    k_gemm<64, 1><<<512, 512, 0, stream>>>(OG, WoT, X2, x, 1024, 2048);

    k_rmsnorm<<<2048, 256, 0, stream>>>(X2, n2w, h2A);
    k_gemm256<3><<<176, 512, 0, stream>>>(h2A, W13T, Mm, 2816, 1024);  // fused silu(u1)*u3
    k_gemm<64, 1><<<512, 512, 0, stream>>>(Mm, W2T, (float*)d_out, X2, 1024, 2816);
}